// Round 1
// baseline (1022.853 us; speedup 1.0000x reference)
//
#include <hip/hip_runtime.h>

#define N_NODES 100000
#define N_EDGES 1600000
#define N_GRAPHS 2000
#define HID 64

// ---------------- utility ----------------
__global__ __launch_bounds__(256) void k_zero_i32(int* __restrict__ p, int n) {
    int i = blockIdx.x * 256 + threadIdx.x;
    if (i < n) p[i] = 0;
}

// ---------------- degree histogram ----------------
__global__ __launch_bounds__(256) void k_hist(const int* __restrict__ src, const int* __restrict__ dst,
                                              int* __restrict__ outc, int* __restrict__ inc) {
    int e = blockIdx.x * 256 + threadIdx.x;
    if (e < N_EDGES) {
        atomicAdd(&outc[src[e]], 1);
        atomicAdd(&inc[dst[e]], 1);
    }
}

__global__ __launch_bounds__(256) void k_deginv(const int* __restrict__ outc, const int* __restrict__ inc,
                                                float* __restrict__ odi, float* __restrict__ idi) {
    int v = blockIdx.x * 256 + threadIdx.x;
    if (v < N_NODES) {
        odi[v] = rsqrtf((float)max(outc[v], 1));
        idi[v] = rsqrtf((float)max(inc[v], 1));
    }
}

// ---------------- exclusive scan (3-phase) ----------------
__global__ __launch_bounds__(256) void k_bsum(const int* __restrict__ cnt, int* __restrict__ bsums) {
    __shared__ int sd[256];
    int tid = threadIdx.x;
    int i = blockIdx.x * 256 + tid;
    sd[tid] = (i < N_NODES) ? cnt[i] : 0;
    __syncthreads();
    for (int s = 128; s > 0; s >>= 1) {
        if (tid < s) sd[tid] += sd[tid + s];
        __syncthreads();
    }
    if (tid == 0) bsums[blockIdx.x] = sd[0];
}

__global__ __launch_bounds__(512) void k_scan_bsums(int* __restrict__ bsums, int nb) {
    __shared__ int sd[512];
    int tid = threadIdx.x;
    int v = (tid < nb) ? bsums[tid] : 0;
    sd[tid] = v;
    __syncthreads();
    for (int off = 1; off < 512; off <<= 1) {
        int t = (tid >= off) ? sd[tid - off] : 0;
        __syncthreads();
        sd[tid] += t;
        __syncthreads();
    }
    if (tid < nb) bsums[tid] = sd[tid] - v;  // exclusive
}

__global__ __launch_bounds__(256) void k_scan_final(const int* __restrict__ cnt, const int* __restrict__ bsums,
                                                    int* __restrict__ rowp, int* __restrict__ cur) {
    __shared__ int sd[256];
    int tid = threadIdx.x;
    int i = blockIdx.x * 256 + tid;
    int v = (i < N_NODES) ? cnt[i] : 0;
    sd[tid] = v;
    __syncthreads();
    for (int off = 1; off < 256; off <<= 1) {
        int t = (tid >= off) ? sd[tid - off] : 0;
        __syncthreads();
        sd[tid] += t;
        __syncthreads();
    }
    if (i < N_NODES) {
        int excl = sd[tid] - v + bsums[blockIdx.x];
        rowp[i] = excl;
        cur[i] = excl;
    }
}

__global__ __launch_bounds__(256) void k_scatter(const int* __restrict__ src, const int* __restrict__ dst,
                                                 int* __restrict__ cur, int* __restrict__ col) {
    int e = blockIdx.x * 256 + threadIdx.x;
    if (e < N_EDGES) {
        int pos = atomicAdd(&cur[dst[e]], 1);
        col[pos] = src[e];
    }
}

// ---------------- per-layer aggregation: agg[v] = idi[v] * sum_{e:dst=v} odi[src] * x[src] -------
__global__ __launch_bounds__(256) void k_agg(const float* __restrict__ x, const int* __restrict__ rowp,
                                             const int* __restrict__ cur, const int* __restrict__ col,
                                             const float* __restrict__ odi, const float* __restrict__ idi,
                                             float* __restrict__ aggS) {
    int wave = (blockIdx.x * 256 + threadIdx.x) >> 6;
    int lane = threadIdx.x & 63;
    if (wave >= N_NODES) return;
    int v = wave;
    int beg = rowp[v], end = cur[v];
    float a0 = 0.f, a1 = 0.f;
    int p = beg;
    for (; p + 2 <= end; p += 2) {
        int s0 = col[p], s1 = col[p + 1];
        float w0 = odi[s0], w1 = odi[s1];
        a0 = fmaf(x[s0 * 64 + lane], w0, a0);
        a1 = fmaf(x[s1 * 64 + lane], w1, a1);
    }
    if (p < end) {
        int s0 = col[p];
        a0 = fmaf(x[s0 * 64 + lane], odi[s0], a0);
    }
    aggS[v * 64 + lane] = (a0 + a1) * idi[v];
}

// ---------------- GEMM: out[v] = (relu?)(A[v] @ W + b), A:[N][64], W:[64][64] ----------------
__global__ __launch_bounds__(256) void k_gemm(const float* __restrict__ A, const float* __restrict__ W,
                                              const float* __restrict__ b, float* __restrict__ out,
                                              int relu) {
    __shared__ float As[64][68];
    __shared__ float Ws[64][64];
    int tid = threadIdx.x;
    int v0 = blockIdx.x * 64;
    // stage W (4096 floats)
    for (int i = tid * 4; i < 4096; i += 1024)
        *(float4*)&Ws[0][i] = *(const float4*)&W[i];
    // stage A tile (64 rows x 64 cols), pad stride 68
    for (int idx = tid; idx < 1024; idx += 256) {
        int r = idx >> 4, c4 = (idx & 15) << 2;
        int v = v0 + r;
        float4 val = make_float4(0.f, 0.f, 0.f, 0.f);
        if (v < N_NODES) val = *(const float4*)&A[(size_t)v * 64 + c4];
        *(float4*)&As[r][c4] = val;
    }
    __syncthreads();
    int ti = tid >> 4, tj = tid & 15;
    int i0 = ti << 2, j0 = tj << 2;
    float acc[4][4] = {{0.f}};
    for (int k4 = 0; k4 < 64; k4 += 4) {
        float a[4][4], w[4][4];
#pragma unroll
        for (int r = 0; r < 4; ++r) *(float4*)a[r] = *(float4*)&As[i0 + r][k4];
#pragma unroll
        for (int q = 0; q < 4; ++q) *(float4*)w[q] = *(float4*)&Ws[k4 + q][j0];
#pragma unroll
        for (int r = 0; r < 4; ++r)
#pragma unroll
            for (int c = 0; c < 4; ++c)
#pragma unroll
                for (int q = 0; q < 4; ++q)
                    acc[r][c] = fmaf(a[r][q], w[q][c], acc[r][c]);
    }
    float bb[4];
    *(float4*)bb = *(const float4*)&b[j0];
#pragma unroll
    for (int r = 0; r < 4; ++r) {
        int v = v0 + i0 + r;
        if (v < N_NODES) {
            float o[4];
#pragma unroll
            for (int c = 0; c < 4; ++c) {
                float m = acc[r][c] + bb[c];
                o[c] = relu ? fmaxf(m, 0.f) : m;
            }
            *(float4*)&out[(size_t)v * 64 + j0] = *(float4*)o;
        }
    }
}

// ---------------- row-norm sum ----------------
__global__ __launch_bounds__(256) void k_norm(const float* __restrict__ h, float* __restrict__ nsum) {
    int wave_g = (blockIdx.x * 256 + threadIdx.x) >> 6;
    int lane = threadIdx.x & 63;
    float x = 0.f;
    if (wave_g < N_NODES) x = h[(size_t)wave_g * 64 + lane];
    float s = x * x;
    for (int off = 32; off > 0; off >>= 1) s += __shfl_xor(s, off, 64);
    __shared__ float part[4];
    int w = threadIdx.x >> 6;
    if (lane == 0) part[w] = (wave_g < N_NODES) ? sqrtf(s) : 0.f;
    __syncthreads();
    if (threadIdx.x == 0) atomicAdd(nsum, part[0] + part[1] + part[2] + part[3]);
}

__global__ void k_factor(const float* __restrict__ nsum, float* __restrict__ factor) {
    factor[0] = 8.0f * (float)N_NODES / nsum[0];
}

// ---------------- sum pooling over sorted graph_ids ----------------
#define POOL_CHUNK 32
__global__ __launch_bounds__(256) void k_pool(const float* __restrict__ h, const int* __restrict__ gid,
                                              const float* __restrict__ factor, float* __restrict__ out) {
    int wave = (blockIdx.x * 256 + threadIdx.x) >> 6;
    int lane = threadIdx.x & 63;
    int v0 = wave * POOL_CHUNK;
    if (v0 >= N_NODES) return;
    float f = factor[0];
    int vend = min(v0 + POOL_CHUNK, N_NODES);
    int gprev = gid[v0];
    float acc = 0.f;
    for (int v = v0; v < vend; ++v) {
        int g = gid[v];
        if (g != gprev) {
            atomicAdd(&out[(size_t)gprev * 64 + lane], acc);
            acc = 0.f;
            gprev = g;
        }
        acc = fmaf(h[(size_t)v * 64 + lane], f, acc);
    }
    atomicAdd(&out[(size_t)gprev * 64 + lane], acc);
}

extern "C" void kernel_launch(void* const* d_in, const int* in_sizes, int n_in,
                              void* d_out, int out_size, void* d_ws, size_t ws_size,
                              hipStream_t stream) {
    const float* h    = (const float*)d_in[0];
    const int*   esrc = (const int*)d_in[1];
    const int*   edst = (const int*)d_in[2];
    const int*   gids = (const int*)d_in[3];
    const float* W0 = (const float*)d_in[4];
    const float* b0 = (const float*)d_in[5];
    const float* W1 = (const float*)d_in[6];
    const float* b1 = (const float*)d_in[7];
    const float* W2 = (const float*)d_in[8];
    const float* b2 = (const float*)d_in[9];
    float* out = (float*)d_out;

    char* wsp = (char*)d_ws;
    size_t off = 0;
    auto alloc = [&](size_t bytes) -> void* {
        void* p = wsp + off;
        off += (bytes + 255) & ~(size_t)255;
        return p;
    };
    int*   deg_out = (int*)alloc((size_t)N_NODES * 4);
    int*   deg_in  = (int*)alloc((size_t)N_NODES * 4);
    float* odi     = (float*)alloc((size_t)N_NODES * 4);
    float* idi     = (float*)alloc((size_t)N_NODES * 4);
    int*   rowp    = (int*)alloc((size_t)N_NODES * 4);
    int*   cursor  = (int*)alloc((size_t)N_NODES * 4);
    int*   bsums   = (int*)alloc(512 * 4);
    float* nsum    = (float*)alloc(4);
    float* factor  = (float*)alloc(4);
    int*   col     = (int*)alloc((size_t)N_EDGES * 4);
    float* bufA    = (float*)alloc((size_t)N_NODES * 64 * 4);
    float* bufB    = (float*)alloc((size_t)N_NODES * 64 * 4);

    // zero the two degree arrays (contiguous region incl. padding), nsum, and d_out
    int zdeg = (int)(((char*)odi - (char*)deg_out) / 4);
    k_zero_i32<<<(zdeg + 255) / 256, 256, 0, stream>>>(deg_out, zdeg);
    k_zero_i32<<<1, 256, 0, stream>>>((int*)nsum, 1);
    k_zero_i32<<<(N_GRAPHS * 64 + 255) / 256, 256, 0, stream>>>((int*)out, N_GRAPHS * 64);

    // degrees + normalizers
    k_hist<<<(N_EDGES + 255) / 256, 256, 0, stream>>>(esrc, edst, deg_out, deg_in);
    k_deginv<<<(N_NODES + 255) / 256, 256, 0, stream>>>(deg_out, deg_in, odi, idi);

    // CSR by destination
    int nblk = (N_NODES + 255) / 256;  // 391
    k_bsum<<<nblk, 256, 0, stream>>>(deg_in, bsums);
    k_scan_bsums<<<1, 512, 0, stream>>>(bsums, nblk);
    k_scan_final<<<nblk, 256, 0, stream>>>(deg_in, bsums, rowp, cursor);
    k_scatter<<<(N_EDGES + 255) / 256, 256, 0, stream>>>(esrc, edst, cursor, col);

    int aggBlocks  = (N_NODES + 3) / 4;        // 1 wave per node, 4 waves/block
    int gemmBlocks = (N_NODES + 63) / 64;

    // layer 0
    k_agg<<<aggBlocks, 256, 0, stream>>>(h, rowp, cursor, col, odi, idi, bufA);
    k_gemm<<<gemmBlocks, 256, 0, stream>>>(bufA, W0, b0, bufB, 1);
    // layer 1
    k_agg<<<aggBlocks, 256, 0, stream>>>(bufB, rowp, cursor, col, odi, idi, bufA);
    k_gemm<<<gemmBlocks, 256, 0, stream>>>(bufA, W1, b1, bufB, 1);
    // layer 2
    k_agg<<<aggBlocks, 256, 0, stream>>>(bufB, rowp, cursor, col, odi, idi, bufA);
    k_gemm<<<gemmBlocks, 256, 0, stream>>>(bufA, W2, b2, bufB, 0);

    // factor + pooling
    k_norm<<<(N_NODES + 3) / 4, 256, 0, stream>>>(bufB, nsum);
    k_factor<<<1, 1, 0, stream>>>(nsum, factor);
    int poolWaves  = (N_NODES + POOL_CHUNK - 1) / POOL_CHUNK;
    int poolBlocks = (poolWaves + 3) / 4;
    k_pool<<<poolBlocks, 256, 0, stream>>>(bufB, gids, factor, out);
}

// Round 2
// 718.216 us; speedup vs baseline: 1.4242x; 1.4242x over previous
//
#include <hip/hip_runtime.h>

#define N_NODES 100000
#define N_EDGES 1600000
#define N_GRAPHS 2000
#define HID 64
#define NORM_BLOCKS 1024

// ---------------- utility ----------------
__global__ __launch_bounds__(256) void k_zero_i32(int* __restrict__ p, int n) {
    int i = blockIdx.x * 256 + threadIdx.x;
    if (i < n) p[i] = 0;
}

// ---------------- degree histogram ----------------
__global__ __launch_bounds__(256) void k_hist(const int* __restrict__ src, const int* __restrict__ dst,
                                              int* __restrict__ outc, int* __restrict__ inc) {
    int e = blockIdx.x * 256 + threadIdx.x;
    if (e < N_EDGES) {
        atomicAdd(&outc[src[e]], 1);
        atomicAdd(&inc[dst[e]], 1);
    }
}

__global__ __launch_bounds__(256) void k_deginv(const int* __restrict__ outc, const int* __restrict__ inc,
                                                float* __restrict__ odi, float* __restrict__ idi) {
    int v = blockIdx.x * 256 + threadIdx.x;
    if (v < N_NODES) {
        odi[v] = rsqrtf((float)max(outc[v], 1));
        idi[v] = rsqrtf((float)max(inc[v], 1));
    }
}

// ---------------- exclusive scan (3-phase) ----------------
__global__ __launch_bounds__(256) void k_bsum(const int* __restrict__ cnt, int* __restrict__ bsums) {
    __shared__ int sd[256];
    int tid = threadIdx.x;
    int i = blockIdx.x * 256 + tid;
    sd[tid] = (i < N_NODES) ? cnt[i] : 0;
    __syncthreads();
    for (int s = 128; s > 0; s >>= 1) {
        if (tid < s) sd[tid] += sd[tid + s];
        __syncthreads();
    }
    if (tid == 0) bsums[blockIdx.x] = sd[0];
}

__global__ __launch_bounds__(512) void k_scan_bsums(int* __restrict__ bsums, int nb) {
    __shared__ int sd[512];
    int tid = threadIdx.x;
    int v = (tid < nb) ? bsums[tid] : 0;
    sd[tid] = v;
    __syncthreads();
    for (int off = 1; off < 512; off <<= 1) {
        int t = (tid >= off) ? sd[tid - off] : 0;
        __syncthreads();
        sd[tid] += t;
        __syncthreads();
    }
    if (tid < nb) bsums[tid] = sd[tid] - v;  // exclusive
}

__global__ __launch_bounds__(256) void k_scan_final(const int* __restrict__ cnt, const int* __restrict__ bsums,
                                                    int* __restrict__ rowp, int* __restrict__ cur) {
    __shared__ int sd[256];
    int tid = threadIdx.x;
    int i = blockIdx.x * 256 + tid;
    int v = (i < N_NODES) ? cnt[i] : 0;
    sd[tid] = v;
    __syncthreads();
    for (int off = 1; off < 256; off <<= 1) {
        int t = (tid >= off) ? sd[tid - off] : 0;
        __syncthreads();
        sd[tid] += t;
        __syncthreads();
    }
    if (i < N_NODES) {
        int excl = sd[tid] - v + bsums[blockIdx.x];
        rowp[i] = excl;
        cur[i] = excl;
    }
}

__global__ __launch_bounds__(256) void k_scatter(const int* __restrict__ src, const int* __restrict__ dst,
                                                 int* __restrict__ cur, int* __restrict__ col) {
    int e = blockIdx.x * 256 + threadIdx.x;
    if (e < N_EDGES) {
        int pos = atomicAdd(&cur[dst[e]], 1);
        col[pos] = src[e];
    }
}

// ---------------- per-layer aggregation: agg[v] = idi[v] * sum_{e:dst=v} odi[src] * x[src] -------
__global__ __launch_bounds__(256) void k_agg(const float* __restrict__ x, const int* __restrict__ rowp,
                                             const int* __restrict__ cur, const int* __restrict__ col,
                                             const float* __restrict__ odi, const float* __restrict__ idi,
                                             float* __restrict__ aggS) {
    int wave = (blockIdx.x * 256 + threadIdx.x) >> 6;
    int lane = threadIdx.x & 63;
    if (wave >= N_NODES) return;
    int v = wave;
    int beg = rowp[v], end = cur[v];
    float a0 = 0.f, a1 = 0.f;
    int p = beg;
    for (; p + 2 <= end; p += 2) {
        int s0 = col[p], s1 = col[p + 1];
        float w0 = odi[s0], w1 = odi[s1];
        a0 = fmaf(x[s0 * 64 + lane], w0, a0);
        a1 = fmaf(x[s1 * 64 + lane], w1, a1);
    }
    if (p < end) {
        int s0 = col[p];
        a0 = fmaf(x[s0 * 64 + lane], odi[s0], a0);
    }
    aggS[v * 64 + lane] = (a0 + a1) * idi[v];
}

// ---------------- GEMM: out[v] = (relu?)(A[v] @ W + b), A:[N][64], W:[64][64] ----------------
__global__ __launch_bounds__(256) void k_gemm(const float* __restrict__ A, const float* __restrict__ W,
                                              const float* __restrict__ b, float* __restrict__ out,
                                              int relu) {
    __shared__ float As[64][68];
    __shared__ float Ws[64][64];
    int tid = threadIdx.x;
    int v0 = blockIdx.x * 64;
    // stage W (4096 floats)
    for (int i = tid * 4; i < 4096; i += 1024)
        *(float4*)&Ws[0][i] = *(const float4*)&W[i];
    // stage A tile (64 rows x 64 cols), pad stride 68
    for (int idx = tid; idx < 1024; idx += 256) {
        int r = idx >> 4, c4 = (idx & 15) << 2;
        int v = v0 + r;
        float4 val = make_float4(0.f, 0.f, 0.f, 0.f);
        if (v < N_NODES) val = *(const float4*)&A[(size_t)v * 64 + c4];
        *(float4*)&As[r][c4] = val;
    }
    __syncthreads();
    int ti = tid >> 4, tj = tid & 15;
    int i0 = ti << 2, j0 = tj << 2;
    float acc[4][4] = {{0.f}};
    for (int k4 = 0; k4 < 64; k4 += 4) {
        float a[4][4], w[4][4];
#pragma unroll
        for (int r = 0; r < 4; ++r) *(float4*)a[r] = *(float4*)&As[i0 + r][k4];
#pragma unroll
        for (int q = 0; q < 4; ++q) *(float4*)w[q] = *(float4*)&Ws[k4 + q][j0];
#pragma unroll
        for (int r = 0; r < 4; ++r)
#pragma unroll
            for (int c = 0; c < 4; ++c)
#pragma unroll
                for (int q = 0; q < 4; ++q)
                    acc[r][c] = fmaf(a[r][q], w[q][c], acc[r][c]);
    }
    float bb[4];
    *(float4*)bb = *(const float4*)&b[j0];
#pragma unroll
    for (int r = 0; r < 4; ++r) {
        int v = v0 + i0 + r;
        if (v < N_NODES) {
            float o[4];
#pragma unroll
            for (int c = 0; c < 4; ++c) {
                float m = acc[r][c] + bb[c];
                o[c] = relu ? fmaxf(m, 0.f) : m;
            }
            *(float4*)&out[(size_t)v * 64 + j0] = *(float4*)o;
        }
    }
}

// ---------------- row-norm sum: two-stage, no same-address atomics ----------------
__global__ __launch_bounds__(256) void k_norm(const float* __restrict__ h, float* __restrict__ partials) {
    int lane = threadIdx.x & 63;
    int wid = threadIdx.x >> 6;
    int gwave = blockIdx.x * 4 + wid;
    int nwaves = NORM_BLOCKS * 4;
    float acc = 0.f;
    for (int v = gwave; v < N_NODES; v += nwaves) {
        float x = h[(size_t)v * 64 + lane];
        float s = x * x;
#pragma unroll
        for (int off = 32; off > 0; off >>= 1) s += __shfl_xor(s, off, 64);
        if (lane == 0) acc += sqrtf(s);
    }
    __shared__ float part[4];
    if (lane == 0) part[wid] = acc;
    __syncthreads();
    if (threadIdx.x == 0) partials[blockIdx.x] = part[0] + part[1] + part[2] + part[3];
}

__global__ __launch_bounds__(256) void k_reduce_factor(const float* __restrict__ partials,
                                                       float* __restrict__ factor) {
    __shared__ float sd[256];
    int tid = threadIdx.x;
    float s = 0.f;
    for (int i = tid; i < NORM_BLOCKS; i += 256) s += partials[i];
    sd[tid] = s;
    __syncthreads();
    for (int off = 128; off > 0; off >>= 1) {
        if (tid < off) sd[tid] += sd[tid + off];
        __syncthreads();
    }
    if (tid == 0) factor[0] = 8.0f * (float)N_NODES / sd[0];
}

// ---------------- sum pooling over sorted graph_ids ----------------
#define POOL_CHUNK 32
__global__ __launch_bounds__(256) void k_pool(const float* __restrict__ h, const int* __restrict__ gid,
                                              const float* __restrict__ factor, float* __restrict__ out) {
    int wave = (blockIdx.x * 256 + threadIdx.x) >> 6;
    int lane = threadIdx.x & 63;
    int v0 = wave * POOL_CHUNK;
    if (v0 >= N_NODES) return;
    float f = factor[0];
    int vend = min(v0 + POOL_CHUNK, N_NODES);
    int gprev = gid[v0];
    float acc = 0.f;
    for (int v = v0; v < vend; ++v) {
        int g = gid[v];
        if (g != gprev) {
            atomicAdd(&out[(size_t)gprev * 64 + lane], acc);
            acc = 0.f;
            gprev = g;
        }
        acc = fmaf(h[(size_t)v * 64 + lane], f, acc);
    }
    atomicAdd(&out[(size_t)gprev * 64 + lane], acc);
}

extern "C" void kernel_launch(void* const* d_in, const int* in_sizes, int n_in,
                              void* d_out, int out_size, void* d_ws, size_t ws_size,
                              hipStream_t stream) {
    const float* h    = (const float*)d_in[0];
    const int*   esrc = (const int*)d_in[1];
    const int*   edst = (const int*)d_in[2];
    const int*   gids = (const int*)d_in[3];
    const float* W0 = (const float*)d_in[4];
    const float* b0 = (const float*)d_in[5];
    const float* W1 = (const float*)d_in[6];
    const float* b1 = (const float*)d_in[7];
    const float* W2 = (const float*)d_in[8];
    const float* b2 = (const float*)d_in[9];
    float* out = (float*)d_out;

    char* wsp = (char*)d_ws;
    size_t off = 0;
    auto alloc = [&](size_t bytes) -> void* {
        void* p = wsp + off;
        off += (bytes + 255) & ~(size_t)255;
        return p;
    };
    int*   deg_out = (int*)alloc((size_t)N_NODES * 4);
    int*   deg_in  = (int*)alloc((size_t)N_NODES * 4);
    float* odi     = (float*)alloc((size_t)N_NODES * 4);
    float* idi     = (float*)alloc((size_t)N_NODES * 4);
    int*   rowp    = (int*)alloc((size_t)N_NODES * 4);
    int*   cursor  = (int*)alloc((size_t)N_NODES * 4);
    int*   bsums   = (int*)alloc(512 * 4);
    float* partials= (float*)alloc(NORM_BLOCKS * 4);
    float* factor  = (float*)alloc(4);
    int*   col     = (int*)alloc((size_t)N_EDGES * 4);
    float* bufA    = (float*)alloc((size_t)N_NODES * 64 * 4);
    float* bufB    = (float*)alloc((size_t)N_NODES * 64 * 4);

    // zero the two degree arrays (contiguous region incl. padding) and d_out
    int zdeg = (int)(((char*)odi - (char*)deg_out) / 4);
    k_zero_i32<<<(zdeg + 255) / 256, 256, 0, stream>>>(deg_out, zdeg);
    k_zero_i32<<<(N_GRAPHS * 64 + 255) / 256, 256, 0, stream>>>((int*)out, N_GRAPHS * 64);

    // degrees + normalizers
    k_hist<<<(N_EDGES + 255) / 256, 256, 0, stream>>>(esrc, edst, deg_out, deg_in);
    k_deginv<<<(N_NODES + 255) / 256, 256, 0, stream>>>(deg_out, deg_in, odi, idi);

    // CSR by destination
    int nblk = (N_NODES + 255) / 256;  // 391
    k_bsum<<<nblk, 256, 0, stream>>>(deg_in, bsums);
    k_scan_bsums<<<1, 512, 0, stream>>>(bsums, nblk);
    k_scan_final<<<nblk, 256, 0, stream>>>(deg_in, bsums, rowp, cursor);
    k_scatter<<<(N_EDGES + 255) / 256, 256, 0, stream>>>(esrc, edst, cursor, col);

    int aggBlocks  = (N_NODES + 3) / 4;        // 1 wave per node, 4 waves/block
    int gemmBlocks = (N_NODES + 63) / 64;

    // layer 0
    k_agg<<<aggBlocks, 256, 0, stream>>>(h, rowp, cursor, col, odi, idi, bufA);
    k_gemm<<<gemmBlocks, 256, 0, stream>>>(bufA, W0, b0, bufB, 1);
    // layer 1
    k_agg<<<aggBlocks, 256, 0, stream>>>(bufB, rowp, cursor, col, odi, idi, bufA);
    k_gemm<<<gemmBlocks, 256, 0, stream>>>(bufA, W1, b1, bufB, 1);
    // layer 2
    k_agg<<<aggBlocks, 256, 0, stream>>>(bufB, rowp, cursor, col, odi, idi, bufA);
    k_gemm<<<gemmBlocks, 256, 0, stream>>>(bufA, W2, b2, bufB, 0);

    // factor + pooling
    k_norm<<<NORM_BLOCKS, 256, 0, stream>>>(bufB, partials);
    k_reduce_factor<<<1, 256, 0, stream>>>(partials, factor);
    int poolWaves  = (N_NODES + POOL_CHUNK - 1) / POOL_CHUNK;
    int poolBlocks = (poolWaves + 3) / 4;
    k_pool<<<poolBlocks, 256, 0, stream>>>(bufB, gids, factor, out);
}

// Round 3
// 587.815 us; speedup vs baseline: 1.7401x; 1.2218x over previous
//
#include <hip/hip_runtime.h>

#define N_NODES 100000
#define N_EDGES 1600000
#define N_GRAPHS 2000
#define HID 64

// ---------------- utility ----------------
__global__ __launch_bounds__(256) void k_zero_i32(int* __restrict__ p, int n) {
    int i = blockIdx.x * 256 + threadIdx.x;
    if (i < n) p[i] = 0;
}

// ---------------- degree histogram ----------------
__global__ __launch_bounds__(256) void k_hist(const int* __restrict__ src, const int* __restrict__ dst,
                                              int* __restrict__ outc, int* __restrict__ inc) {
    int e = blockIdx.x * 256 + threadIdx.x;
    if (e < N_EDGES) {
        atomicAdd(&outc[src[e]], 1);
        atomicAdd(&inc[dst[e]], 1);
    }
}

__global__ __launch_bounds__(256) void k_deginv(const int* __restrict__ outc, const int* __restrict__ inc,
                                                float* __restrict__ odi, float* __restrict__ idi) {
    int v = blockIdx.x * 256 + threadIdx.x;
    if (v < N_NODES) {
        odi[v] = rsqrtf((float)max(outc[v], 1));
        idi[v] = rsqrtf((float)max(inc[v], 1));
    }
}

// ---------------- exclusive scan (3-phase) ----------------
__global__ __launch_bounds__(256) void k_bsum(const int* __restrict__ cnt, int* __restrict__ bsums) {
    __shared__ int sd[256];
    int tid = threadIdx.x;
    int i = blockIdx.x * 256 + tid;
    sd[tid] = (i < N_NODES) ? cnt[i] : 0;
    __syncthreads();
    for (int s = 128; s > 0; s >>= 1) {
        if (tid < s) sd[tid] += sd[tid + s];
        __syncthreads();
    }
    if (tid == 0) bsums[blockIdx.x] = sd[0];
}

__global__ __launch_bounds__(512) void k_scan_bsums(int* __restrict__ bsums, int nb) {
    __shared__ int sd[512];
    int tid = threadIdx.x;
    int v = (tid < nb) ? bsums[tid] : 0;
    sd[tid] = v;
    __syncthreads();
    for (int off = 1; off < 512; off <<= 1) {
        int t = (tid >= off) ? sd[tid - off] : 0;
        __syncthreads();
        sd[tid] += t;
        __syncthreads();
    }
    if (tid < nb) bsums[tid] = sd[tid] - v;  // exclusive
}

__global__ __launch_bounds__(256) void k_scan_final(const int* __restrict__ cnt, const int* __restrict__ bsums,
                                                    int* __restrict__ rowp, int* __restrict__ cur) {
    __shared__ int sd[256];
    int tid = threadIdx.x;
    int i = blockIdx.x * 256 + tid;
    int v = (i < N_NODES) ? cnt[i] : 0;
    sd[tid] = v;
    __syncthreads();
    for (int off = 1; off < 256; off <<= 1) {
        int t = (tid >= off) ? sd[tid - off] : 0;
        __syncthreads();
        sd[tid] += t;
        __syncthreads();
    }
    if (i < N_NODES) {
        int excl = sd[tid] - v + bsums[blockIdx.x];
        rowp[i] = excl;
        cur[i] = excl;
    }
}

__global__ __launch_bounds__(256) void k_scatter(const int* __restrict__ src, const int* __restrict__ dst,
                                                 int* __restrict__ cur, int* __restrict__ col) {
    int e = blockIdx.x * 256 + threadIdx.x;
    if (e < N_EDGES) {
        int pos = atomicAdd(&cur[dst[e]], 1);
        col[pos] = src[e];
    }
}

// ---------------- fused layer: out[v] = act( (idi[v] * sum_{e:dst=v} odi[s]*x[s]) @ W + b ) -----
// One wave per node (lane = feature). 8-deep unrolled gather (independent chains),
// wave-uniform node id => scalar loads for rowp/cur/col/odi. GEMM via LDS round-trip:
// W staged in LDS per block; 64 broadcast-read x FMA per lane. NORM fuses row-norm partials.
template <int RELU, int NORM>
__global__ __launch_bounds__(256) void k_layer(const float* __restrict__ x, const int* __restrict__ rowp,
                                               const int* __restrict__ cur, const int* __restrict__ col,
                                               const float* __restrict__ odi, const float* __restrict__ idi,
                                               const float* __restrict__ W, const float* __restrict__ b,
                                               float* __restrict__ out, float* __restrict__ partials) {
    __shared__ float Ws[64 * 64];
    __shared__ float aggLds[4 * 64];
    __shared__ float part[4];
    int tid = threadIdx.x;
    // stage W (4096 floats)
    for (int i = tid * 4; i < 4096; i += 1024)
        *(float4*)&Ws[i] = *(const float4*)&W[i];
    __syncthreads();

    int lane = tid & 63;
    int wid = tid >> 6;
    int v = __builtin_amdgcn_readfirstlane(blockIdx.x * 4 + wid);  // wave-uniform node id
    int beg = rowp[v], end = cur[v];
    float a0 = 0.f, a1 = 0.f, a2 = 0.f, a3 = 0.f;
    int p = beg;
    for (; p + 8 <= end; p += 8) {
        int s0 = col[p + 0], s1 = col[p + 1], s2 = col[p + 2], s3 = col[p + 3];
        int s4 = col[p + 4], s5 = col[p + 5], s6 = col[p + 6], s7 = col[p + 7];
        float w0 = odi[s0], w1 = odi[s1], w2 = odi[s2], w3 = odi[s3];
        float w4 = odi[s4], w5 = odi[s5], w6 = odi[s6], w7 = odi[s7];
        a0 = fmaf(x[s0 * 64 + lane], w0, a0);
        a1 = fmaf(x[s1 * 64 + lane], w1, a1);
        a2 = fmaf(x[s2 * 64 + lane], w2, a2);
        a3 = fmaf(x[s3 * 64 + lane], w3, a3);
        a0 = fmaf(x[s4 * 64 + lane], w4, a0);
        a1 = fmaf(x[s5 * 64 + lane], w5, a1);
        a2 = fmaf(x[s6 * 64 + lane], w6, a2);
        a3 = fmaf(x[s7 * 64 + lane], w7, a3);
    }
    if (p < end) {  // masked octet tail (clamped index, zero weight for overrun slots)
#pragma unroll
        for (int k = 0; k < 8; ++k) {
            int q = (p + k < end) ? (p + k) : (end - 1);
            int s = col[q];
            float w = (p + k < end) ? odi[s] : 0.f;
            float xv = x[s * 64 + lane];
            if (k & 2) { if (k & 1) a3 = fmaf(xv, w, a3); else a2 = fmaf(xv, w, a2); }
            else       { if (k & 1) a1 = fmaf(xv, w, a1); else a0 = fmaf(xv, w, a0); }
        }
    }
    float a = ((a0 + a1) + (a2 + a3)) * idi[v];

    // GEMM: o[lane] = b[lane] + sum_k a[k] * W[k][lane]
    aggLds[wid * 64 + lane] = a;
    float o = b[lane];
#pragma unroll
    for (int k = 0; k < 64; ++k)
        o = fmaf(aggLds[wid * 64 + k], Ws[k * 64 + lane], o);
    if (RELU) o = fmaxf(o, 0.f);
    out[(size_t)v * 64 + lane] = o;

    if (NORM) {
        float s = o * o;
#pragma unroll
        for (int off = 32; off > 0; off >>= 1) s += __shfl_xor(s, off, 64);
        if (lane == 0) part[wid] = sqrtf(s);
        __syncthreads();
        if (tid == 0) partials[blockIdx.x] = part[0] + part[1] + part[2] + part[3];
    }
}

#define LAYER_BLOCKS (N_NODES / 4)  // 25000, exact

__global__ __launch_bounds__(256) void k_reduce_factor(const float* __restrict__ partials,
                                                       float* __restrict__ factor) {
    __shared__ float sd[256];
    int tid = threadIdx.x;
    float s = 0.f;
    for (int i = tid; i < LAYER_BLOCKS; i += 256) s += partials[i];
    sd[tid] = s;
    __syncthreads();
    for (int off = 128; off > 0; off >>= 1) {
        if (tid < off) sd[tid] += sd[tid + off];
        __syncthreads();
    }
    if (tid == 0) factor[0] = 8.0f * (float)N_NODES / sd[0];
}

// ---------------- sum pooling over sorted graph_ids ----------------
#define POOL_CHUNK 32
__global__ __launch_bounds__(256) void k_pool(const float* __restrict__ h, const int* __restrict__ gid,
                                              const float* __restrict__ factor, float* __restrict__ out) {
    int wave = (blockIdx.x * 256 + threadIdx.x) >> 6;
    int lane = threadIdx.x & 63;
    int v0 = wave * POOL_CHUNK;
    if (v0 >= N_NODES) return;
    float f = factor[0];
    int vend = min(v0 + POOL_CHUNK, N_NODES);
    int gprev = gid[v0];
    float acc = 0.f;
    for (int v = v0; v < vend; ++v) {
        int g = gid[v];
        if (g != gprev) {
            atomicAdd(&out[(size_t)gprev * 64 + lane], acc);
            acc = 0.f;
            gprev = g;
        }
        acc = fmaf(h[(size_t)v * 64 + lane], f, acc);
    }
    atomicAdd(&out[(size_t)gprev * 64 + lane], acc);
}

extern "C" void kernel_launch(void* const* d_in, const int* in_sizes, int n_in,
                              void* d_out, int out_size, void* d_ws, size_t ws_size,
                              hipStream_t stream) {
    const float* h    = (const float*)d_in[0];
    const int*   esrc = (const int*)d_in[1];
    const int*   edst = (const int*)d_in[2];
    const int*   gids = (const int*)d_in[3];
    const float* W0 = (const float*)d_in[4];
    const float* b0 = (const float*)d_in[5];
    const float* W1 = (const float*)d_in[6];
    const float* b1 = (const float*)d_in[7];
    const float* W2 = (const float*)d_in[8];
    const float* b2 = (const float*)d_in[9];
    float* out = (float*)d_out;

    char* wsp = (char*)d_ws;
    size_t off = 0;
    auto alloc = [&](size_t bytes) -> void* {
        void* p = wsp + off;
        off += (bytes + 255) & ~(size_t)255;
        return p;
    };
    int*   deg_out = (int*)alloc((size_t)N_NODES * 4);
    int*   deg_in  = (int*)alloc((size_t)N_NODES * 4);
    float* odi     = (float*)alloc((size_t)N_NODES * 4);
    float* idi     = (float*)alloc((size_t)N_NODES * 4);
    int*   rowp    = (int*)alloc((size_t)N_NODES * 4);
    int*   cursor  = (int*)alloc((size_t)N_NODES * 4);
    int*   bsums   = (int*)alloc(512 * 4);
    float* partials= (float*)alloc((size_t)LAYER_BLOCKS * 4);
    float* factor  = (float*)alloc(4);
    int*   col     = (int*)alloc((size_t)N_EDGES * 4);
    float* bufA    = (float*)alloc((size_t)N_NODES * 64 * 4);
    float* bufB    = (float*)alloc((size_t)N_NODES * 64 * 4);

    // zero the two degree arrays (contiguous region incl. padding) and d_out
    int zdeg = (int)(((char*)odi - (char*)deg_out) / 4);
    k_zero_i32<<<(zdeg + 255) / 256, 256, 0, stream>>>(deg_out, zdeg);
    k_zero_i32<<<(N_GRAPHS * 64 + 255) / 256, 256, 0, stream>>>((int*)out, N_GRAPHS * 64);

    // degrees + normalizers
    k_hist<<<(N_EDGES + 255) / 256, 256, 0, stream>>>(esrc, edst, deg_out, deg_in);
    k_deginv<<<(N_NODES + 255) / 256, 256, 0, stream>>>(deg_out, deg_in, odi, idi);

    // CSR by destination
    int nblk = (N_NODES + 255) / 256;  // 391
    k_bsum<<<nblk, 256, 0, stream>>>(deg_in, bsums);
    k_scan_bsums<<<1, 512, 0, stream>>>(bsums, nblk);
    k_scan_final<<<nblk, 256, 0, stream>>>(deg_in, bsums, rowp, cursor);
    k_scatter<<<(N_EDGES + 255) / 256, 256, 0, stream>>>(esrc, edst, cursor, col);

    // fused layers (agg + GEMM + bias + act [+ norm partials])
    k_layer<1, 0><<<LAYER_BLOCKS, 256, 0, stream>>>(h,    rowp, cursor, col, odi, idi, W0, b0, bufB, nullptr);
    k_layer<1, 0><<<LAYER_BLOCKS, 256, 0, stream>>>(bufB, rowp, cursor, col, odi, idi, W1, b1, bufA, nullptr);
    k_layer<0, 1><<<LAYER_BLOCKS, 256, 0, stream>>>(bufA, rowp, cursor, col, odi, idi, W2, b2, bufB, partials);

    // factor + pooling
    k_reduce_factor<<<1, 256, 0, stream>>>(partials, factor);
    int poolWaves  = (N_NODES + POOL_CHUNK - 1) / POOL_CHUNK;
    int poolBlocks = (poolWaves + 3) / 4;
    k_pool<<<poolBlocks, 256, 0, stream>>>(bufB, gids, factor, out);
}

// Round 4
// 456.405 us; speedup vs baseline: 2.2411x; 1.2879x over previous
//
#include <hip/hip_runtime.h>

#define N_NODES 100000
#define N_EDGES 1600000
#define N_GRAPHS 2000
#define HID 64
#define NB 391        // buckets of 256 dst nodes: (N_NODES+255)/256
#define CH 4096       // edges per partition chunk

// ---------------- utility ----------------
__global__ __launch_bounds__(256) void k_zero_i32(int* __restrict__ p, int n) {
    int i = blockIdx.x * 256 + threadIdx.x;
    if (i < n) p[i] = 0;
}

// ---------------- out-degree histogram + bucket counts (one read of src+dst) ----------------
__global__ __launch_bounds__(256) void k_hist_fused(const int* __restrict__ src, const int* __restrict__ dst,
                                                    int* __restrict__ outc, int* __restrict__ bucket_cnt) {
    __shared__ int bc[NB];
    int tid = threadIdx.x;
    for (int i = tid; i < NB; i += 256) bc[i] = 0;
    __syncthreads();
    for (int e = blockIdx.x * 256 + tid; e < N_EDGES; e += gridDim.x * 256) {
        atomicAdd(&outc[src[e]], 1);
        atomicAdd(&bc[dst[e] >> 8], 1);
    }
    __syncthreads();
    for (int i = tid; i < NB; i += 256)
        if (bc[i]) atomicAdd(&bucket_cnt[i], bc[i]);
}

__global__ __launch_bounds__(256) void k_odi(const int* __restrict__ outc, float* __restrict__ odi) {
    int v = blockIdx.x * 256 + threadIdx.x;
    if (v < N_NODES) odi[v] = rsqrtf((float)max(outc[v], 1));
}

// ---------------- scan bucket counts -> bucket_base; zero gcursor ----------------
__global__ __launch_bounds__(512) void k_scan_buckets(const int* __restrict__ bucket_cnt,
                                                      int* __restrict__ bucket_base,
                                                      int* __restrict__ gcursor) {
    __shared__ int sd[512];
    int tid = threadIdx.x;
    int v = (tid < NB) ? bucket_cnt[tid] : 0;
    sd[tid] = v;
    __syncthreads();
    for (int off = 1; off < 512; off <<= 1) {
        int t = (tid >= off) ? sd[tid - off] : 0;
        __syncthreads();
        sd[tid] += t;
        __syncthreads();
    }
    if (tid < NB) {
        bucket_base[tid] = sd[tid] - v;  // exclusive
        gcursor[tid] = 0;
    }
    if (tid == 0) bucket_base[NB] = sd[NB - 1];
}

// ---------------- pass 1: partition edges into dst-buckets (staged, coalesced flush) ----------
// entry u32 = (src << 8) | (dst & 255)
__global__ __launch_bounds__(256) void k_partition(const int* __restrict__ src, const int* __restrict__ dst,
                                                   const int* __restrict__ bucket_base,
                                                   int* __restrict__ gcursor, unsigned* __restrict__ part) {
    __shared__ unsigned stage[CH];
    __shared__ int lcnt[NB];
    __shared__ int lexcl[NB];
    __shared__ int lofs[NB];
    __shared__ int runbase[NB];
    __shared__ int scanbuf[512];
    int tid = threadIdx.x;
    for (int chunk = blockIdx.x; chunk * CH < N_EDGES; chunk += gridDim.x) {
        int e0 = chunk * CH;
        int n = min(CH, N_EDGES - e0);
        for (int i = tid; i < NB; i += 256) lcnt[i] = 0;
        __syncthreads();
        unsigned ent[16];
        short bb[16];
#pragma unroll
        for (int k = 0; k < 16; ++k) {
            int i = k * 256 + tid;
            if (i < n) {
                int d = dst[e0 + i];
                int s = src[e0 + i];
                int b = d >> 8;
                ent[k] = ((unsigned)s << 8) | (unsigned)(d & 255);
                bb[k] = (short)b;
                atomicAdd(&lcnt[b], 1);
            } else bb[k] = -1;
        }
        __syncthreads();
        // inclusive Hillis-Steele over 512 (2 slots/thread) -> exclusive lexcl
        for (int s = tid; s < 512; s += 256) scanbuf[s] = (s < NB) ? lcnt[s] : 0;
        __syncthreads();
        for (int off = 1; off < 512; off <<= 1) {
            int i0 = tid, i1 = tid + 256;
            int v0 = scanbuf[i0] + ((i0 >= off) ? scanbuf[i0 - off] : 0);
            int v1 = scanbuf[i1] + ((i1 >= off) ? scanbuf[i1 - off] : 0);
            __syncthreads();
            scanbuf[i0] = v0;
            scanbuf[i1] = v1;
            __syncthreads();
        }
        for (int i = tid; i < NB; i += 256) {
            int ex = scanbuf[i] - lcnt[i];
            lexcl[i] = ex;
            lofs[i] = ex;
        }
        __syncthreads();
        // place into stage (local bucket-sorted order)
#pragma unroll
        for (int k = 0; k < 16; ++k) {
            if (bb[k] >= 0) {
                int p = atomicAdd(&lofs[bb[k]], 1);
                stage[p] = ent[k];
            }
        }
        // reserve per-bucket runs
        __syncthreads();
        for (int b = tid; b < NB; b += 256)
            if (lcnt[b]) runbase[b] = atomicAdd(&gcursor[b], lcnt[b]);
        __syncthreads();
        // coalesced flush: find bucket of slot i by binary search in lexcl
        for (int i = tid; i < n; i += 256) {
            int lo = 0, hi = NB - 1;
            while (lo < hi) {
                int mid = (lo + hi + 1) >> 1;
                if (lexcl[mid] <= i) lo = mid; else hi = mid - 1;
            }
            part[bucket_base[lo] + runbase[lo] + (i - lexcl[lo])] = stage[i];
        }
        __syncthreads();
    }
}

// ---------------- pass 2: per-bucket CSR (col, rowbeg, rowend, idi) ----------------
__global__ __launch_bounds__(256) void k_csr(const unsigned* __restrict__ part,
                                             const int* __restrict__ bucket_base,
                                             int* __restrict__ rowbeg, int* __restrict__ rowend,
                                             float* __restrict__ idi, int* __restrict__ col) {
    __shared__ int cnt[256];
    __shared__ int cur[256];
    __shared__ int wsum[4];
    int b = blockIdx.x;
    int tid = threadIdx.x;
    int base = bucket_base[b], lim = bucket_base[b + 1];
    int nE = lim - base;
    cnt[tid] = 0;
    __syncthreads();
    for (int i = tid; i < nE; i += 256) atomicAdd(&cnt[part[base + i] & 255], 1);
    __syncthreads();
    // exclusive scan of cnt[256] via wave shfl + cross-wave LDS
    int c = cnt[tid];
    int incl = c;
#pragma unroll
    for (int off = 1; off < 64; off <<= 1) {
        int t = __shfl_up(incl, off, 64);
        if ((tid & 63) >= off) incl += t;
    }
    if ((tid & 63) == 63) wsum[tid >> 6] = incl;
    __syncthreads();
    int add = 0;
    for (int w = 0; w < (tid >> 6); ++w) add += wsum[w];
    incl += add;
    int excl = incl - c;
    int v = b * 256 + tid;
    if (v < N_NODES) {
        rowbeg[v] = base + excl;
        rowend[v] = base + incl;
        idi[v] = rsqrtf((float)max(c, 1));
    }
    cur[tid] = excl;
    __syncthreads();
    for (int i = tid; i < nE; i += 256) {
        unsigned e = part[base + i];
        int p = atomicAdd(&cur[e & 255], 1);
        col[base + p] = (int)(e >> 8);
    }
}

// ---------------- fused layer: out[v] = act( (idi[v] * sum odi[s]*x[s]) @ W + b ) ----------
template <int RELU, int NORM>
__global__ __launch_bounds__(256) void k_layer(const float* __restrict__ x, const int* __restrict__ rowbeg,
                                               const int* __restrict__ rowend, const int* __restrict__ col,
                                               const float* __restrict__ odi, const float* __restrict__ idi,
                                               const float* __restrict__ W, const float* __restrict__ b,
                                               float* __restrict__ out, float* __restrict__ partials) {
    __shared__ float Ws[64 * 64];
    __shared__ float aggLds[4 * 64];
    __shared__ float part[4];
    int tid = threadIdx.x;
    for (int i = tid * 4; i < 4096; i += 1024)
        *(float4*)&Ws[i] = *(const float4*)&W[i];
    __syncthreads();

    int lane = tid & 63;
    int wid = tid >> 6;
    int v = __builtin_amdgcn_readfirstlane(blockIdx.x * 4 + wid);
    int beg = rowbeg[v], end = rowend[v];
    float a0 = 0.f, a1 = 0.f, a2 = 0.f, a3 = 0.f;
    int p = beg;
    for (; p + 8 <= end; p += 8) {
        int s0 = col[p + 0], s1 = col[p + 1], s2 = col[p + 2], s3 = col[p + 3];
        int s4 = col[p + 4], s5 = col[p + 5], s6 = col[p + 6], s7 = col[p + 7];
        float w0 = odi[s0], w1 = odi[s1], w2 = odi[s2], w3 = odi[s3];
        float w4 = odi[s4], w5 = odi[s5], w6 = odi[s6], w7 = odi[s7];
        a0 = fmaf(x[s0 * 64 + lane], w0, a0);
        a1 = fmaf(x[s1 * 64 + lane], w1, a1);
        a2 = fmaf(x[s2 * 64 + lane], w2, a2);
        a3 = fmaf(x[s3 * 64 + lane], w3, a3);
        a0 = fmaf(x[s4 * 64 + lane], w4, a0);
        a1 = fmaf(x[s5 * 64 + lane], w5, a1);
        a2 = fmaf(x[s6 * 64 + lane], w6, a2);
        a3 = fmaf(x[s7 * 64 + lane], w7, a3);
    }
    if (p < end) {
#pragma unroll
        for (int k = 0; k < 8; ++k) {
            int q = (p + k < end) ? (p + k) : (end - 1);
            int s = col[q];
            float w = (p + k < end) ? odi[s] : 0.f;
            float xv = x[s * 64 + lane];
            if (k & 2) { if (k & 1) a3 = fmaf(xv, w, a3); else a2 = fmaf(xv, w, a2); }
            else       { if (k & 1) a1 = fmaf(xv, w, a1); else a0 = fmaf(xv, w, a0); }
        }
    }
    float a = ((a0 + a1) + (a2 + a3)) * idi[v];

    aggLds[wid * 64 + lane] = a;
    float o = b[lane];
#pragma unroll
    for (int k = 0; k < 64; ++k)
        o = fmaf(aggLds[wid * 64 + k], Ws[k * 64 + lane], o);
    if (RELU) o = fmaxf(o, 0.f);
    out[(size_t)v * 64 + lane] = o;

    if (NORM) {
        float s = o * o;
#pragma unroll
        for (int off = 32; off > 0; off >>= 1) s += __shfl_xor(s, off, 64);
        if (lane == 0) part[wid] = sqrtf(s);
        __syncthreads();
        if (tid == 0) partials[blockIdx.x] = part[0] + part[1] + part[2] + part[3];
    }
}

#define LAYER_BLOCKS (N_NODES / 4)  // 25000, exact

__global__ __launch_bounds__(256) void k_reduce_factor(const float* __restrict__ partials,
                                                       float* __restrict__ factor) {
    __shared__ float sd[256];
    int tid = threadIdx.x;
    float s = 0.f;
    for (int i = tid; i < LAYER_BLOCKS; i += 256) s += partials[i];
    sd[tid] = s;
    __syncthreads();
    for (int off = 128; off > 0; off >>= 1) {
        if (tid < off) sd[tid] += sd[tid + off];
        __syncthreads();
    }
    if (tid == 0) factor[0] = 8.0f * (float)N_NODES / sd[0];
}

// ---------------- sum pooling over sorted graph_ids ----------------
#define POOL_CHUNK 32
__global__ __launch_bounds__(256) void k_pool(const float* __restrict__ h, const int* __restrict__ gid,
                                              const float* __restrict__ factor, float* __restrict__ out) {
    int wave = (blockIdx.x * 256 + threadIdx.x) >> 6;
    int lane = threadIdx.x & 63;
    int v0 = wave * POOL_CHUNK;
    if (v0 >= N_NODES) return;
    float f = factor[0];
    int vend = min(v0 + POOL_CHUNK, N_NODES);
    int gprev = gid[v0];
    float acc = 0.f;
    for (int v = v0; v < vend; ++v) {
        int g = gid[v];
        if (g != gprev) {
            atomicAdd(&out[(size_t)gprev * 64 + lane], acc);
            acc = 0.f;
            gprev = g;
        }
        acc = fmaf(h[(size_t)v * 64 + lane], f, acc);
    }
    atomicAdd(&out[(size_t)gprev * 64 + lane], acc);
}

extern "C" void kernel_launch(void* const* d_in, const int* in_sizes, int n_in,
                              void* d_out, int out_size, void* d_ws, size_t ws_size,
                              hipStream_t stream) {
    const float* h    = (const float*)d_in[0];
    const int*   esrc = (const int*)d_in[1];
    const int*   edst = (const int*)d_in[2];
    const int*   gids = (const int*)d_in[3];
    const float* W0 = (const float*)d_in[4];
    const float* b0 = (const float*)d_in[5];
    const float* W1 = (const float*)d_in[6];
    const float* b1 = (const float*)d_in[7];
    const float* W2 = (const float*)d_in[8];
    const float* b2 = (const float*)d_in[9];
    float* out = (float*)d_out;

    char* wsp = (char*)d_ws;
    size_t off = 0;
    auto alloc = [&](size_t bytes) -> void* {
        void* p = wsp + off;
        off += (bytes + 255) & ~(size_t)255;
        return p;
    };
    int*   outc       = (int*)alloc((size_t)N_NODES * 4);
    int*   bucket_cnt = (int*)alloc((size_t)NB * 4);
    int*   bucket_base= (int*)alloc((size_t)(NB + 1) * 4);
    int*   gcursor    = (int*)alloc((size_t)NB * 4);
    float* odi        = (float*)alloc((size_t)N_NODES * 4);
    float* idi        = (float*)alloc((size_t)N_NODES * 4);
    int*   rowbeg     = (int*)alloc((size_t)N_NODES * 4);
    int*   rowend     = (int*)alloc((size_t)N_NODES * 4);
    float* partials   = (float*)alloc((size_t)LAYER_BLOCKS * 4);
    float* factor     = (float*)alloc(4);
    int*   col        = (int*)alloc((size_t)N_EDGES * 4);
    float* bufA       = (float*)alloc((size_t)N_NODES * 64 * 4);
    float* bufB       = (float*)alloc((size_t)N_NODES * 64 * 4);
    unsigned* partbuf = (unsigned*)bufA;  // alias: dead until layer-1 output

    // zero outc..bucket_cnt (contiguous incl. padding) and d_out
    int zc = (int)(((char*)bucket_base - (char*)outc) / 4);
    k_zero_i32<<<(zc + 255) / 256, 256, 0, stream>>>(outc, zc);
    k_zero_i32<<<(N_GRAPHS * 64 + 255) / 256, 256, 0, stream>>>((int*)out, N_GRAPHS * 64);

    // degrees + buckets
    k_hist_fused<<<512, 256, 0, stream>>>(esrc, edst, outc, bucket_cnt);
    k_odi<<<(N_NODES + 255) / 256, 256, 0, stream>>>(outc, odi);
    k_scan_buckets<<<1, 512, 0, stream>>>(bucket_cnt, bucket_base, gcursor);

    // CSR by destination (bucketed, 2-pass)
    int nchunks = (N_EDGES + CH - 1) / CH;  // 391
    k_partition<<<nchunks, 256, 0, stream>>>(esrc, edst, bucket_base, gcursor, partbuf);
    k_csr<<<NB, 256, 0, stream>>>(partbuf, bucket_base, rowbeg, rowend, idi, col);

    // fused layers (agg + GEMM + bias + act [+ norm partials])
    k_layer<1, 0><<<LAYER_BLOCKS, 256, 0, stream>>>(h,    rowbeg, rowend, col, odi, idi, W0, b0, bufB, nullptr);
    k_layer<1, 0><<<LAYER_BLOCKS, 256, 0, stream>>>(bufB, rowbeg, rowend, col, odi, idi, W1, b1, bufA, nullptr);
    k_layer<0, 1><<<LAYER_BLOCKS, 256, 0, stream>>>(bufA, rowbeg, rowend, col, odi, idi, W2, b2, bufB, partials);

    // factor + pooling
    k_reduce_factor<<<1, 256, 0, stream>>>(partials, factor);
    int poolWaves  = (N_NODES + POOL_CHUNK - 1) / POOL_CHUNK;
    int poolBlocks = (poolWaves + 3) / 4;
    k_pool<<<poolBlocks, 256, 0, stream>>>(bufB, gids, factor, out);
}

// Round 5
// 355.327 us; speedup vs baseline: 2.8786x; 1.2845x over previous
//
#include <hip/hip_runtime.h>
#include <hip/hip_fp16.h>

#define N_NODES 100000
#define N_EDGES 1600000
#define N_GRAPHS 2000
#define HID 64
#define NB 391        // buckets of 256 dst nodes: (N_NODES+255)/256
#define CH 4096       // edges per partition chunk
#define LAYER_GRID 2048
#define N_GROUPS (N_NODES / 4)  // 25000

// ---------------- utility ----------------
__global__ __launch_bounds__(256) void k_zero_i32(int* __restrict__ p, int n) {
    int i = blockIdx.x * 256 + threadIdx.x;
    if (i < n) p[i] = 0;
}

// ---------------- out-degree histogram + bucket counts (one read of src+dst) ----------------
__global__ __launch_bounds__(256) void k_hist_fused(const int* __restrict__ src, const int* __restrict__ dst,
                                                    int* __restrict__ outc, int* __restrict__ bucket_cnt) {
    __shared__ int bc[NB];
    int tid = threadIdx.x;
    for (int i = tid; i < NB; i += 256) bc[i] = 0;
    __syncthreads();
    for (int e = blockIdx.x * 256 + tid; e < N_EDGES; e += gridDim.x * 256) {
        atomicAdd(&outc[src[e]], 1);
        atomicAdd(&bc[dst[e] >> 8], 1);
    }
    __syncthreads();
    for (int i = tid; i < NB; i += 256)
        if (bc[i]) atomicAdd(&bucket_cnt[i], bc[i]);
}

__global__ __launch_bounds__(256) void k_odi(const int* __restrict__ outc, float* __restrict__ odi) {
    int v = blockIdx.x * 256 + threadIdx.x;
    if (v < N_NODES) odi[v] = rsqrtf((float)max(outc[v], 1));
}

// ---------------- prescale: xs[v][f] = h[v][f] * odi[v]  (fp16) ----------------
__global__ __launch_bounds__(256) void k_prescale(const float* __restrict__ h, const float* __restrict__ odi,
                                                  __half* __restrict__ xs) {
    int t4 = blockIdx.x * 256 + threadIdx.x;           // one float4 per thread
    if (t4 >= N_NODES * 16) return;
    int v = t4 >> 4;
    int f0 = (t4 & 15) << 2;
    float4 f = *(const float4*)&h[(size_t)v * 64 + f0];
    float w = odi[v];
    __half2 p0 = __floats2half2_rn(f.x * w, f.y * w);
    __half2 p1 = __floats2half2_rn(f.z * w, f.w * w);
    uint2 st;
    st.x = *(unsigned*)&p0;
    st.y = *(unsigned*)&p1;
    *(uint2*)&xs[(size_t)v * 64 + f0] = st;
}

// ---------------- scan bucket counts -> bucket_base; zero gcursor ----------------
__global__ __launch_bounds__(512) void k_scan_buckets(const int* __restrict__ bucket_cnt,
                                                      int* __restrict__ bucket_base,
                                                      int* __restrict__ gcursor) {
    __shared__ int sd[512];
    int tid = threadIdx.x;
    int v = (tid < NB) ? bucket_cnt[tid] : 0;
    sd[tid] = v;
    __syncthreads();
    for (int off = 1; off < 512; off <<= 1) {
        int t = (tid >= off) ? sd[tid - off] : 0;
        __syncthreads();
        sd[tid] += t;
        __syncthreads();
    }
    if (tid < NB) {
        bucket_base[tid] = sd[tid] - v;  // exclusive
        gcursor[tid] = 0;
    }
    if (tid == 0) bucket_base[NB] = sd[NB - 1];
}

// ---------------- pass 1: partition edges into dst-buckets (staged, coalesced flush) ----------
// entry u32 = (src << 8) | (dst & 255)
__global__ __launch_bounds__(256) void k_partition(const int* __restrict__ src, const int* __restrict__ dst,
                                                   const int* __restrict__ bucket_base,
                                                   int* __restrict__ gcursor, unsigned* __restrict__ part) {
    __shared__ unsigned stage[CH];
    __shared__ int lcnt[NB];
    __shared__ int lexcl[NB];
    __shared__ int lofs[NB];
    __shared__ int runbase[NB];
    __shared__ int scanbuf[512];
    int tid = threadIdx.x;
    for (int chunk = blockIdx.x; chunk * CH < N_EDGES; chunk += gridDim.x) {
        int e0 = chunk * CH;
        int n = min(CH, N_EDGES - e0);
        for (int i = tid; i < NB; i += 256) lcnt[i] = 0;
        __syncthreads();
        unsigned ent[16];
        short bb[16];
#pragma unroll
        for (int k = 0; k < 16; ++k) {
            int i = k * 256 + tid;
            if (i < n) {
                int d = dst[e0 + i];
                int s = src[e0 + i];
                int b = d >> 8;
                ent[k] = ((unsigned)s << 8) | (unsigned)(d & 255);
                bb[k] = (short)b;
                atomicAdd(&lcnt[b], 1);
            } else bb[k] = -1;
        }
        __syncthreads();
        for (int s = tid; s < 512; s += 256) scanbuf[s] = (s < NB) ? lcnt[s] : 0;
        __syncthreads();
        for (int off = 1; off < 512; off <<= 1) {
            int i0 = tid, i1 = tid + 256;
            int v0 = scanbuf[i0] + ((i0 >= off) ? scanbuf[i0 - off] : 0);
            int v1 = scanbuf[i1] + ((i1 >= off) ? scanbuf[i1 - off] : 0);
            __syncthreads();
            scanbuf[i0] = v0;
            scanbuf[i1] = v1;
            __syncthreads();
        }
        for (int i = tid; i < NB; i += 256) {
            int ex = scanbuf[i] - lcnt[i];
            lexcl[i] = ex;
            lofs[i] = ex;
        }
        __syncthreads();
#pragma unroll
        for (int k = 0; k < 16; ++k) {
            if (bb[k] >= 0) {
                int p = atomicAdd(&lofs[bb[k]], 1);
                stage[p] = ent[k];
            }
        }
        __syncthreads();
        for (int b = tid; b < NB; b += 256)
            if (lcnt[b]) runbase[b] = atomicAdd(&gcursor[b], lcnt[b]);
        __syncthreads();
        for (int i = tid; i < n; i += 256) {
            int lo = 0, hi = NB - 1;
            while (lo < hi) {
                int mid = (lo + hi + 1) >> 1;
                if (lexcl[mid] <= i) lo = mid; else hi = mid - 1;
            }
            part[bucket_base[lo] + runbase[lo] + (i - lexcl[lo])] = stage[i];
        }
        __syncthreads();
    }
}

// ---------------- pass 2: per-bucket CSR (col, rowbeg, rowend, idi) ----------------
__global__ __launch_bounds__(256) void k_csr(const unsigned* __restrict__ part,
                                             const int* __restrict__ bucket_base,
                                             int* __restrict__ rowbeg, int* __restrict__ rowend,
                                             float* __restrict__ idi, int* __restrict__ col) {
    __shared__ int cnt[256];
    __shared__ int cur[256];
    __shared__ int wsum[4];
    int b = blockIdx.x;
    int tid = threadIdx.x;
    int base = bucket_base[b], lim = bucket_base[b + 1];
    int nE = lim - base;
    cnt[tid] = 0;
    __syncthreads();
    for (int i = tid; i < nE; i += 256) atomicAdd(&cnt[part[base + i] & 255], 1);
    __syncthreads();
    int c = cnt[tid];
    int incl = c;
#pragma unroll
    for (int off = 1; off < 64; off <<= 1) {
        int t = __shfl_up(incl, off, 64);
        if ((tid & 63) >= off) incl += t;
    }
    if ((tid & 63) == 63) wsum[tid >> 6] = incl;
    __syncthreads();
    int add = 0;
    for (int w = 0; w < (tid >> 6); ++w) add += wsum[w];
    incl += add;
    int excl = incl - c;
    int v = b * 256 + tid;
    if (v < N_NODES) {
        rowbeg[v] = base + excl;
        rowend[v] = base + incl;
        idi[v] = rsqrtf((float)max(c, 1));
    }
    cur[tid] = excl;
    __syncthreads();
    for (int i = tid; i < nE; i += 256) {
        unsigned e = part[base + i];
        int p = atomicAdd(&cur[e & 255], 1);
        col[base + p] = (int)(e >> 8);
    }
}

// ---------------- fused layer over pre-scaled fp16 rows ----------------
// agg[v] = idi[v] * sum_{e:dst=v} xs[src]   (xs already carries odi[src])
// o = act(agg @ W + b); layers 0,1: write xs_out = o*odi (fp16); last: write f32 + norm partials
template <int RELU, int LAST>
__global__ __launch_bounds__(256) void k_layer(const __half* __restrict__ xs, const int* __restrict__ rowbeg,
                                               const int* __restrict__ rowend, const int* __restrict__ col,
                                               const float* __restrict__ odi, const float* __restrict__ idi,
                                               const float* __restrict__ W, const float* __restrict__ b,
                                               __half* __restrict__ xs_out, float* __restrict__ out_f32,
                                               float* __restrict__ partials) {
    __shared__ float Ws[64 * 64];
    __shared__ float aggLds[4 * 64];
    __shared__ float part[4];
    int tid = threadIdx.x;
    for (int i = tid * 4; i < 4096; i += 1024)
        *(float4*)&Ws[i] = *(const float4*)&W[i];
    __syncthreads();

    int lane = tid & 63;
    int wid = tid >> 6;
    float bias = b[lane];
    float nacc = 0.f;

    for (int g = blockIdx.x; g < N_GROUPS; g += LAYER_GRID) {
        int v = __builtin_amdgcn_readfirstlane(g * 4 + wid);
        int beg = rowbeg[v], end = rowend[v];
        float a0 = 0.f, a1 = 0.f, a2 = 0.f, a3 = 0.f;
        int p = beg;
        for (; p + 8 <= end; p += 8) {
            int s0 = col[p + 0], s1 = col[p + 1], s2 = col[p + 2], s3 = col[p + 3];
            int s4 = col[p + 4], s5 = col[p + 5], s6 = col[p + 6], s7 = col[p + 7];
            a0 += __half2float(xs[s0 * 64 + lane]);
            a1 += __half2float(xs[s1 * 64 + lane]);
            a2 += __half2float(xs[s2 * 64 + lane]);
            a3 += __half2float(xs[s3 * 64 + lane]);
            a0 += __half2float(xs[s4 * 64 + lane]);
            a1 += __half2float(xs[s5 * 64 + lane]);
            a2 += __half2float(xs[s6 * 64 + lane]);
            a3 += __half2float(xs[s7 * 64 + lane]);
        }
        if (p < end) {  // masked octet tail (clamped index, wave-uniform select)
#pragma unroll
            for (int k = 0; k < 8; ++k) {
                int q = (p + k < end) ? (p + k) : (end - 1);
                float xv = __half2float(xs[col[q] * 64 + lane]);
                xv = (p + k < end) ? xv : 0.f;
                if (k & 2) { if (k & 1) a3 += xv; else a2 += xv; }
                else       { if (k & 1) a1 += xv; else a0 += xv; }
            }
        }
        float a = ((a0 + a1) + (a2 + a3)) * idi[v];

        aggLds[wid * 64 + lane] = a;  // wave-local round-trip (no barrier needed)
        float o = bias;
#pragma unroll
        for (int k = 0; k < 64; ++k)
            o = fmaf(aggLds[wid * 64 + k], Ws[k * 64 + lane], o);
        if (RELU) o = fmaxf(o, 0.f);

        if (LAST) {
            out_f32[(size_t)v * 64 + lane] = o;
            float s = o * o;
#pragma unroll
            for (int off = 32; off > 0; off >>= 1) s += __shfl_xor(s, off, 64);
            if (lane == 0) nacc += sqrtf(s);
        } else {
            xs_out[(size_t)v * 64 + lane] = __float2half_rn(o * odi[v]);
        }
    }

    if (LAST) {
        if (lane == 0) part[wid] = nacc;
        __syncthreads();
        if (tid == 0) partials[blockIdx.x] = part[0] + part[1] + part[2] + part[3];
    }
}

__global__ __launch_bounds__(256) void k_reduce_factor(const float* __restrict__ partials,
                                                       float* __restrict__ factor) {
    __shared__ float sd[256];
    int tid = threadIdx.x;
    float s = 0.f;
    for (int i = tid; i < LAYER_GRID; i += 256) s += partials[i];
    sd[tid] = s;
    __syncthreads();
    for (int off = 128; off > 0; off >>= 1) {
        if (tid < off) sd[tid] += sd[tid + off];
        __syncthreads();
    }
    if (tid == 0) factor[0] = 8.0f * (float)N_NODES / sd[0];
}

// ---------------- sum pooling over sorted graph_ids ----------------
#define POOL_CHUNK 32
__global__ __launch_bounds__(256) void k_pool(const float* __restrict__ h, const int* __restrict__ gid,
                                              const float* __restrict__ factor, float* __restrict__ out) {
    int wave = (blockIdx.x * 256 + threadIdx.x) >> 6;
    int lane = threadIdx.x & 63;
    int v0 = wave * POOL_CHUNK;
    if (v0 >= N_NODES) return;
    float f = factor[0];
    int vend = min(v0 + POOL_CHUNK, N_NODES);
    int gprev = gid[v0];
    float acc = 0.f;
    for (int v = v0; v < vend; ++v) {
        int g = gid[v];
        if (g != gprev) {
            atomicAdd(&out[(size_t)gprev * 64 + lane], acc);
            acc = 0.f;
            gprev = g;
        }
        acc = fmaf(h[(size_t)v * 64 + lane], f, acc);
    }
    atomicAdd(&out[(size_t)gprev * 64 + lane], acc);
}

extern "C" void kernel_launch(void* const* d_in, const int* in_sizes, int n_in,
                              void* d_out, int out_size, void* d_ws, size_t ws_size,
                              hipStream_t stream) {
    const float* h    = (const float*)d_in[0];
    const int*   esrc = (const int*)d_in[1];
    const int*   edst = (const int*)d_in[2];
    const int*   gids = (const int*)d_in[3];
    const float* W0 = (const float*)d_in[4];
    const float* b0 = (const float*)d_in[5];
    const float* W1 = (const float*)d_in[6];
    const float* b1 = (const float*)d_in[7];
    const float* W2 = (const float*)d_in[8];
    const float* b2 = (const float*)d_in[9];
    float* out = (float*)d_out;

    char* wsp = (char*)d_ws;
    size_t off = 0;
    auto alloc = [&](size_t bytes) -> void* {
        void* p = wsp + off;
        off += (bytes + 255) & ~(size_t)255;
        return p;
    };
    int*   outc       = (int*)alloc((size_t)N_NODES * 4);
    int*   bucket_cnt = (int*)alloc((size_t)NB * 4);
    int*   bucket_base= (int*)alloc((size_t)(NB + 1) * 4);
    int*   gcursor    = (int*)alloc((size_t)NB * 4);
    float* odi        = (float*)alloc((size_t)N_NODES * 4);
    float* idi        = (float*)alloc((size_t)N_NODES * 4);
    int*   rowbeg     = (int*)alloc((size_t)N_NODES * 4);
    int*   rowend     = (int*)alloc((size_t)N_NODES * 4);
    float* partials   = (float*)alloc((size_t)LAYER_GRID * 4);
    float* factor     = (float*)alloc(4);
    int*   col        = (int*)alloc((size_t)N_EDGES * 4);
    __half* hsA       = (__half*)alloc((size_t)N_NODES * 64 * 2);
    __half* hsB       = (__half*)alloc((size_t)N_NODES * 64 * 2);
    float* outF       = (float*)alloc((size_t)N_NODES * 64 * 4);
    unsigned* partbuf = (unsigned*)outF;  // alias: dead until layer-2 output

    // zero outc..bucket_cnt (contiguous incl. padding) and d_out
    int zc = (int)(((char*)bucket_base - (char*)outc) / 4);
    k_zero_i32<<<(zc + 255) / 256, 256, 0, stream>>>(outc, zc);
    k_zero_i32<<<(N_GRAPHS * 64 + 255) / 256, 256, 0, stream>>>((int*)out, N_GRAPHS * 64);

    // degrees + buckets
    k_hist_fused<<<512, 256, 0, stream>>>(esrc, edst, outc, bucket_cnt);
    k_odi<<<(N_NODES + 255) / 256, 256, 0, stream>>>(outc, odi);
    k_prescale<<<(N_NODES * 16 + 255) / 256, 256, 0, stream>>>(h, odi, hsA);
    k_scan_buckets<<<1, 512, 0, stream>>>(bucket_cnt, bucket_base, gcursor);

    // CSR by destination (bucketed, 2-pass)
    int nchunks = (N_EDGES + CH - 1) / CH;  // 391
    k_partition<<<nchunks, 256, 0, stream>>>(esrc, edst, bucket_base, gcursor, partbuf);
    k_csr<<<NB, 256, 0, stream>>>(partbuf, bucket_base, rowbeg, rowend, idi, col);

    // fused layers (agg + GEMM + bias + act; fp16 pre-scaled gather buffers)
    k_layer<1, 0><<<LAYER_GRID, 256, 0, stream>>>(hsA, rowbeg, rowend, col, odi, idi, W0, b0, hsB, nullptr, nullptr);
    k_layer<1, 0><<<LAYER_GRID, 256, 0, stream>>>(hsB, rowbeg, rowend, col, odi, idi, W1, b1, hsA, nullptr, nullptr);
    k_layer<0, 1><<<LAYER_GRID, 256, 0, stream>>>(hsA, rowbeg, rowend, col, odi, idi, W2, b2, nullptr, outF, partials);

    // factor + pooling
    k_reduce_factor<<<1, 256, 0, stream>>>(partials, factor);
    int poolWaves  = (N_NODES + POOL_CHUNK - 1) / POOL_CHUNK;
    int poolBlocks = (poolWaves + 3) / 4;
    k_pool<<<poolBlocks, 256, 0, stream>>>(outF, gids, factor, out);
}

// Round 6
// 299.927 us; speedup vs baseline: 3.4103x; 1.1847x over previous
//
#include <hip/hip_runtime.h>
#include <hip/hip_fp16.h>

#define N_NODES 100000
#define N_EDGES 1600000
#define N_GRAPHS 2000
#define HID 64
#define NB 391        // buckets of 256 nodes: (N_NODES+255)/256
#define CH 4096       // edges per partition chunk
#define CAP 5120      // per-bucket region capacity (mean 4096, std ~64; +16 sigma)
#define LAYER_GRID 2048
#define N_GROUPS (N_NODES / 4)  // 25000

// ---------------- utility ----------------
__global__ __launch_bounds__(256) void k_zero_i32(int* __restrict__ p, int n) {
    int i = blockIdx.x * 256 + threadIdx.x;
    if (i < n) p[i] = 0;
}

// ---------------- single pass: partition edges into dst-buckets (u32) AND src-buckets (u8) ----
// dst entry u32 = (src << 8) | (dst & 255); src entry u8 = src & 255
__global__ __launch_bounds__(256) void k_partition_dual(const int* __restrict__ src, const int* __restrict__ dst,
                                                        int* __restrict__ gcur_dst, int* __restrict__ gcur_src,
                                                        unsigned* __restrict__ part_dst,
                                                        unsigned char* __restrict__ part_src) {
    __shared__ unsigned stage[CH];   // 16KB; reused as u8[CH] in src phase
    __shared__ int lcnt[NB];
    __shared__ int lexcl[NB];
    __shared__ int lofs[NB];
    __shared__ int runbase[NB];
    __shared__ int scanbuf[512];
    int tid = threadIdx.x;
    int e0 = blockIdx.x * CH;
    int n = min(CH, N_EDGES - e0);

    int sv[16], dv[16];
#pragma unroll
    for (int k = 0; k < 16; ++k) {
        int i = k * 256 + tid;
        if (i < n) { sv[k] = src[e0 + i]; dv[k] = dst[e0 + i]; }
        else dv[k] = -1;
    }

    // ================= dst phase =================
    for (int i = tid; i < NB; i += 256) lcnt[i] = 0;
    __syncthreads();
#pragma unroll
    for (int k = 0; k < 16; ++k)
        if (dv[k] >= 0) atomicAdd(&lcnt[dv[k] >> 8], 1);
    __syncthreads();
    for (int s = tid; s < 512; s += 256) scanbuf[s] = (s < NB) ? lcnt[s] : 0;
    __syncthreads();
    for (int off = 1; off < 512; off <<= 1) {
        int i0 = tid, i1 = tid + 256;
        int v0 = scanbuf[i0] + ((i0 >= off) ? scanbuf[i0 - off] : 0);
        int v1 = scanbuf[i1] + ((i1 >= off) ? scanbuf[i1 - off] : 0);
        __syncthreads();
        scanbuf[i0] = v0;
        scanbuf[i1] = v1;
        __syncthreads();
    }
    for (int i = tid; i < NB; i += 256) {
        int ex = scanbuf[i] - lcnt[i];
        lexcl[i] = ex;
        lofs[i] = ex;
    }
    __syncthreads();
#pragma unroll
    for (int k = 0; k < 16; ++k) {
        if (dv[k] >= 0) {
            int p = atomicAdd(&lofs[dv[k] >> 8], 1);
            stage[p] = ((unsigned)sv[k] << 8) | (unsigned)(dv[k] & 255);
        }
    }
    __syncthreads();
    for (int b = tid; b < NB; b += 256)
        if (lcnt[b]) runbase[b] = atomicAdd(&gcur_dst[b], lcnt[b]);
    __syncthreads();
    for (int i = tid; i < n; i += 256) {
        int lo = 0, hi = NB - 1;
        while (lo < hi) {
            int mid = (lo + hi + 1) >> 1;
            if (lexcl[mid] <= i) lo = mid; else hi = mid - 1;
        }
        int pos = runbase[lo] + (i - lexcl[lo]);
        if (pos < CAP) part_dst[(size_t)lo * CAP + pos] = stage[i];
    }
    __syncthreads();

    // ================= src phase (u8 entries) =================
    for (int i = tid; i < NB; i += 256) lcnt[i] = 0;
    __syncthreads();
#pragma unroll
    for (int k = 0; k < 16; ++k)
        if (dv[k] >= 0) atomicAdd(&lcnt[sv[k] >> 8], 1);
    __syncthreads();
    for (int s = tid; s < 512; s += 256) scanbuf[s] = (s < NB) ? lcnt[s] : 0;
    __syncthreads();
    for (int off = 1; off < 512; off <<= 1) {
        int i0 = tid, i1 = tid + 256;
        int v0 = scanbuf[i0] + ((i0 >= off) ? scanbuf[i0 - off] : 0);
        int v1 = scanbuf[i1] + ((i1 >= off) ? scanbuf[i1 - off] : 0);
        __syncthreads();
        scanbuf[i0] = v0;
        scanbuf[i1] = v1;
        __syncthreads();
    }
    for (int i = tid; i < NB; i += 256) {
        int ex = scanbuf[i] - lcnt[i];
        lexcl[i] = ex;
        lofs[i] = ex;
    }
    __syncthreads();
    unsigned char* stage8 = (unsigned char*)stage;
#pragma unroll
    for (int k = 0; k < 16; ++k) {
        if (dv[k] >= 0) {
            int p = atomicAdd(&lofs[sv[k] >> 8], 1);
            stage8[p] = (unsigned char)(sv[k] & 255);
        }
    }
    __syncthreads();
    for (int b = tid; b < NB; b += 256)
        if (lcnt[b]) runbase[b] = atomicAdd(&gcur_src[b], lcnt[b]);
    __syncthreads();
    for (int i = tid; i < n; i += 256) {
        int lo = 0, hi = NB - 1;
        while (lo < hi) {
            int mid = (lo + hi + 1) >> 1;
            if (lexcl[mid] <= i) lo = mid; else hi = mid - 1;
        }
        int pos = runbase[lo] + (i - lexcl[lo]);
        if (pos < CAP) part_src[(size_t)lo * CAP + pos] = stage8[i];
    }
}

// ---------------- scan dst-bucket counts -> bucket_base ----------------
__global__ __launch_bounds__(512) void k_scan_buckets(const int* __restrict__ gcur_dst,
                                                      int* __restrict__ bucket_base) {
    __shared__ int sd[512];
    int tid = threadIdx.x;
    int v = (tid < NB) ? gcur_dst[tid] : 0;
    sd[tid] = v;
    __syncthreads();
    for (int off = 1; off < 512; off <<= 1) {
        int t = (tid >= off) ? sd[tid - off] : 0;
        __syncthreads();
        sd[tid] += t;
        __syncthreads();
    }
    if (tid < NB) bucket_base[tid] = sd[tid] - v;  // exclusive
    if (tid == 0) bucket_base[NB] = sd[NB - 1];
}

// ---------------- per dst-bucket CSR (col, rowbeg, rowend, idi) ----------------
__global__ __launch_bounds__(256) void k_csr(const unsigned* __restrict__ part_dst,
                                             const int* __restrict__ bucket_base,
                                             int* __restrict__ rowbeg, int* __restrict__ rowend,
                                             float* __restrict__ idi, int* __restrict__ col) {
    __shared__ int cnt[256];
    __shared__ int cur[256];
    __shared__ int wsum[4];
    int b = blockIdx.x;
    int tid = threadIdx.x;
    int base = bucket_base[b];
    int nE = bucket_base[b + 1] - base;
    const unsigned* pb = part_dst + (size_t)b * CAP;
    cnt[tid] = 0;
    __syncthreads();
    for (int i = tid; i < nE; i += 256) atomicAdd(&cnt[pb[i] & 255], 1);
    __syncthreads();
    int c = cnt[tid];
    int incl = c;
#pragma unroll
    for (int off = 1; off < 64; off <<= 1) {
        int t = __shfl_up(incl, off, 64);
        if ((tid & 63) >= off) incl += t;
    }
    if ((tid & 63) == 63) wsum[tid >> 6] = incl;
    __syncthreads();
    int add = 0;
    for (int w = 0; w < (tid >> 6); ++w) add += wsum[w];
    incl += add;
    int excl = incl - c;
    int v = b * 256 + tid;
    if (v < N_NODES) {
        rowbeg[v] = base + excl;
        rowend[v] = base + incl;
        idi[v] = rsqrtf((float)max(c, 1));
    }
    cur[tid] = excl;
    __syncthreads();
    for (int i = tid; i < nE; i += 256) {
        unsigned e = pb[i];
        int p = atomicAdd(&cur[e & 255], 1);
        col[base + p] = (int)(e >> 8);
    }
}

// ---------------- per src-bucket: out-degree count -> odi, fused h*odi -> fp16 prescale -------
__global__ __launch_bounds__(256) void k_count_prescale(const unsigned char* __restrict__ part_src,
                                                        const int* __restrict__ gcur_src,
                                                        const float* __restrict__ h,
                                                        float* __restrict__ odi, __half* __restrict__ xs) {
    __shared__ int cnt[256];
    int b = blockIdx.x;
    int tid = threadIdx.x;
    int nE = gcur_src[b];
    const unsigned char* pb = part_src + (size_t)b * CAP;
    cnt[tid] = 0;
    __syncthreads();
    for (int i = tid; i < nE; i += 256) atomicAdd(&cnt[pb[i]], 1);
    __syncthreads();
    int v = b * 256 + tid;
    if (v < N_NODES) odi[v] = rsqrtf((float)max(cnt[tid], 1));
    // prescale this bucket's rows: 256 nodes x 16 float4
    for (int idx = tid; idx < 4096; idx += 256) {
        int row = idx >> 4;
        int vv = b * 256 + row;
        if (vv >= N_NODES) break;
        float w = rsqrtf((float)max(cnt[row], 1));
        int f0 = (idx & 15) << 2;
        float4 f = *(const float4*)&h[(size_t)vv * 64 + f0];
        __half2 p0 = __floats2half2_rn(f.x * w, f.y * w);
        __half2 p1 = __floats2half2_rn(f.z * w, f.w * w);
        uint2 st;
        st.x = *(unsigned*)&p0;
        st.y = *(unsigned*)&p1;
        *(uint2*)&xs[(size_t)vv * 64 + f0] = st;
    }
}

// ---------------- fused layer over pre-scaled fp16 rows ----------------
template <int RELU, int LAST>
__global__ __launch_bounds__(256) void k_layer(const __half* __restrict__ xs, const int* __restrict__ rowbeg,
                                               const int* __restrict__ rowend, const int* __restrict__ col,
                                               const float* __restrict__ odi, const float* __restrict__ idi,
                                               const float* __restrict__ W, const float* __restrict__ b,
                                               __half* __restrict__ xs_out, float* __restrict__ out_f32,
                                               float* __restrict__ partials) {
    __shared__ float Ws[64 * 64];
    __shared__ float aggLds[4 * 64];
    __shared__ float part[4];
    int tid = threadIdx.x;
    for (int i = tid * 4; i < 4096; i += 1024)
        *(float4*)&Ws[i] = *(const float4*)&W[i];
    __syncthreads();

    int lane = tid & 63;
    int wid = tid >> 6;
    float bias = b[lane];
    float nacc = 0.f;

    for (int g = blockIdx.x; g < N_GROUPS; g += LAYER_GRID) {
        int v = __builtin_amdgcn_readfirstlane(g * 4 + wid);
        int beg = rowbeg[v], end = rowend[v];
        float a0 = 0.f, a1 = 0.f, a2 = 0.f, a3 = 0.f;
        int p = beg;
        for (; p + 8 <= end; p += 8) {
            int s0 = col[p + 0], s1 = col[p + 1], s2 = col[p + 2], s3 = col[p + 3];
            int s4 = col[p + 4], s5 = col[p + 5], s6 = col[p + 6], s7 = col[p + 7];
            a0 += __half2float(xs[s0 * 64 + lane]);
            a1 += __half2float(xs[s1 * 64 + lane]);
            a2 += __half2float(xs[s2 * 64 + lane]);
            a3 += __half2float(xs[s3 * 64 + lane]);
            a0 += __half2float(xs[s4 * 64 + lane]);
            a1 += __half2float(xs[s5 * 64 + lane]);
            a2 += __half2float(xs[s6 * 64 + lane]);
            a3 += __half2float(xs[s7 * 64 + lane]);
        }
        if (p < end) {  // masked octet tail (clamped index, wave-uniform select)
#pragma unroll
            for (int k = 0; k < 8; ++k) {
                int q = (p + k < end) ? (p + k) : (end - 1);
                float xv = __half2float(xs[col[q] * 64 + lane]);
                xv = (p + k < end) ? xv : 0.f;
                if (k & 2) { if (k & 1) a3 += xv; else a2 += xv; }
                else       { if (k & 1) a1 += xv; else a0 += xv; }
            }
        }
        float a = ((a0 + a1) + (a2 + a3)) * idi[v];

        aggLds[wid * 64 + lane] = a;  // wave-local round-trip (no barrier needed)
        float o = bias;
#pragma unroll
        for (int k = 0; k < 64; ++k)
            o = fmaf(aggLds[wid * 64 + k], Ws[k * 64 + lane], o);
        if (RELU) o = fmaxf(o, 0.f);

        if (LAST) {
            out_f32[(size_t)v * 64 + lane] = o;
            float s = o * o;
#pragma unroll
            for (int off = 32; off > 0; off >>= 1) s += __shfl_xor(s, off, 64);
            if (lane == 0) nacc += sqrtf(s);
        } else {
            xs_out[(size_t)v * 64 + lane] = __float2half_rn(o * odi[v]);
        }
    }

    if (LAST) {
        if (lane == 0) part[wid] = nacc;
        __syncthreads();
        if (tid == 0) partials[blockIdx.x] = part[0] + part[1] + part[2] + part[3];
    }
}

__global__ __launch_bounds__(256) void k_reduce_factor(const float* __restrict__ partials,
                                                       float* __restrict__ factor) {
    __shared__ float sd[256];
    int tid = threadIdx.x;
    float s = 0.f;
    for (int i = tid; i < LAYER_GRID; i += 256) s += partials[i];
    sd[tid] = s;
    __syncthreads();
    for (int off = 128; off > 0; off >>= 1) {
        if (tid < off) sd[tid] += sd[tid + off];
        __syncthreads();
    }
    if (tid == 0) factor[0] = 8.0f * (float)N_NODES / sd[0];
}

// ---------------- sum pooling over sorted graph_ids ----------------
#define POOL_CHUNK 32
__global__ __launch_bounds__(256) void k_pool(const float* __restrict__ h, const int* __restrict__ gid,
                                              const float* __restrict__ factor, float* __restrict__ out) {
    int wave = (blockIdx.x * 256 + threadIdx.x) >> 6;
    int lane = threadIdx.x & 63;
    int v0 = wave * POOL_CHUNK;
    if (v0 >= N_NODES) return;
    float f = factor[0];
    int vend = min(v0 + POOL_CHUNK, N_NODES);
    int gprev = gid[v0];
    float acc = 0.f;
    for (int v = v0; v < vend; ++v) {
        int g = gid[v];
        if (g != gprev) {
            atomicAdd(&out[(size_t)gprev * 64 + lane], acc);
            acc = 0.f;
            gprev = g;
        }
        acc = fmaf(h[(size_t)v * 64 + lane], f, acc);
    }
    atomicAdd(&out[(size_t)gprev * 64 + lane], acc);
}

extern "C" void kernel_launch(void* const* d_in, const int* in_sizes, int n_in,
                              void* d_out, int out_size, void* d_ws, size_t ws_size,
                              hipStream_t stream) {
    const float* h    = (const float*)d_in[0];
    const int*   esrc = (const int*)d_in[1];
    const int*   edst = (const int*)d_in[2];
    const int*   gids = (const int*)d_in[3];
    const float* W0 = (const float*)d_in[4];
    const float* b0 = (const float*)d_in[5];
    const float* W1 = (const float*)d_in[6];
    const float* b1 = (const float*)d_in[7];
    const float* W2 = (const float*)d_in[8];
    const float* b2 = (const float*)d_in[9];
    float* out = (float*)d_out;

    char* wsp = (char*)d_ws;
    size_t off = 0;
    auto alloc = [&](size_t bytes) -> void* {
        void* p = wsp + off;
        off += (bytes + 255) & ~(size_t)255;
        return p;
    };
    int*   gcur       = (int*)alloc((size_t)(2 * NB) * 4);   // [0..NB): dst, [NB..2NB): src
    int*   bucket_base= (int*)alloc((size_t)(NB + 1) * 4);
    float* odi        = (float*)alloc((size_t)N_NODES * 4);
    float* idi        = (float*)alloc((size_t)N_NODES * 4);
    int*   rowbeg     = (int*)alloc((size_t)N_NODES * 4);
    int*   rowend     = (int*)alloc((size_t)N_NODES * 4);
    float* partials   = (float*)alloc((size_t)LAYER_GRID * 4);
    float* factor     = (float*)alloc(4);
    int*   col        = (int*)alloc((size_t)N_EDGES * 4);
    __half* hsA       = (__half*)alloc((size_t)N_NODES * 64 * 2);
    __half* hsB       = (__half*)alloc((size_t)N_NODES * 64 * 2);
    float* outF       = (float*)alloc((size_t)N_NODES * 64 * 4);
    // aliases into outF (dead until layer-2 output; partition buffers dead before layer 0)
    unsigned*      part_dst = (unsigned*)outF;                       // NB*CAP*4 = 8.0 MB
    unsigned char* part_src = (unsigned char*)outF + (size_t)NB * CAP * 4;  // NB*CAP = 2.0 MB

    int* gcur_dst = gcur;
    int* gcur_src = gcur + NB;

    k_zero_i32<<<(2 * NB + 255) / 256, 256, 0, stream>>>(gcur, 2 * NB);
    k_zero_i32<<<(N_GRAPHS * 64 + 255) / 256, 256, 0, stream>>>((int*)out, N_GRAPHS * 64);

    // single-pass dual partition (dst u32 entries, src u8 entries)
    int nchunks = (N_EDGES + CH - 1) / CH;  // 391
    k_partition_dual<<<nchunks, 256, 0, stream>>>(esrc, edst, gcur_dst, gcur_src, part_dst, part_src);
    k_scan_buckets<<<1, 512, 0, stream>>>(gcur_dst, bucket_base);
    k_csr<<<NB, 256, 0, stream>>>(part_dst, bucket_base, rowbeg, rowend, idi, col);
    k_count_prescale<<<NB, 256, 0, stream>>>(part_src, gcur_src, h, odi, hsA);

    // fused layers (agg + GEMM + bias + act; fp16 pre-scaled gather buffers)
    k_layer<1, 0><<<LAYER_GRID, 256, 0, stream>>>(hsA, rowbeg, rowend, col, odi, idi, W0, b0, hsB, nullptr, nullptr);
    k_layer<1, 0><<<LAYER_GRID, 256, 0, stream>>>(hsB, rowbeg, rowend, col, odi, idi, W1, b1, hsA, nullptr, nullptr);
    k_layer<0, 1><<<LAYER_GRID, 256, 0, stream>>>(hsA, rowbeg, rowend, col, odi, idi, W2, b2, nullptr, outF, partials);

    // factor + pooling
    k_reduce_factor<<<1, 256, 0, stream>>>(partials, factor);
    int poolWaves  = (N_NODES + POOL_CHUNK - 1) / POOL_CHUNK;
    int poolBlocks = (poolWaves + 3) / 4;
    k_pool<<<poolBlocks, 256, 0, stream>>>(outF, gids, factor, out);
}

// Round 7
// 241.104 us; speedup vs baseline: 4.2424x; 1.2440x over previous
//
#include <hip/hip_runtime.h>
#include <hip/hip_fp16.h>

#define N_NODES 100000
#define N_EDGES 1600000
#define N_GRAPHS 2000
#define HID 64
#define NB 391        // buckets of 256 nodes: (N_NODES+255)/256
#define CH 4096       // edges per partition chunk
#define CAP 5120      // per-bucket region capacity (mean 4096; +16 sigma)
#define GATHER_GRID 2048
#define GEMM_GRID 512
#define N_GROUPS (N_NODES / 4)   // 25000
#define N_TILE16 (N_NODES / 16)  // 6250 (exact)

typedef _Float16 half8 __attribute__((ext_vector_type(8)));
typedef float f32x4 __attribute__((ext_vector_type(4)));

// ---------------- utility ----------------
__global__ __launch_bounds__(256) void k_zero_i32(int* __restrict__ p, int n) {
    int i = blockIdx.x * 256 + threadIdx.x;
    if (i < n) p[i] = 0;
}

// ---------------- single pass: partition edges into dst-buckets (u32) AND src-buckets (u8) ----
__global__ __launch_bounds__(256) void k_partition_dual(const int* __restrict__ src, const int* __restrict__ dst,
                                                        int* __restrict__ gcur_dst, int* __restrict__ gcur_src,
                                                        unsigned* __restrict__ part_dst,
                                                        unsigned char* __restrict__ part_src) {
    __shared__ unsigned stage[CH];
    __shared__ int lcnt[NB];
    __shared__ int lexcl[NB];
    __shared__ int lofs[NB];
    __shared__ int runbase[NB];
    __shared__ int scanbuf[512];
    int tid = threadIdx.x;
    int e0 = blockIdx.x * CH;
    int n = min(CH, N_EDGES - e0);

    int sv[16], dv[16];
#pragma unroll
    for (int k = 0; k < 16; ++k) {
        int i = k * 256 + tid;
        if (i < n) { sv[k] = src[e0 + i]; dv[k] = dst[e0 + i]; }
        else dv[k] = -1;
    }

    // ================= dst phase =================
    for (int i = tid; i < NB; i += 256) lcnt[i] = 0;
    __syncthreads();
#pragma unroll
    for (int k = 0; k < 16; ++k)
        if (dv[k] >= 0) atomicAdd(&lcnt[dv[k] >> 8], 1);
    __syncthreads();
    for (int s = tid; s < 512; s += 256) scanbuf[s] = (s < NB) ? lcnt[s] : 0;
    __syncthreads();
    for (int off = 1; off < 512; off <<= 1) {
        int i0 = tid, i1 = tid + 256;
        int v0 = scanbuf[i0] + ((i0 >= off) ? scanbuf[i0 - off] : 0);
        int v1 = scanbuf[i1] + ((i1 >= off) ? scanbuf[i1 - off] : 0);
        __syncthreads();
        scanbuf[i0] = v0;
        scanbuf[i1] = v1;
        __syncthreads();
    }
    for (int i = tid; i < NB; i += 256) {
        int ex = scanbuf[i] - lcnt[i];
        lexcl[i] = ex;
        lofs[i] = ex;
    }
    __syncthreads();
#pragma unroll
    for (int k = 0; k < 16; ++k) {
        if (dv[k] >= 0) {
            int p = atomicAdd(&lofs[dv[k] >> 8], 1);
            stage[p] = ((unsigned)sv[k] << 8) | (unsigned)(dv[k] & 255);
        }
    }
    __syncthreads();
    for (int b = tid; b < NB; b += 256)
        if (lcnt[b]) runbase[b] = atomicAdd(&gcur_dst[b], lcnt[b]);
    __syncthreads();
    for (int i = tid; i < n; i += 256) {
        int lo = 0, hi = NB - 1;
        while (lo < hi) {
            int mid = (lo + hi + 1) >> 1;
            if (lexcl[mid] <= i) lo = mid; else hi = mid - 1;
        }
        int pos = runbase[lo] + (i - lexcl[lo]);
        if (pos < CAP) part_dst[(size_t)lo * CAP + pos] = stage[i];
    }
    __syncthreads();

    // ================= src phase (u8 entries) =================
    for (int i = tid; i < NB; i += 256) lcnt[i] = 0;
    __syncthreads();
#pragma unroll
    for (int k = 0; k < 16; ++k)
        if (dv[k] >= 0) atomicAdd(&lcnt[sv[k] >> 8], 1);
    __syncthreads();
    for (int s = tid; s < 512; s += 256) scanbuf[s] = (s < NB) ? lcnt[s] : 0;
    __syncthreads();
    for (int off = 1; off < 512; off <<= 1) {
        int i0 = tid, i1 = tid + 256;
        int v0 = scanbuf[i0] + ((i0 >= off) ? scanbuf[i0 - off] : 0);
        int v1 = scanbuf[i1] + ((i1 >= off) ? scanbuf[i1 - off] : 0);
        __syncthreads();
        scanbuf[i0] = v0;
        scanbuf[i1] = v1;
        __syncthreads();
    }
    for (int i = tid; i < NB; i += 256) {
        int ex = scanbuf[i] - lcnt[i];
        lexcl[i] = ex;
        lofs[i] = ex;
    }
    __syncthreads();
    unsigned char* stage8 = (unsigned char*)stage;
#pragma unroll
    for (int k = 0; k < 16; ++k) {
        if (dv[k] >= 0) {
            int p = atomicAdd(&lofs[sv[k] >> 8], 1);
            stage8[p] = (unsigned char)(sv[k] & 255);
        }
    }
    __syncthreads();
    for (int b = tid; b < NB; b += 256)
        if (lcnt[b]) runbase[b] = atomicAdd(&gcur_src[b], lcnt[b]);
    __syncthreads();
    for (int i = tid; i < n; i += 256) {
        int lo = 0, hi = NB - 1;
        while (lo < hi) {
            int mid = (lo + hi + 1) >> 1;
            if (lexcl[mid] <= i) lo = mid; else hi = mid - 1;
        }
        int pos = runbase[lo] + (i - lexcl[lo]);
        if (pos < CAP) part_src[(size_t)lo * CAP + pos] = stage8[i];
    }
}

// ---------------- scan dst-bucket counts -> bucket_base ----------------
__global__ __launch_bounds__(512) void k_scan_buckets(const int* __restrict__ gcur_dst,
                                                      int* __restrict__ bucket_base) {
    __shared__ int sd[512];
    int tid = threadIdx.x;
    int v = (tid < NB) ? gcur_dst[tid] : 0;
    sd[tid] = v;
    __syncthreads();
    for (int off = 1; off < 512; off <<= 1) {
        int t = (tid >= off) ? sd[tid - off] : 0;
        __syncthreads();
        sd[tid] += t;
        __syncthreads();
    }
    if (tid < NB) bucket_base[tid] = sd[tid] - v;  // exclusive
    if (tid == 0) bucket_base[NB] = sd[NB - 1];
}

// ---------------- per dst-bucket CSR (col, rowbeg, rowend, idi) ----------------
__global__ __launch_bounds__(256) void k_csr(const unsigned* __restrict__ part_dst,
                                             const int* __restrict__ bucket_base,
                                             int* __restrict__ rowbeg, int* __restrict__ rowend,
                                             float* __restrict__ idi, int* __restrict__ col) {
    __shared__ int cnt[256];
    __shared__ int cur[256];
    __shared__ int wsum[4];
    int b = blockIdx.x;
    int tid = threadIdx.x;
    int base = bucket_base[b];
    int nE = bucket_base[b + 1] - base;
    const unsigned* pb = part_dst + (size_t)b * CAP;
    cnt[tid] = 0;
    __syncthreads();
    for (int i = tid; i < nE; i += 256) atomicAdd(&cnt[pb[i] & 255], 1);
    __syncthreads();
    int c = cnt[tid];
    int incl = c;
#pragma unroll
    for (int off = 1; off < 64; off <<= 1) {
        int t = __shfl_up(incl, off, 64);
        if ((tid & 63) >= off) incl += t;
    }
    if ((tid & 63) == 63) wsum[tid >> 6] = incl;
    __syncthreads();
    int add = 0;
    for (int w = 0; w < (tid >> 6); ++w) add += wsum[w];
    incl += add;
    int excl = incl - c;
    int v = b * 256 + tid;
    if (v < N_NODES) {
        rowbeg[v] = base + excl;
        rowend[v] = base + incl;
        idi[v] = rsqrtf((float)max(c, 1));
    }
    cur[tid] = excl;
    __syncthreads();
    for (int i = tid; i < nE; i += 256) {
        unsigned e = pb[i];
        int p = atomicAdd(&cur[e & 255], 1);
        col[base + p] = (int)(e >> 8);
    }
}

// ---------------- per src-bucket: out-degree count -> odi ----------------
__global__ __launch_bounds__(256) void k_count(const unsigned char* __restrict__ part_src,
                                               const int* __restrict__ gcur_src,
                                               float* __restrict__ odi) {
    __shared__ int cnt[256];
    int b = blockIdx.x;
    int tid = threadIdx.x;
    int nE = gcur_src[b];
    const unsigned char* pb = part_src + (size_t)b * CAP;
    cnt[tid] = 0;
    __syncthreads();
    for (int i = tid; i < nE; i += 256) atomicAdd(&cnt[pb[i]], 1);
    __syncthreads();
    int v = b * 256 + tid;
    if (v < N_NODES) odi[v] = rsqrtf((float)max(cnt[tid], 1));
}

// ---------------- dense GEMM via MFMA: zs[v] = (x[v] @ W) * odi[v]  (fp16 out) ----------------
// mfma_f32_16x16x32_f16 layouts: A: row=l&15, k=(l>>4)*8+j ; B: col=l&15, k=(l>>4)*8+j ;
// D: col=l&15, row=(l>>4)*4+reg  (m89-verified C/D mapping).
template <int F32IN>
__global__ __launch_bounds__(256) void k_gemm_mfma(const void* __restrict__ inv,
                                                   const float* __restrict__ W,
                                                   const float* __restrict__ odi,
                                                   __half* __restrict__ zs) {
    __shared__ _Float16 Wt[64 * 64];  // Wt[j][k] = W[k][j]
    int tid = threadIdx.x;
    for (int i = tid; i < 4096; i += 256) {
        int k = i >> 6, j = i & 63;
        Wt[j * 64 + k] = (_Float16)W[i];
    }
    __syncthreads();

    int lane = tid & 63;
    int wid = tid >> 6;
    int lrow = lane & 15;   // A row / B col / D col
    int lgrp = lane >> 4;   // 0..3

    half8 Bf[4][2];  // [n-tile][k-half], register-resident for whole kernel
#pragma unroll
    for (int nt = 0; nt < 4; ++nt)
#pragma unroll
        for (int kh = 0; kh < 2; ++kh)
            Bf[nt][kh] = *(half8*)&Wt[(nt * 16 + lrow) * 64 + kh * 32 + lgrp * 8];

    for (int t = blockIdx.x * 4 + wid; t < N_TILE16; t += GEMM_GRID * 4) {
        int v0 = t * 16;
        half8 a0, a1;
        if (F32IN) {
            const float* A = (const float*)inv + (size_t)(v0 + lrow) * 64 + lgrp * 8;
            float4 f0 = *(const float4*)A;
            float4 f1 = *(const float4*)(A + 4);
            float4 g0 = *(const float4*)(A + 32);
            float4 g1 = *(const float4*)(A + 36);
            a0[0] = (_Float16)f0.x; a0[1] = (_Float16)f0.y; a0[2] = (_Float16)f0.z; a0[3] = (_Float16)f0.w;
            a0[4] = (_Float16)f1.x; a0[5] = (_Float16)f1.y; a0[6] = (_Float16)f1.z; a0[7] = (_Float16)f1.w;
            a1[0] = (_Float16)g0.x; a1[1] = (_Float16)g0.y; a1[2] = (_Float16)g0.z; a1[3] = (_Float16)g0.w;
            a1[4] = (_Float16)g1.x; a1[5] = (_Float16)g1.y; a1[6] = (_Float16)g1.z; a1[7] = (_Float16)g1.w;
        } else {
            const _Float16* A = (const _Float16*)inv + (size_t)(v0 + lrow) * 64 + lgrp * 8;
            a0 = *(const half8*)A;
            a1 = *(const half8*)(A + 32);
        }
        f32x4 acc[4];
#pragma unroll
        for (int nt = 0; nt < 4; ++nt) { acc[nt] = (f32x4)0.f; }
#pragma unroll
        for (int nt = 0; nt < 4; ++nt) {
            acc[nt] = __builtin_amdgcn_mfma_f32_16x16x32_f16(a0, Bf[nt][0], acc[nt], 0, 0, 0);
            acc[nt] = __builtin_amdgcn_mfma_f32_16x16x32_f16(a1, Bf[nt][1], acc[nt], 0, 0, 0);
        }
#pragma unroll
        for (int r = 0; r < 4; ++r) {
            int node = v0 + lgrp * 4 + r;
            float w = odi[node];
#pragma unroll
            for (int nt = 0; nt < 4; ++nt)
                zs[(size_t)node * 64 + nt * 16 + lrow] = __float2half_rn(acc[nt][r] * w);
        }
    }
}

// ---------------- gather: out[v] = act( idi[v] * sum_{e:dst=v} zs[src] + b )  (no LDS) -------
template <int RELU, int LAST>
__global__ __launch_bounds__(256) void k_gather(const __half* __restrict__ zs, const int* __restrict__ rowbeg,
                                                const int* __restrict__ rowend, const int* __restrict__ col,
                                                const float* __restrict__ idi, const float* __restrict__ b,
                                                __half* __restrict__ xout, float* __restrict__ outF,
                                                float* __restrict__ partials) {
    __shared__ float part[4];
    int tid = threadIdx.x;
    int lane = tid & 63;
    int wid = tid >> 6;
    float bias = b[lane];
    float nacc = 0.f;

    for (int g = blockIdx.x; g < N_GROUPS; g += GATHER_GRID) {
        int v = __builtin_amdgcn_readfirstlane(g * 4 + wid);
        int beg = rowbeg[v], end = rowend[v];
        float a0 = 0.f, a1 = 0.f, a2 = 0.f, a3 = 0.f;
        int p = beg;
        for (; p + 8 <= end; p += 8) {
            int s0 = col[p + 0], s1 = col[p + 1], s2 = col[p + 2], s3 = col[p + 3];
            int s4 = col[p + 4], s5 = col[p + 5], s6 = col[p + 6], s7 = col[p + 7];
            a0 += __half2float(zs[s0 * 64 + lane]);
            a1 += __half2float(zs[s1 * 64 + lane]);
            a2 += __half2float(zs[s2 * 64 + lane]);
            a3 += __half2float(zs[s3 * 64 + lane]);
            a0 += __half2float(zs[s4 * 64 + lane]);
            a1 += __half2float(zs[s5 * 64 + lane]);
            a2 += __half2float(zs[s6 * 64 + lane]);
            a3 += __half2float(zs[s7 * 64 + lane]);
        }
        if (p < end) {  // masked octet tail (clamped index, wave-uniform select)
#pragma unroll
            for (int k = 0; k < 8; ++k) {
                int q = (p + k < end) ? (p + k) : (end - 1);
                float xv = __half2float(zs[col[q] * 64 + lane]);
                xv = (p + k < end) ? xv : 0.f;
                if (k & 2) { if (k & 1) a3 += xv; else a2 += xv; }
                else       { if (k & 1) a1 += xv; else a0 += xv; }
            }
        }
        float o = fmaf(((a0 + a1) + (a2 + a3)), idi[v], bias);
        if (RELU) o = fmaxf(o, 0.f);

        if (LAST) {
            outF[(size_t)v * 64 + lane] = o;
            float s = o * o;
#pragma unroll
            for (int off = 32; off > 0; off >>= 1) s += __shfl_xor(s, off, 64);
            if (lane == 0) nacc += sqrtf(s);
        } else {
            xout[(size_t)v * 64 + lane] = __float2half_rn(o);
        }
    }

    if (LAST) {
        if (lane == 0) part[wid] = nacc;
        __syncthreads();
        if (tid == 0) partials[blockIdx.x] = part[0] + part[1] + part[2] + part[3];
    }
}

__global__ __launch_bounds__(256) void k_reduce_factor(const float* __restrict__ partials,
                                                       float* __restrict__ factor) {
    __shared__ float sd[256];
    int tid = threadIdx.x;
    float s = 0.f;
    for (int i = tid; i < GATHER_GRID; i += 256) s += partials[i];
    sd[tid] = s;
    __syncthreads();
    for (int off = 128; off > 0; off >>= 1) {
        if (tid < off) sd[tid] += sd[tid + off];
        __syncthreads();
    }
    if (tid == 0) factor[0] = 8.0f * (float)N_NODES / sd[0];
}

// ---------------- sum pooling over sorted graph_ids ----------------
#define POOL_CHUNK 32
__global__ __launch_bounds__(256) void k_pool(const float* __restrict__ h, const int* __restrict__ gid,
                                              const float* __restrict__ factor, float* __restrict__ out) {
    int wave = (blockIdx.x * 256 + threadIdx.x) >> 6;
    int lane = threadIdx.x & 63;
    int v0 = wave * POOL_CHUNK;
    if (v0 >= N_NODES) return;
    float f = factor[0];
    int vend = min(v0 + POOL_CHUNK, N_NODES);
    int gprev = gid[v0];
    float acc = 0.f;
    for (int v = v0; v < vend; ++v) {
        int g = gid[v];
        if (g != gprev) {
            atomicAdd(&out[(size_t)gprev * 64 + lane], acc);
            acc = 0.f;
            gprev = g;
        }
        acc = fmaf(h[(size_t)v * 64 + lane], f, acc);
    }
    atomicAdd(&out[(size_t)gprev * 64 + lane], acc);
}

extern "C" void kernel_launch(void* const* d_in, const int* in_sizes, int n_in,
                              void* d_out, int out_size, void* d_ws, size_t ws_size,
                              hipStream_t stream) {
    const float* h    = (const float*)d_in[0];
    const int*   esrc = (const int*)d_in[1];
    const int*   edst = (const int*)d_in[2];
    const int*   gids = (const int*)d_in[3];
    const float* W0 = (const float*)d_in[4];
    const float* b0 = (const float*)d_in[5];
    const float* W1 = (const float*)d_in[6];
    const float* b1 = (const float*)d_in[7];
    const float* W2 = (const float*)d_in[8];
    const float* b2 = (const float*)d_in[9];
    float* out = (float*)d_out;

    char* wsp = (char*)d_ws;
    size_t off = 0;
    auto alloc = [&](size_t bytes) -> void* {
        void* p = wsp + off;
        off += (bytes + 255) & ~(size_t)255;
        return p;
    };
    int*   gcur       = (int*)alloc((size_t)(2 * NB) * 4);   // [0..NB): dst, [NB..2NB): src
    int*   bucket_base= (int*)alloc((size_t)(NB + 1) * 4);
    float* odi        = (float*)alloc((size_t)N_NODES * 4);
    float* idi        = (float*)alloc((size_t)N_NODES * 4);
    int*   rowbeg     = (int*)alloc((size_t)N_NODES * 4);
    int*   rowend     = (int*)alloc((size_t)N_NODES * 4);
    float* partials   = (float*)alloc((size_t)GATHER_GRID * 4);
    float* factor     = (float*)alloc(4);
    int*   col        = (int*)alloc((size_t)N_EDGES * 4);
    __half* zsb       = (__half*)alloc((size_t)N_NODES * 64 * 2);
    __half* xh        = (__half*)alloc((size_t)N_NODES * 64 * 2);
    float* outF       = (float*)alloc((size_t)N_NODES * 64 * 4);
    // aliases into outF (partition buffers dead before layer-0 GEMM; outF written by last gather)
    unsigned*      part_dst = (unsigned*)outF;                              // NB*CAP*4 = 8.0 MB
    unsigned char* part_src = (unsigned char*)outF + (size_t)NB * CAP * 4;  // NB*CAP = 2.0 MB

    int* gcur_dst = gcur;
    int* gcur_src = gcur + NB;

    k_zero_i32<<<(2 * NB + 255) / 256, 256, 0, stream>>>(gcur, 2 * NB);
    k_zero_i32<<<(N_GRAPHS * 64 + 255) / 256, 256, 0, stream>>>((int*)out, N_GRAPHS * 64);

    // CSR build: single-pass dual partition, then per-bucket CSR + out-degree
    int nchunks = (N_EDGES + CH - 1) / CH;  // 391
    k_partition_dual<<<nchunks, 256, 0, stream>>>(esrc, edst, gcur_dst, gcur_src, part_dst, part_src);
    k_scan_buckets<<<1, 512, 0, stream>>>(gcur_dst, bucket_base);
    k_csr<<<NB, 256, 0, stream>>>(part_dst, bucket_base, rowbeg, rowend, idi, col);
    k_count<<<NB, 256, 0, stream>>>(part_src, gcur_src, odi);

    // layer 0: z = h@W0 (MFMA, odi-scaled fp16) -> gather
    k_gemm_mfma<1><<<GEMM_GRID, 256, 0, stream>>>(h, W0, odi, zsb);
    k_gather<1, 0><<<GATHER_GRID, 256, 0, stream>>>(zsb, rowbeg, rowend, col, idi, b0, xh, nullptr, nullptr);
    // layer 1
    k_gemm_mfma<0><<<GEMM_GRID, 256, 0, stream>>>(xh, W1, odi, zsb);
    k_gather<1, 0><<<GATHER_GRID, 256, 0, stream>>>(zsb, rowbeg, rowend, col, idi, b1, xh, nullptr, nullptr);
    // layer 2 (last: f32 out + norm partials)
    k_gemm_mfma<0><<<GEMM_GRID, 256, 0, stream>>>(xh, W2, odi, zsb);
    k_gather<0, 1><<<GATHER_GRID, 256, 0, stream>>>(zsb, rowbeg, rowend, col, idi, b2, nullptr, outF, partials);

    // factor + pooling
    k_reduce_factor<<<1, 256, 0, stream>>>(partials, factor);
    int poolWaves  = (N_NODES + POOL_CHUNK - 1) / POOL_CHUNK;
    int poolBlocks = (poolWaves + 3) / 4;
    k_pool<<<poolBlocks, 256, 0, stream>>>(outF, gids, factor, out);
}

// Round 8
// 238.985 us; speedup vs baseline: 4.2800x; 1.0089x over previous
//
#include <hip/hip_runtime.h>
#include <hip/hip_fp16.h>

#define N_NODES 100000
#define N_EDGES 1600000
#define N_GRAPHS 2000
#define HID 64
#define NB 391        // buckets of 256 nodes: (N_NODES+255)/256
#define CH 2048       // edges per partition chunk
#define CAP 5120      // per-bucket region capacity (mean 4096; +16 sigma)
#define GATHER_GRID 2048
#define GEMM_GRID 512
#define N_GROUPS (N_NODES / 4)   // 25000
#define N_TILE16 (N_NODES / 16)  // 6250 (exact)

typedef _Float16 half8 __attribute__((ext_vector_type(8)));
typedef float f32x4 __attribute__((ext_vector_type(4)));

// ---------------- utility ----------------
__global__ __launch_bounds__(256) void k_zero_i32(int* __restrict__ p, int n) {
    int i = blockIdx.x * 256 + threadIdx.x;
    if (i < n) p[i] = 0;
}

// ---------------- single pass: partition edges into dst-buckets (u32) AND src-buckets (u8) ----
// dst entry u32 = (src << 8) | (dst & 255); src entry u8 = src & 255
// stageB records each staged slot's bucket id -> direct flush (no binary search).
__global__ __launch_bounds__(256) void k_partition_dual(const int* __restrict__ src, const int* __restrict__ dst,
                                                        int* __restrict__ gcur_dst, int* __restrict__ gcur_src,
                                                        unsigned* __restrict__ part_dst,
                                                        unsigned char* __restrict__ part_src) {
    __shared__ unsigned stage[CH];            // 8KB (aliased as u8[CH] in src phase)
    __shared__ unsigned short stageB[CH];     // 4KB bucket-of-slot
    __shared__ int lcnt[NB];
    __shared__ int lexcl[NB];
    __shared__ int lofs[NB];
    __shared__ int runbase[NB];
    __shared__ int scanbuf[512];
    int tid = threadIdx.x;
    int e0 = blockIdx.x * CH;
    int n = min(CH, N_EDGES - e0);

    int sv[8], dv[8];
#pragma unroll
    for (int k = 0; k < 8; ++k) {
        int i = k * 256 + tid;
        if (i < n) { sv[k] = src[e0 + i]; dv[k] = dst[e0 + i]; }
        else dv[k] = -1;
    }

    // ================= dst phase =================
    for (int i = tid; i < NB; i += 256) lcnt[i] = 0;
    __syncthreads();
#pragma unroll
    for (int k = 0; k < 8; ++k)
        if (dv[k] >= 0) atomicAdd(&lcnt[dv[k] >> 8], 1);
    __syncthreads();
    for (int s = tid; s < 512; s += 256) scanbuf[s] = (s < NB) ? lcnt[s] : 0;
    __syncthreads();
    for (int off = 1; off < 512; off <<= 1) {
        int i0 = tid, i1 = tid + 256;
        int v0 = scanbuf[i0] + ((i0 >= off) ? scanbuf[i0 - off] : 0);
        int v1 = scanbuf[i1] + ((i1 >= off) ? scanbuf[i1 - off] : 0);
        __syncthreads();
        scanbuf[i0] = v0;
        scanbuf[i1] = v1;
        __syncthreads();
    }
    for (int i = tid; i < NB; i += 256) {
        int ex = scanbuf[i] - lcnt[i];
        lexcl[i] = ex;
        lofs[i] = ex;
    }
    __syncthreads();
#pragma unroll
    for (int k = 0; k < 8; ++k) {
        if (dv[k] >= 0) {
            int b = dv[k] >> 8;
            int p = atomicAdd(&lofs[b], 1);
            stage[p] = ((unsigned)sv[k] << 8) | (unsigned)(dv[k] & 255);
            stageB[p] = (unsigned short)b;
        }
    }
    __syncthreads();
    for (int b = tid; b < NB; b += 256)
        if (lcnt[b]) runbase[b] = atomicAdd(&gcur_dst[b], lcnt[b]);
    __syncthreads();
    for (int i = tid; i < n; i += 256) {
        int b = stageB[i];
        int pos = runbase[b] + (i - lexcl[b]);
        if (pos < CAP) part_dst[(size_t)b * CAP + pos] = stage[i];
    }
    __syncthreads();

    // ================= src phase (u8 entries) =================
    for (int i = tid; i < NB; i += 256) lcnt[i] = 0;
    __syncthreads();
#pragma unroll
    for (int k = 0; k < 8; ++k)
        if (dv[k] >= 0) atomicAdd(&lcnt[sv[k] >> 8], 1);
    __syncthreads();
    for (int s = tid; s < 512; s += 256) scanbuf[s] = (s < NB) ? lcnt[s] : 0;
    __syncthreads();
    for (int off = 1; off < 512; off <<= 1) {
        int i0 = tid, i1 = tid + 256;
        int v0 = scanbuf[i0] + ((i0 >= off) ? scanbuf[i0 - off] : 0);
        int v1 = scanbuf[i1] + ((i1 >= off) ? scanbuf[i1 - off] : 0);
        __syncthreads();
        scanbuf[i0] = v0;
        scanbuf[i1] = v1;
        __syncthreads();
    }
    for (int i = tid; i < NB; i += 256) {
        int ex = scanbuf[i] - lcnt[i];
        lexcl[i] = ex;
        lofs[i] = ex;
    }
    __syncthreads();
    unsigned char* stage8 = (unsigned char*)stage;
#pragma unroll
    for (int k = 0; k < 8; ++k) {
        if (dv[k] >= 0) {
            int b = sv[k] >> 8;
            int p = atomicAdd(&lofs[b], 1);
            stage8[p] = (unsigned char)(sv[k] & 255);
            stageB[p] = (unsigned short)b;
        }
    }
    __syncthreads();
    for (int b = tid; b < NB; b += 256)
        if (lcnt[b]) runbase[b] = atomicAdd(&gcur_src[b], lcnt[b]);
    __syncthreads();
    for (int i = tid; i < n; i += 256) {
        int b = stageB[i];
        int pos = runbase[b] + (i - lexcl[b]);
        if (pos < CAP) part_src[(size_t)b * CAP + pos] = stage8[i];
    }
}

// ---------------- scan dst-bucket counts -> bucket_base ----------------
__global__ __launch_bounds__(512) void k_scan_buckets(const int* __restrict__ gcur_dst,
                                                      int* __restrict__ bucket_base) {
    __shared__ int sd[512];
    int tid = threadIdx.x;
    int v = (tid < NB) ? gcur_dst[tid] : 0;
    sd[tid] = v;
    __syncthreads();
    for (int off = 1; off < 512; off <<= 1) {
        int t = (tid >= off) ? sd[tid - off] : 0;
        __syncthreads();
        sd[tid] += t;
        __syncthreads();
    }
    if (tid < NB) bucket_base[tid] = sd[tid] - v;  // exclusive
    if (tid == 0) bucket_base[NB] = sd[NB - 1];
}

// ---------------- merged: blocks [0,NB) build dst CSR; [NB,2NB) count out-deg -> odi ----------
__global__ __launch_bounds__(256) void k_csr_count(const unsigned* __restrict__ part_dst,
                                                   const unsigned char* __restrict__ part_src,
                                                   const int* __restrict__ bucket_base,
                                                   const int* __restrict__ gcur_src,
                                                   int* __restrict__ rowbeg, int* __restrict__ rowend,
                                                   float* __restrict__ idi, float* __restrict__ odi,
                                                   int* __restrict__ col) {
    __shared__ int cnt[256];
    __shared__ int cur[256];
    __shared__ int wsum[4];
    int tid = threadIdx.x;
    if (blockIdx.x >= NB) {
        // ---- out-degree count ----
        int b = blockIdx.x - NB;
        int nE = gcur_src[b];
        const unsigned char* pb = part_src + (size_t)b * CAP;
        cnt[tid] = 0;
        __syncthreads();
        for (int i = tid; i < nE; i += 256) atomicAdd(&cnt[pb[i]], 1);
        __syncthreads();
        int v = b * 256 + tid;
        if (v < N_NODES) odi[v] = rsqrtf((float)max(cnt[tid], 1));
        return;
    }
    // ---- dst CSR ----
    int b = blockIdx.x;
    int base = bucket_base[b];
    int nE = bucket_base[b + 1] - base;
    const unsigned* pb = part_dst + (size_t)b * CAP;
    cnt[tid] = 0;
    __syncthreads();
    for (int i = tid; i < nE; i += 256) atomicAdd(&cnt[pb[i] & 255], 1);
    __syncthreads();
    int c = cnt[tid];
    int incl = c;
#pragma unroll
    for (int off = 1; off < 64; off <<= 1) {
        int t = __shfl_up(incl, off, 64);
        if ((tid & 63) >= off) incl += t;
    }
    if ((tid & 63) == 63) wsum[tid >> 6] = incl;
    __syncthreads();
    int add = 0;
    for (int w = 0; w < (tid >> 6); ++w) add += wsum[w];
    incl += add;
    int excl = incl - c;
    int v = b * 256 + tid;
    if (v < N_NODES) {
        rowbeg[v] = base + excl;
        rowend[v] = base + incl;
        idi[v] = rsqrtf((float)max(c, 1));
    }
    cur[tid] = excl;
    __syncthreads();
    for (int i = tid; i < nE; i += 256) {
        unsigned e = pb[i];
        int p = atomicAdd(&cur[e & 255], 1);
        col[base + p] = (int)(e >> 8);
    }
}

// ---------------- dense GEMM via MFMA: zs[v] = (x[v] @ W) * odi[v]  (fp16 out) ----------------
// mfma_f32_16x16x32_f16 layouts: A: row=l&15, k=(l>>4)*8+j ; B: col=l&15, k=(l>>4)*8+j ;
// D: col=l&15, row=(l>>4)*4+reg  (m89-verified C/D mapping).
template <int F32IN>
__global__ __launch_bounds__(256) void k_gemm_mfma(const void* __restrict__ inv,
                                                   const float* __restrict__ W,
                                                   const float* __restrict__ odi,
                                                   __half* __restrict__ zs) {
    __shared__ _Float16 Wt[64 * 64];  // Wt[j][k] = W[k][j]
    int tid = threadIdx.x;
    for (int i = tid; i < 4096; i += 256) {
        int k = i >> 6, j = i & 63;
        Wt[j * 64 + k] = (_Float16)W[i];
    }
    __syncthreads();

    int lane = tid & 63;
    int wid = tid >> 6;
    int lrow = lane & 15;   // A row / B col / D col
    int lgrp = lane >> 4;   // 0..3

    half8 Bf[4][2];  // [n-tile][k-half], register-resident for whole kernel
#pragma unroll
    for (int nt = 0; nt < 4; ++nt)
#pragma unroll
        for (int kh = 0; kh < 2; ++kh)
            Bf[nt][kh] = *(half8*)&Wt[(nt * 16 + lrow) * 64 + kh * 32 + lgrp * 8];

    for (int t = blockIdx.x * 4 + wid; t < N_TILE16; t += GEMM_GRID * 4) {
        int v0 = t * 16;
        half8 a0, a1;
        if (F32IN) {
            const float* A = (const float*)inv + (size_t)(v0 + lrow) * 64 + lgrp * 8;
            float4 f0 = *(const float4*)A;
            float4 f1 = *(const float4*)(A + 4);
            float4 g0 = *(const float4*)(A + 32);
            float4 g1 = *(const float4*)(A + 36);
            a0[0] = (_Float16)f0.x; a0[1] = (_Float16)f0.y; a0[2] = (_Float16)f0.z; a0[3] = (_Float16)f0.w;
            a0[4] = (_Float16)f1.x; a0[5] = (_Float16)f1.y; a0[6] = (_Float16)f1.z; a0[7] = (_Float16)f1.w;
            a1[0] = (_Float16)g0.x; a1[1] = (_Float16)g0.y; a1[2] = (_Float16)g0.z; a1[3] = (_Float16)g0.w;
            a1[4] = (_Float16)g1.x; a1[5] = (_Float16)g1.y; a1[6] = (_Float16)g1.z; a1[7] = (_Float16)g1.w;
        } else {
            const _Float16* A = (const _Float16*)inv + (size_t)(v0 + lrow) * 64 + lgrp * 8;
            a0 = *(const half8*)A;
            a1 = *(const half8*)(A + 32);
        }
        f32x4 acc[4];
#pragma unroll
        for (int nt = 0; nt < 4; ++nt) { acc[nt] = (f32x4)0.f; }
#pragma unroll
        for (int nt = 0; nt < 4; ++nt) {
            acc[nt] = __builtin_amdgcn_mfma_f32_16x16x32_f16(a0, Bf[nt][0], acc[nt], 0, 0, 0);
            acc[nt] = __builtin_amdgcn_mfma_f32_16x16x32_f16(a1, Bf[nt][1], acc[nt], 0, 0, 0);
        }
#pragma unroll
        for (int r = 0; r < 4; ++r) {
            int node = v0 + lgrp * 4 + r;
            float w = odi[node];
#pragma unroll
            for (int nt = 0; nt < 4; ++nt)
                zs[(size_t)node * 64 + nt * 16 + lrow] = __float2half_rn(acc[nt][r] * w);
        }
    }
}

// ---------------- gather: out[v] = act( idi[v] * sum_{e:dst=v} zs[src] + b )  (no LDS) -------
template <int RELU, int LAST>
__global__ __launch_bounds__(256) void k_gather(const __half* __restrict__ zs, const int* __restrict__ rowbeg,
                                                const int* __restrict__ rowend, const int* __restrict__ col,
                                                const float* __restrict__ idi, const float* __restrict__ b,
                                                __half* __restrict__ xout, float* __restrict__ outF,
                                                float* __restrict__ partials) {
    __shared__ float part[4];
    int tid = threadIdx.x;
    int lane = tid & 63;
    int wid = tid >> 6;
    float bias = b[lane];
    float nacc = 0.f;

    for (int g = blockIdx.x; g < N_GROUPS; g += GATHER_GRID) {
        int v = __builtin_amdgcn_readfirstlane(g * 4 + wid);
        int beg = rowbeg[v], end = rowend[v];
        float a0 = 0.f, a1 = 0.f, a2 = 0.f, a3 = 0.f;
        int p = beg;
        for (; p + 8 <= end; p += 8) {
            int s0 = col[p + 0], s1 = col[p + 1], s2 = col[p + 2], s3 = col[p + 3];
            int s4 = col[p + 4], s5 = col[p + 5], s6 = col[p + 6], s7 = col[p + 7];
            a0 += __half2float(zs[s0 * 64 + lane]);
            a1 += __half2float(zs[s1 * 64 + lane]);
            a2 += __half2float(zs[s2 * 64 + lane]);
            a3 += __half2float(zs[s3 * 64 + lane]);
            a0 += __half2float(zs[s4 * 64 + lane]);
            a1 += __half2float(zs[s5 * 64 + lane]);
            a2 += __half2float(zs[s6 * 64 + lane]);
            a3 += __half2float(zs[s7 * 64 + lane]);
        }
        if (p < end) {  // masked octet tail (clamped index, wave-uniform select)
#pragma unroll
            for (int k = 0; k < 8; ++k) {
                int q = (p + k < end) ? (p + k) : (end - 1);
                float xv = __half2float(zs[col[q] * 64 + lane]);
                xv = (p + k < end) ? xv : 0.f;
                if (k & 2) { if (k & 1) a3 += xv; else a2 += xv; }
                else       { if (k & 1) a1 += xv; else a0 += xv; }
            }
        }
        float o = fmaf(((a0 + a1) + (a2 + a3)), idi[v], bias);
        if (RELU) o = fmaxf(o, 0.f);

        if (LAST) {
            outF[(size_t)v * 64 + lane] = o;
            float s = o * o;
#pragma unroll
            for (int off = 32; off > 0; off >>= 1) s += __shfl_xor(s, off, 64);
            if (lane == 0) nacc += sqrtf(s);
        } else {
            xout[(size_t)v * 64 + lane] = __float2half_rn(o);
        }
    }

    if (LAST) {
        if (lane == 0) part[wid] = nacc;
        __syncthreads();
        if (tid == 0) partials[blockIdx.x] = part[0] + part[1] + part[2] + part[3];
    }
}

__global__ __launch_bounds__(256) void k_reduce_factor(const float* __restrict__ partials,
                                                       float* __restrict__ factor) {
    __shared__ float sd[256];
    int tid = threadIdx.x;
    float s = 0.f;
    for (int i = tid; i < GATHER_GRID; i += 256) s += partials[i];
    sd[tid] = s;
    __syncthreads();
    for (int off = 128; off > 0; off >>= 1) {
        if (tid < off) sd[tid] += sd[tid + off];
        __syncthreads();
    }
    if (tid == 0) factor[0] = 8.0f * (float)N_NODES / sd[0];
}

// ---------------- sum pooling over sorted graph_ids ----------------
#define POOL_CHUNK 32
__global__ __launch_bounds__(256) void k_pool(const float* __restrict__ h, const int* __restrict__ gid,
                                              const float* __restrict__ factor, float* __restrict__ out) {
    int wave = (blockIdx.x * 256 + threadIdx.x) >> 6;
    int lane = threadIdx.x & 63;
    int v0 = wave * POOL_CHUNK;
    if (v0 >= N_NODES) return;
    float f = factor[0];
    int vend = min(v0 + POOL_CHUNK, N_NODES);
    int gprev = gid[v0];
    float acc = 0.f;
    for (int v = v0; v < vend; ++v) {
        int g = gid[v];
        if (g != gprev) {
            atomicAdd(&out[(size_t)gprev * 64 + lane], acc);
            acc = 0.f;
            gprev = g;
        }
        acc = fmaf(h[(size_t)v * 64 + lane], f, acc);
    }
    atomicAdd(&out[(size_t)gprev * 64 + lane], acc);
}

extern "C" void kernel_launch(void* const* d_in, const int* in_sizes, int n_in,
                              void* d_out, int out_size, void* d_ws, size_t ws_size,
                              hipStream_t stream) {
    const float* h    = (const float*)d_in[0];
    const int*   esrc = (const int*)d_in[1];
    const int*   edst = (const int*)d_in[2];
    const int*   gids = (const int*)d_in[3];
    const float* W0 = (const float*)d_in[4];
    const float* b0 = (const float*)d_in[5];
    const float* W1 = (const float*)d_in[6];
    const float* b1 = (const float*)d_in[7];
    const float* W2 = (const float*)d_in[8];
    const float* b2 = (const float*)d_in[9];
    float* out = (float*)d_out;

    char* wsp = (char*)d_ws;
    size_t off = 0;
    auto alloc = [&](size_t bytes) -> void* {
        void* p = wsp + off;
        off += (bytes + 255) & ~(size_t)255;
        return p;
    };
    int*   gcur       = (int*)alloc((size_t)(2 * NB) * 4);   // [0..NB): dst, [NB..2NB): src
    int*   bucket_base= (int*)alloc((size_t)(NB + 1) * 4);
    float* odi        = (float*)alloc((size_t)N_NODES * 4);
    float* idi        = (float*)alloc((size_t)N_NODES * 4);
    int*   rowbeg     = (int*)alloc((size_t)N_NODES * 4);
    int*   rowend     = (int*)alloc((size_t)N_NODES * 4);
    float* partials   = (float*)alloc((size_t)GATHER_GRID * 4);
    float* factor     = (float*)alloc(4);
    int*   col        = (int*)alloc((size_t)N_EDGES * 4);
    __half* zsb       = (__half*)alloc((size_t)N_NODES * 64 * 2);
    __half* xh        = (__half*)alloc((size_t)N_NODES * 64 * 2);
    float* outF       = (float*)alloc((size_t)N_NODES * 64 * 4);
    // aliases into outF (partition buffers dead before layer-0 GEMM; outF written by last gather)
    unsigned*      part_dst = (unsigned*)outF;                              // NB*CAP*4 = 8.0 MB
    unsigned char* part_src = (unsigned char*)outF + (size_t)NB * CAP * 4;  // NB*CAP = 2.0 MB

    int* gcur_dst = gcur;
    int* gcur_src = gcur + NB;

    k_zero_i32<<<(2 * NB + 255) / 256, 256, 0, stream>>>(gcur, 2 * NB);
    k_zero_i32<<<(N_GRAPHS * 64 + 255) / 256, 256, 0, stream>>>((int*)out, N_GRAPHS * 64);

    // CSR build: single-pass dual partition, then per-bucket CSR + out-degree (merged)
    int nchunks = (N_EDGES + CH - 1) / CH;  // 782
    k_partition_dual<<<nchunks, 256, 0, stream>>>(esrc, edst, gcur_dst, gcur_src, part_dst, part_src);
    k_scan_buckets<<<1, 512, 0, stream>>>(gcur_dst, bucket_base);
    k_csr_count<<<2 * NB, 256, 0, stream>>>(part_dst, part_src, bucket_base, gcur_src,
                                            rowbeg, rowend, idi, odi, col);

    // layer 0: z = h@W0 (MFMA, odi-scaled fp16) -> gather
    k_gemm_mfma<1><<<GEMM_GRID, 256, 0, stream>>>(h, W0, odi, zsb);
    k_gather<1, 0><<<GATHER_GRID, 256, 0, stream>>>(zsb, rowbeg, rowend, col, idi, b0, xh, nullptr, nullptr);
    // layer 1
    k_gemm_mfma<0><<<GEMM_GRID, 256, 0, stream>>>(xh, W1, odi, zsb);
    k_gather<1, 0><<<GATHER_GRID, 256, 0, stream>>>(zsb, rowbeg, rowend, col, idi, b1, xh, nullptr, nullptr);
    // layer 2 (last: f32 out + norm partials)
    k_gemm_mfma<0><<<GEMM_GRID, 256, 0, stream>>>(xh, W2, odi, zsb);
    k_gather<0, 1><<<GATHER_GRID, 256, 0, stream>>>(zsb, rowbeg, rowend, col, idi, b2, nullptr, outF, partials);

    // factor + pooling
    k_reduce_factor<<<1, 256, 0, stream>>>(partials, factor);
    int poolWaves  = (N_NODES + POOL_CHUNK - 1) / POOL_CHUNK;
    int poolBlocks = (poolWaves + 3) / 4;
    k_pool<<<poolBlocks, 256, 0, stream>>>(outF, gids, factor, out);
}

// Round 9
// 222.403 us; speedup vs baseline: 4.5991x; 1.0746x over previous
//
#include <hip/hip_runtime.h>
#include <hip/hip_fp16.h>

#define N_NODES 100000
#define N_EDGES 1600000
#define N_GRAPHS 2000
#define HID 64
#define NB 391          // final buckets of 256 nodes
#define CAP 5120        // per-bucket capacity (mean 4096; +16 sigma)
#define NSUP 16         // super-buckets of SUPW nodes
#define SUPW 6400       // 25 * 256
#define CAP_S 106496    // per-super capacity (mean 102400, +13 sigma), = 26*4096
#define CH_A 2048
#define NCH_A ((N_EDGES + CH_A - 1) / CH_A)   // 782
#define BCH 4096
#define NCHB 26         // CAP_S / BCH
#define GATHER_GRID 2048
#define GEMM_GRID 512
#define N_GROUPS (N_NODES / 4)   // 25000
#define N_TILE16 (N_NODES / 16)  // 6250 (exact)

typedef _Float16 half8 __attribute__((ext_vector_type(8)));
typedef float f32x4 __attribute__((ext_vector_type(4)));

// ---------------- utility ----------------
__global__ __launch_bounds__(256) void k_zero_i32(int* __restrict__ p, int n) {
    int i = blockIdx.x * 256 + threadIdx.x;
    if (i < n) p[i] = 0;
}

// ---------------- pass A: 16-way super-bucket split (dst u32 entries, src u16 entries) --------
// dst entry: (dstRel<<17)|src  (dstRel<6400 fits 13b, src<2^17); src entry: srcRel (u16)
__global__ __launch_bounds__(256) void k_passA(const int* __restrict__ src, const int* __restrict__ dst,
                                               int* __restrict__ scur_dst, int* __restrict__ scur_src,
                                               unsigned* __restrict__ sup_dst,
                                               unsigned short* __restrict__ sup_src) {
    __shared__ unsigned stD[CH_A];        // 8KB
    __shared__ unsigned short stS[CH_A];  // 4KB
    __shared__ unsigned char binD[CH_A];  // 2KB
    __shared__ unsigned char binS[CH_A];  // 2KB
    __shared__ int lcntD[NSUP], lexD[NSUP], lofD[NSUP], runD[NSUP];
    __shared__ int lcntS[NSUP], lexS[NSUP], lofS[NSUP], runS[NSUP];
    int tid = threadIdx.x;
    int e0 = blockIdx.x * CH_A;
    int n = min(CH_A, N_EDGES - e0);
    if (tid < NSUP) { lcntD[tid] = 0; lcntS[tid] = 0; }
    __syncthreads();
    int sv[8], dv[8];
#pragma unroll
    for (int k = 0; k < 8; ++k) {
        int i = k * 256 + tid;
        if (i < n) { sv[k] = src[e0 + i]; dv[k] = dst[e0 + i]; }
        else dv[k] = -1;
    }
#pragma unroll
    for (int k = 0; k < 8; ++k)
        if (dv[k] >= 0) {
            atomicAdd(&lcntD[dv[k] / SUPW], 1);
            atomicAdd(&lcntS[sv[k] / SUPW], 1);
        }
    __syncthreads();
    if (tid == 0)  { int a = 0; for (int i = 0; i < NSUP; ++i) { lexD[i] = a; lofD[i] = a; a += lcntD[i]; } }
    if (tid == 64) { int a = 0; for (int i = 0; i < NSUP; ++i) { lexS[i] = a; lofS[i] = a; a += lcntS[i]; } }
    __syncthreads();
#pragma unroll
    for (int k = 0; k < 8; ++k)
        if (dv[k] >= 0) {
            int d = dv[k], s = sv[k];
            int bD = d / SUPW;
            int pD = atomicAdd(&lofD[bD], 1);
            stD[pD] = ((unsigned)(d - bD * SUPW) << 17) | (unsigned)s;
            binD[pD] = (unsigned char)bD;
            int bS = s / SUPW;
            int pS = atomicAdd(&lofS[bS], 1);
            stS[pS] = (unsigned short)(s - bS * SUPW);
            binS[pS] = (unsigned char)bS;
        }
    __syncthreads();
    if (tid < NSUP) runD[tid] = lcntD[tid] ? atomicAdd(&scur_dst[tid], lcntD[tid]) : 0;
    if (tid >= 128 && tid < 128 + NSUP) {
        int b = tid - 128;
        runS[b] = lcntS[b] ? atomicAdd(&scur_src[b], lcntS[b]) : 0;
    }
    __syncthreads();
    for (int i = tid; i < n; i += 256) {
        int b = binD[i];
        int pos = runD[b] + (i - lexD[b]);
        if (pos < CAP_S) sup_dst[(size_t)b * CAP_S + pos] = stD[i];
    }
    for (int i = tid; i < n; i += 256) {
        int b = binS[i];
        int pos = runS[b] + (i - lexS[b]);
        if (pos < CAP_S) sup_src[(size_t)b * CAP_S + pos] = stS[i];
    }
}

// ---------------- pass B: refine each super-bucket into its 25 sub-buckets ----------------
// blocks [0, NSUP*NCHB): dst side -> part_dst entries (src<<8)|(node&255)
// blocks [NSUP*NCHB, 2*NSUP*NCHB): src side -> part_src u8 entries (node&255)
__global__ __launch_bounds__(256) void k_passB(const unsigned* __restrict__ sup_dst,
                                               const unsigned short* __restrict__ sup_src,
                                               const int* __restrict__ scur_dst,
                                               const int* __restrict__ scur_src,
                                               int* __restrict__ gcur_dst, int* __restrict__ gcur_src,
                                               unsigned* __restrict__ part_dst,
                                               unsigned char* __restrict__ part_src) {
    __shared__ unsigned st[BCH];        // 16KB (dst); aliased as u8 for src payloads
    __shared__ unsigned char bin[BCH];  // 4KB
    __shared__ int lcnt[25], lex[25], lof[25], run[25];
    int tid = threadIdx.x;
    int isSrc = blockIdx.x >= NSUP * NCHB;
    int bx = isSrc ? blockIdx.x - NSUP * NCHB : blockIdx.x;
    int sb = bx / NCHB, ch = bx % NCHB;
    int total = isSrc ? scur_src[sb] : scur_dst[sb];
    total = min(total, CAP_S);
    int o0 = ch * BCH;
    int n = min(BCH, total - o0);
    if (n <= 0) return;
    int bg0 = sb * 25;
    if (tid < 25) lcnt[tid] = 0;
    __syncthreads();

    if (!isSrc) {
        unsigned ev[16];
        int bb[16];
#pragma unroll
        for (int k = 0; k < 16; ++k) {
            int i = k * 256 + tid;
            if (i < n) {
                unsigned e = sup_dst[(size_t)sb * CAP_S + o0 + i];
                ev[k] = e;
                bb[k] = (int)(e >> 25);  // dstRel>>8
                atomicAdd(&lcnt[bb[k]], 1);
            } else bb[k] = -1;
        }
        __syncthreads();
        if (tid == 0) { int a = 0; for (int i = 0; i < 25; ++i) { lex[i] = a; lof[i] = a; a += lcnt[i]; } }
        __syncthreads();
#pragma unroll
        for (int k = 0; k < 16; ++k)
            if (bb[k] >= 0) {
                unsigned e = ev[k];
                unsigned s = e & 0x1FFFFu;
                unsigned low = (e >> 17) & 255u;
                int p = atomicAdd(&lof[bb[k]], 1);
                st[p] = (s << 8) | low;
                bin[p] = (unsigned char)bb[k];
            }
        __syncthreads();
        if (tid < 25) run[tid] = lcnt[tid] ? atomicAdd(&gcur_dst[bg0 + tid], lcnt[tid]) : 0;
        __syncthreads();
        for (int i = tid; i < n; i += 256) {
            int b = bin[i];
            int pos = run[b] + (i - lex[b]);
            if (pos < CAP) part_dst[(size_t)(bg0 + b) * CAP + pos] = st[i];
        }
    } else {
        unsigned char* st8 = (unsigned char*)st;
        int rv[16];
        int bb[16];
#pragma unroll
        for (int k = 0; k < 16; ++k) {
            int i = k * 256 + tid;
            if (i < n) {
                int r = (int)sup_src[(size_t)sb * CAP_S + o0 + i];
                rv[k] = r;
                bb[k] = r >> 8;
                atomicAdd(&lcnt[bb[k]], 1);
            } else bb[k] = -1;
        }
        __syncthreads();
        if (tid == 0) { int a = 0; for (int i = 0; i < 25; ++i) { lex[i] = a; lof[i] = a; a += lcnt[i]; } }
        __syncthreads();
#pragma unroll
        for (int k = 0; k < 16; ++k)
            if (bb[k] >= 0) {
                int p = atomicAdd(&lof[bb[k]], 1);
                st8[p] = (unsigned char)(rv[k] & 255);
                bin[p] = (unsigned char)bb[k];
            }
        __syncthreads();
        if (tid < 25) run[tid] = lcnt[tid] ? atomicAdd(&gcur_src[bg0 + tid], lcnt[tid]) : 0;
        __syncthreads();
        for (int i = tid; i < n; i += 256) {
            int b = bin[i];
            int pos = run[b] + (i - lex[b]);
            if (pos < CAP) part_src[(size_t)(bg0 + b) * CAP + pos] = st8[i];
        }
    }
}

// ---------------- merged: blocks [0,NB) build dst CSR; [NB,2NB) count out-deg -> odi ----------
// fixed-stride layout: bucket b's col/part region starts at b*CAP (holes allowed; gather uses rowbeg/rowend)
__global__ __launch_bounds__(256) void k_csr_count(const unsigned* __restrict__ part_dst,
                                                   const unsigned char* __restrict__ part_src,
                                                   const int* __restrict__ gcur_dst,
                                                   const int* __restrict__ gcur_src,
                                                   int* __restrict__ rowbeg, int* __restrict__ rowend,
                                                   float* __restrict__ idi, float* __restrict__ odi,
                                                   int* __restrict__ col) {
    __shared__ int cnt[256];
    __shared__ int cur[256];
    __shared__ int wsum[4];
    int tid = threadIdx.x;
    if (blockIdx.x >= NB) {
        int b = blockIdx.x - NB;
        int nE = min(gcur_src[b], CAP);
        const unsigned char* pb = part_src + (size_t)b * CAP;
        cnt[tid] = 0;
        __syncthreads();
        for (int i = tid; i < nE; i += 256) atomicAdd(&cnt[pb[i]], 1);
        __syncthreads();
        int v = b * 256 + tid;
        if (v < N_NODES) odi[v] = rsqrtf((float)max(cnt[tid], 1));
        return;
    }
    int b = blockIdx.x;
    int base = b * CAP;
    int nE = min(gcur_dst[b], CAP);
    const unsigned* pb = part_dst + (size_t)b * CAP;
    cnt[tid] = 0;
    __syncthreads();
    for (int i = tid; i < nE; i += 256) atomicAdd(&cnt[pb[i] & 255], 1);
    __syncthreads();
    int c = cnt[tid];
    int incl = c;
#pragma unroll
    for (int off = 1; off < 64; off <<= 1) {
        int t = __shfl_up(incl, off, 64);
        if ((tid & 63) >= off) incl += t;
    }
    if ((tid & 63) == 63) wsum[tid >> 6] = incl;
    __syncthreads();
    int add = 0;
    for (int w = 0; w < (tid >> 6); ++w) add += wsum[w];
    incl += add;
    int excl = incl - c;
    int v = b * 256 + tid;
    if (v < N_NODES) {
        rowbeg[v] = base + excl;
        rowend[v] = base + incl;
        idi[v] = rsqrtf((float)max(c, 1));
    }
    cur[tid] = excl;
    __syncthreads();
    for (int i = tid; i < nE; i += 256) {
        unsigned e = pb[i];
        int p = atomicAdd(&cur[e & 255], 1);
        col[base + p] = (int)(e >> 8);
    }
}

// ---------------- dense GEMM via MFMA: zs[v] = (x[v] @ W) * odi[v]  (fp16 out) ----------------
template <int F32IN>
__global__ __launch_bounds__(256) void k_gemm_mfma(const void* __restrict__ inv,
                                                   const float* __restrict__ W,
                                                   const float* __restrict__ odi,
                                                   __half* __restrict__ zs) {
    __shared__ _Float16 Wt[64 * 64];  // Wt[j][k] = W[k][j]
    int tid = threadIdx.x;
    for (int i = tid; i < 4096; i += 256) {
        int k = i >> 6, j = i & 63;
        Wt[j * 64 + k] = (_Float16)W[i];
    }
    __syncthreads();

    int lane = tid & 63;
    int wid = tid >> 6;
    int lrow = lane & 15;
    int lgrp = lane >> 4;

    half8 Bf[4][2];
#pragma unroll
    for (int nt = 0; nt < 4; ++nt)
#pragma unroll
        for (int kh = 0; kh < 2; ++kh)
            Bf[nt][kh] = *(half8*)&Wt[(nt * 16 + lrow) * 64 + kh * 32 + lgrp * 8];

    for (int t = blockIdx.x * 4 + wid; t < N_TILE16; t += GEMM_GRID * 4) {
        int v0 = t * 16;
        half8 a0, a1;
        if (F32IN) {
            const float* A = (const float*)inv + (size_t)(v0 + lrow) * 64 + lgrp * 8;
            float4 f0 = *(const float4*)A;
            float4 f1 = *(const float4*)(A + 4);
            float4 g0 = *(const float4*)(A + 32);
            float4 g1 = *(const float4*)(A + 36);
            a0[0] = (_Float16)f0.x; a0[1] = (_Float16)f0.y; a0[2] = (_Float16)f0.z; a0[3] = (_Float16)f0.w;
            a0[4] = (_Float16)f1.x; a0[5] = (_Float16)f1.y; a0[6] = (_Float16)f1.z; a0[7] = (_Float16)f1.w;
            a1[0] = (_Float16)g0.x; a1[1] = (_Float16)g0.y; a1[2] = (_Float16)g0.z; a1[3] = (_Float16)g0.w;
            a1[4] = (_Float16)g1.x; a1[5] = (_Float16)g1.y; a1[6] = (_Float16)g1.z; a1[7] = (_Float16)g1.w;
        } else {
            const _Float16* A = (const _Float16*)inv + (size_t)(v0 + lrow) * 64 + lgrp * 8;
            a0 = *(const half8*)A;
            a1 = *(const half8*)(A + 32);
        }
        f32x4 acc[4];
#pragma unroll
        for (int nt = 0; nt < 4; ++nt) { acc[nt] = (f32x4)0.f; }
#pragma unroll
        for (int nt = 0; nt < 4; ++nt) {
            acc[nt] = __builtin_amdgcn_mfma_f32_16x16x32_f16(a0, Bf[nt][0], acc[nt], 0, 0, 0);
            acc[nt] = __builtin_amdgcn_mfma_f32_16x16x32_f16(a1, Bf[nt][1], acc[nt], 0, 0, 0);
        }
#pragma unroll
        for (int r = 0; r < 4; ++r) {
            int node = v0 + lgrp * 4 + r;
            float w = odi[node];
#pragma unroll
            for (int nt = 0; nt < 4; ++nt)
                zs[(size_t)node * 64 + nt * 16 + lrow] = __float2half_rn(acc[nt][r] * w);
        }
    }
}

// ---------------- gather: out[v] = act( idi[v] * sum_{e:dst=v} zs[src] + b )  (no LDS) -------
template <int RELU, int LAST>
__global__ __launch_bounds__(256) void k_gather(const __half* __restrict__ zs, const int* __restrict__ rowbeg,
                                                const int* __restrict__ rowend, const int* __restrict__ col,
                                                const float* __restrict__ idi, const float* __restrict__ b,
                                                __half* __restrict__ xout, float* __restrict__ outF,
                                                float* __restrict__ partials) {
    __shared__ float part[4];
    int tid = threadIdx.x;
    int lane = tid & 63;
    int wid = tid >> 6;
    float bias = b[lane];
    float nacc = 0.f;

    for (int g = blockIdx.x; g < N_GROUPS; g += GATHER_GRID) {
        int v = __builtin_amdgcn_readfirstlane(g * 4 + wid);
        int beg = rowbeg[v], end = rowend[v];
        float a0 = 0.f, a1 = 0.f, a2 = 0.f, a3 = 0.f;
        int p = beg;
        for (; p + 8 <= end; p += 8) {
            int s0 = col[p + 0], s1 = col[p + 1], s2 = col[p + 2], s3 = col[p + 3];
            int s4 = col[p + 4], s5 = col[p + 5], s6 = col[p + 6], s7 = col[p + 7];
            a0 += __half2float(zs[s0 * 64 + lane]);
            a1 += __half2float(zs[s1 * 64 + lane]);
            a2 += __half2float(zs[s2 * 64 + lane]);
            a3 += __half2float(zs[s3 * 64 + lane]);
            a0 += __half2float(zs[s4 * 64 + lane]);
            a1 += __half2float(zs[s5 * 64 + lane]);
            a2 += __half2float(zs[s6 * 64 + lane]);
            a3 += __half2float(zs[s7 * 64 + lane]);
        }
        if (p < end) {
#pragma unroll
            for (int k = 0; k < 8; ++k) {
                int q = (p + k < end) ? (p + k) : (end - 1);
                float xv = __half2float(zs[col[q] * 64 + lane]);
                xv = (p + k < end) ? xv : 0.f;
                if (k & 2) { if (k & 1) a3 += xv; else a2 += xv; }
                else       { if (k & 1) a1 += xv; else a0 += xv; }
            }
        }
        float o = fmaf(((a0 + a1) + (a2 + a3)), idi[v], bias);
        if (RELU) o = fmaxf(o, 0.f);

        if (LAST) {
            outF[(size_t)v * 64 + lane] = o;
            float s = o * o;
#pragma unroll
            for (int off = 32; off > 0; off >>= 1) s += __shfl_xor(s, off, 64);
            if (lane == 0) nacc += sqrtf(s);
        } else {
            xout[(size_t)v * 64 + lane] = __float2half_rn(o);
        }
    }

    if (LAST) {
        if (lane == 0) part[wid] = nacc;
        __syncthreads();
        if (tid == 0) partials[blockIdx.x] = part[0] + part[1] + part[2] + part[3];
    }
}

__global__ __launch_bounds__(256) void k_reduce_factor(const float* __restrict__ partials,
                                                       float* __restrict__ factor) {
    __shared__ float sd[256];
    int tid = threadIdx.x;
    float s = 0.f;
    for (int i = tid; i < GATHER_GRID; i += 256) s += partials[i];
    sd[tid] = s;
    __syncthreads();
    for (int off = 128; off > 0; off >>= 1) {
        if (tid < off) sd[tid] += sd[tid + off];
        __syncthreads();
    }
    if (tid == 0) factor[0] = 8.0f * (float)N_NODES / sd[0];
}

// ---------------- sum pooling over sorted graph_ids ----------------
#define POOL_CHUNK 32
__global__ __launch_bounds__(256) void k_pool(const float* __restrict__ h, const int* __restrict__ gid,
                                              const float* __restrict__ factor, float* __restrict__ out) {
    int wave = (blockIdx.x * 256 + threadIdx.x) >> 6;
    int lane = threadIdx.x & 63;
    int v0 = wave * POOL_CHUNK;
    if (v0 >= N_NODES) return;
    float f = factor[0];
    int vend = min(v0 + POOL_CHUNK, N_NODES);
    int gprev = gid[v0];
    float acc = 0.f;
    for (int v = v0; v < vend; ++v) {
        int g = gid[v];
        if (g != gprev) {
            atomicAdd(&out[(size_t)gprev * 64 + lane], acc);
            acc = 0.f;
            gprev = g;
        }
        acc = fmaf(h[(size_t)v * 64 + lane], f, acc);
    }
    atomicAdd(&out[(size_t)gprev * 64 + lane], acc);
}

extern "C" void kernel_launch(void* const* d_in, const int* in_sizes, int n_in,
                              void* d_out, int out_size, void* d_ws, size_t ws_size,
                              hipStream_t stream) {
    const float* h    = (const float*)d_in[0];
    const int*   esrc = (const int*)d_in[1];
    const int*   edst = (const int*)d_in[2];
    const int*   gids = (const int*)d_in[3];
    const float* W0 = (const float*)d_in[4];
    const float* b0 = (const float*)d_in[5];
    const float* W1 = (const float*)d_in[6];
    const float* b1 = (const float*)d_in[7];
    const float* W2 = (const float*)d_in[8];
    const float* b2 = (const float*)d_in[9];
    float* out = (float*)d_out;

    char* wsp = (char*)d_ws;
    size_t off = 0;
    auto alloc = [&](size_t bytes) -> void* {
        void* p = wsp + off;
        off += (bytes + 255) & ~(size_t)255;
        return p;
    };
    // cursors: [0,16) sup-dst, [16,32) sup-src, [32,423) sub-dst, [423,814) sub-src
    int*   cursors    = (int*)alloc(814 * 4);
    float* odi        = (float*)alloc((size_t)N_NODES * 4);
    float* idi        = (float*)alloc((size_t)N_NODES * 4);
    int*   rowbeg     = (int*)alloc((size_t)N_NODES * 4);
    int*   rowend     = (int*)alloc((size_t)N_NODES * 4);
    float* partials   = (float*)alloc((size_t)GATHER_GRID * 4);
    float* factor     = (float*)alloc(4);
    int*   col        = (int*)alloc((size_t)NB * CAP * 4);        // 8.0 MB, fixed-stride
    __half* zsb       = (__half*)alloc((size_t)N_NODES * 64 * 2);
    __half* xh        = (__half*)alloc((size_t)N_NODES * 64 * 2);
    float* outF       = (float*)alloc((size_t)N_NODES * 64 * 4);  // 25.6 MB
    // aliases into outF (all dead before layer-0 GEMM; outF written by last gather)
    unsigned*       sup_dst  = (unsigned*)outF;                                   // 6.82 MB
    unsigned short* sup_src  = (unsigned short*)((char*)outF + (size_t)NSUP * CAP_S * 4);           // 3.41 MB
    unsigned*       part_dst = (unsigned*)((char*)outF + (size_t)NSUP * CAP_S * 6);                 // 8.00 MB
    unsigned char*  part_src = (unsigned char*)((char*)outF + (size_t)NSUP * CAP_S * 6 + (size_t)NB * CAP * 4);  // 2.0 MB

    int* scur_dst = cursors;
    int* scur_src = cursors + 16;
    int* gcur_dst = cursors + 32;
    int* gcur_src = cursors + 32 + NB;

    k_zero_i32<<<4, 256, 0, stream>>>(cursors, 814);
    k_zero_i32<<<(N_GRAPHS * 64 + 255) / 256, 256, 0, stream>>>((int*)out, N_GRAPHS * 64);

    // CSR build: two-level radix partition (16 supers -> 25 subs each), then per-bucket CSR/count
    k_passA<<<NCH_A, 256, 0, stream>>>(esrc, edst, scur_dst, scur_src, sup_dst, sup_src);
    k_passB<<<2 * NSUP * NCHB, 256, 0, stream>>>(sup_dst, sup_src, scur_dst, scur_src,
                                                 gcur_dst, gcur_src, part_dst, part_src);
    k_csr_count<<<2 * NB, 256, 0, stream>>>(part_dst, part_src, gcur_dst, gcur_src,
                                            rowbeg, rowend, idi, odi, col);

    // layer 0: z = h@W0 (MFMA, odi-scaled fp16) -> gather
    k_gemm_mfma<1><<<GEMM_GRID, 256, 0, stream>>>(h, W0, odi, zsb);
    k_gather<1, 0><<<GATHER_GRID, 256, 0, stream>>>(zsb, rowbeg, rowend, col, idi, b0, xh, nullptr, nullptr);
    // layer 1
    k_gemm_mfma<0><<<GEMM_GRID, 256, 0, stream>>>(xh, W1, odi, zsb);
    k_gather<1, 0><<<GATHER_GRID, 256, 0, stream>>>(zsb, rowbeg, rowend, col, idi, b1, xh, nullptr, nullptr);
    // layer 2 (last: f32 out + norm partials)
    k_gemm_mfma<0><<<GEMM_GRID, 256, 0, stream>>>(xh, W2, odi, zsb);
    k_gather<0, 1><<<GATHER_GRID, 256, 0, stream>>>(zsb, rowbeg, rowend, col, idi, b2, nullptr, outF, partials);

    // factor + pooling
    k_reduce_factor<<<1, 256, 0, stream>>>(partials, factor);
    int poolWaves  = (N_NODES + POOL_CHUNK - 1) / POOL_CHUNK;
    int poolBlocks = (poolWaves + 3) / 4;
    k_pool<<<poolBlocks, 256, 0, stream>>>(outF, gids, factor, out);
}

// Round 10
// 211.472 us; speedup vs baseline: 4.8368x; 1.0517x over previous
//
#include <hip/hip_runtime.h>
#include <hip/hip_fp16.h>

#define N_NODES 100000
#define N_EDGES 1600000
#define N_GRAPHS 2000
#define HID 64
#define NB 391          // final buckets of 256 nodes
#define CAP 5120        // per-bucket capacity (mean 4096; +16 sigma)
#define NSUP 16         // super-buckets of SUPW nodes
#define SUPW 6400       // 25 * 256
#define CAP_S 106496    // per-super capacity (mean 102400, +13 sigma), = 26*4096
#define CH_A 2048
#define NCH_A ((N_EDGES + CH_A - 1) / CH_A)   // 782
#define BCH 4096
#define NCHB 26         // CAP_S / BCH
#define GATHER_GRID 2048
#define GEMM_GRID 512
#define N_GROUPS (N_NODES / 4)   // 25000
#define N_TILE16 (N_NODES / 16)  // 6250 (exact)

typedef _Float16 half8 __attribute__((ext_vector_type(8)));
typedef float f32x4 __attribute__((ext_vector_type(4)));

// ---------------- utility ----------------
__global__ __launch_bounds__(256) void k_zero_i32(int* __restrict__ p, int n) {
    int i = blockIdx.x * 256 + threadIdx.x;
    if (i < n) p[i] = 0;
}

// ---------------- pass A: 16-way super-bucket split (dst u32 entries, src u16 entries) --------
__global__ __launch_bounds__(256) void k_passA(const int* __restrict__ src, const int* __restrict__ dst,
                                               int* __restrict__ scur_dst, int* __restrict__ scur_src,
                                               unsigned* __restrict__ sup_dst,
                                               unsigned short* __restrict__ sup_src) {
    __shared__ unsigned stD[CH_A];
    __shared__ unsigned short stS[CH_A];
    __shared__ unsigned char binD[CH_A];
    __shared__ unsigned char binS[CH_A];
    __shared__ int lcntD[NSUP], lexD[NSUP], lofD[NSUP], runD[NSUP];
    __shared__ int lcntS[NSUP], lexS[NSUP], lofS[NSUP], runS[NSUP];
    int tid = threadIdx.x;
    int e0 = blockIdx.x * CH_A;
    int n = min(CH_A, N_EDGES - e0);
    if (tid < NSUP) { lcntD[tid] = 0; lcntS[tid] = 0; }
    __syncthreads();
    int sv[8], dv[8];
#pragma unroll
    for (int k = 0; k < 8; ++k) {
        int i = k * 256 + tid;
        if (i < n) { sv[k] = src[e0 + i]; dv[k] = dst[e0 + i]; }
        else dv[k] = -1;
    }
#pragma unroll
    for (int k = 0; k < 8; ++k)
        if (dv[k] >= 0) {
            atomicAdd(&lcntD[dv[k] / SUPW], 1);
            atomicAdd(&lcntS[sv[k] / SUPW], 1);
        }
    __syncthreads();
    if (tid == 0)  { int a = 0; for (int i = 0; i < NSUP; ++i) { lexD[i] = a; lofD[i] = a; a += lcntD[i]; } }
    if (tid == 64) { int a = 0; for (int i = 0; i < NSUP; ++i) { lexS[i] = a; lofS[i] = a; a += lcntS[i]; } }
    __syncthreads();
#pragma unroll
    for (int k = 0; k < 8; ++k)
        if (dv[k] >= 0) {
            int d = dv[k], s = sv[k];
            int bD = d / SUPW;
            int pD = atomicAdd(&lofD[bD], 1);
            stD[pD] = ((unsigned)(d - bD * SUPW) << 17) | (unsigned)s;
            binD[pD] = (unsigned char)bD;
            int bS = s / SUPW;
            int pS = atomicAdd(&lofS[bS], 1);
            stS[pS] = (unsigned short)(s - bS * SUPW);
            binS[pS] = (unsigned char)bS;
        }
    __syncthreads();
    if (tid < NSUP) runD[tid] = lcntD[tid] ? atomicAdd(&scur_dst[tid], lcntD[tid]) : 0;
    if (tid >= 128 && tid < 128 + NSUP) {
        int b = tid - 128;
        runS[b] = lcntS[b] ? atomicAdd(&scur_src[b], lcntS[b]) : 0;
    }
    __syncthreads();
    for (int i = tid; i < n; i += 256) {
        int b = binD[i];
        int pos = runD[b] + (i - lexD[b]);
        if (pos < CAP_S) sup_dst[(size_t)b * CAP_S + pos] = stD[i];
    }
    for (int i = tid; i < n; i += 256) {
        int b = binS[i];
        int pos = runS[b] + (i - lexS[b]);
        if (pos < CAP_S) sup_src[(size_t)b * CAP_S + pos] = stS[i];
    }
}

// ---------------- pass B: refine each super-bucket into its 25 sub-buckets ----------------
__global__ __launch_bounds__(256) void k_passB(const unsigned* __restrict__ sup_dst,
                                               const unsigned short* __restrict__ sup_src,
                                               const int* __restrict__ scur_dst,
                                               const int* __restrict__ scur_src,
                                               int* __restrict__ gcur_dst, int* __restrict__ gcur_src,
                                               unsigned* __restrict__ part_dst,
                                               unsigned char* __restrict__ part_src) {
    __shared__ unsigned st[BCH];
    __shared__ unsigned char bin[BCH];
    __shared__ int lcnt[25], lex[25], lof[25], run[25];
    int tid = threadIdx.x;
    int isSrc = blockIdx.x >= NSUP * NCHB;
    int bx = isSrc ? blockIdx.x - NSUP * NCHB : blockIdx.x;
    int sb = bx / NCHB, ch = bx % NCHB;
    int total = isSrc ? scur_src[sb] : scur_dst[sb];
    total = min(total, CAP_S);
    int o0 = ch * BCH;
    int n = min(BCH, total - o0);
    if (n <= 0) return;
    int bg0 = sb * 25;
    if (tid < 25) lcnt[tid] = 0;
    __syncthreads();

    if (!isSrc) {
        unsigned ev[16];
        int bb[16];
#pragma unroll
        for (int k = 0; k < 16; ++k) {
            int i = k * 256 + tid;
            if (i < n) {
                unsigned e = sup_dst[(size_t)sb * CAP_S + o0 + i];
                ev[k] = e;
                bb[k] = (int)(e >> 25);
                atomicAdd(&lcnt[bb[k]], 1);
            } else bb[k] = -1;
        }
        __syncthreads();
        if (tid == 0) { int a = 0; for (int i = 0; i < 25; ++i) { lex[i] = a; lof[i] = a; a += lcnt[i]; } }
        __syncthreads();
#pragma unroll
        for (int k = 0; k < 16; ++k)
            if (bb[k] >= 0) {
                unsigned e = ev[k];
                unsigned s = e & 0x1FFFFu;
                unsigned low = (e >> 17) & 255u;
                int p = atomicAdd(&lof[bb[k]], 1);
                st[p] = (s << 8) | low;
                bin[p] = (unsigned char)bb[k];
            }
        __syncthreads();
        if (tid < 25) run[tid] = lcnt[tid] ? atomicAdd(&gcur_dst[bg0 + tid], lcnt[tid]) : 0;
        __syncthreads();
        for (int i = tid; i < n; i += 256) {
            int b = bin[i];
            int pos = run[b] + (i - lex[b]);
            if (pos < CAP) part_dst[(size_t)(bg0 + b) * CAP + pos] = st[i];
        }
    } else {
        unsigned char* st8 = (unsigned char*)st;
        int rv[16];
        int bb[16];
#pragma unroll
        for (int k = 0; k < 16; ++k) {
            int i = k * 256 + tid;
            if (i < n) {
                int r = (int)sup_src[(size_t)sb * CAP_S + o0 + i];
                rv[k] = r;
                bb[k] = r >> 8;
                atomicAdd(&lcnt[bb[k]], 1);
            } else bb[k] = -1;
        }
        __syncthreads();
        if (tid == 0) { int a = 0; for (int i = 0; i < 25; ++i) { lex[i] = a; lof[i] = a; a += lcnt[i]; } }
        __syncthreads();
#pragma unroll
        for (int k = 0; k < 16; ++k)
            if (bb[k] >= 0) {
                int p = atomicAdd(&lof[bb[k]], 1);
                st8[p] = (unsigned char)(rv[k] & 255);
                bin[p] = (unsigned char)bb[k];
            }
        __syncthreads();
        if (tid < 25) run[tid] = lcnt[tid] ? atomicAdd(&gcur_src[bg0 + tid], lcnt[tid]) : 0;
        __syncthreads();
        for (int i = tid; i < n; i += 256) {
            int b = bin[i];
            int pos = run[b] + (i - lex[b]);
            if (pos < CAP) part_src[(size_t)(bg0 + b) * CAP + pos] = st8[i];
        }
    }
}

// ---------------- merged: blocks [0,NB) build dst CSR; [NB,2NB) count out-deg -> odi ----------
__global__ __launch_bounds__(256) void k_csr_count(const unsigned* __restrict__ part_dst,
                                                   const unsigned char* __restrict__ part_src,
                                                   const int* __restrict__ gcur_dst,
                                                   const int* __restrict__ gcur_src,
                                                   int* __restrict__ rowbeg, int* __restrict__ rowend,
                                                   float* __restrict__ idi, float* __restrict__ odi,
                                                   int* __restrict__ col) {
    __shared__ int cnt[256];
    __shared__ int cur[256];
    __shared__ int wsum[4];
    int tid = threadIdx.x;
    if (blockIdx.x >= NB) {
        int b = blockIdx.x - NB;
        int nE = min(gcur_src[b], CAP);
        const unsigned char* pb = part_src + (size_t)b * CAP;
        cnt[tid] = 0;
        __syncthreads();
        for (int i = tid; i < nE; i += 256) atomicAdd(&cnt[pb[i]], 1);
        __syncthreads();
        int v = b * 256 + tid;
        if (v < N_NODES) odi[v] = rsqrtf((float)max(cnt[tid], 1));
        return;
    }
    int b = blockIdx.x;
    int base = b * CAP;
    int nE = min(gcur_dst[b], CAP);
    const unsigned* pb = part_dst + (size_t)b * CAP;
    cnt[tid] = 0;
    __syncthreads();
    for (int i = tid; i < nE; i += 256) atomicAdd(&cnt[pb[i] & 255], 1);
    __syncthreads();
    int c = cnt[tid];
    int incl = c;
#pragma unroll
    for (int off = 1; off < 64; off <<= 1) {
        int t = __shfl_up(incl, off, 64);
        if ((tid & 63) >= off) incl += t;
    }
    if ((tid & 63) == 63) wsum[tid >> 6] = incl;
    __syncthreads();
    int add = 0;
    for (int w = 0; w < (tid >> 6); ++w) add += wsum[w];
    incl += add;
    int excl = incl - c;
    int v = b * 256 + tid;
    if (v < N_NODES) {
        rowbeg[v] = base + excl;
        rowend[v] = base + incl;
        idi[v] = rsqrtf((float)max(c, 1));
    }
    cur[tid] = excl;
    __syncthreads();
    for (int i = tid; i < nE; i += 256) {
        unsigned e = pb[i];
        int p = atomicAdd(&cur[e & 255], 1);
        col[base + p] = (int)(e >> 8);
    }
}

// ---------------- dense GEMM via MFMA: zs[v] = (x[v] @ W) * odi[v]  (fp16 out) ----------------
template <int F32IN>
__global__ __launch_bounds__(256) void k_gemm_mfma(const void* __restrict__ inv,
                                                   const float* __restrict__ W,
                                                   const float* __restrict__ odi,
                                                   __half* __restrict__ zs) {
    __shared__ _Float16 Wt[64 * 64];  // Wt[j][k] = W[k][j]
    int tid = threadIdx.x;
    for (int i = tid; i < 4096; i += 256) {
        int k = i >> 6, j = i & 63;
        Wt[j * 64 + k] = (_Float16)W[i];
    }
    __syncthreads();

    int lane = tid & 63;
    int wid = tid >> 6;
    int lrow = lane & 15;
    int lgrp = lane >> 4;

    half8 Bf[4][2];
#pragma unroll
    for (int nt = 0; nt < 4; ++nt)
#pragma unroll
        for (int kh = 0; kh < 2; ++kh)
            Bf[nt][kh] = *(half8*)&Wt[(nt * 16 + lrow) * 64 + kh * 32 + lgrp * 8];

    for (int t = blockIdx.x * 4 + wid; t < N_TILE16; t += GEMM_GRID * 4) {
        int v0 = t * 16;
        half8 a0, a1;
        if (F32IN) {
            const float* A = (const float*)inv + (size_t)(v0 + lrow) * 64 + lgrp * 8;
            float4 f0 = *(const float4*)A;
            float4 f1 = *(const float4*)(A + 4);
            float4 g0 = *(const float4*)(A + 32);
            float4 g1 = *(const float4*)(A + 36);
            a0[0] = (_Float16)f0.x; a0[1] = (_Float16)f0.y; a0[2] = (_Float16)f0.z; a0[3] = (_Float16)f0.w;
            a0[4] = (_Float16)f1.x; a0[5] = (_Float16)f1.y; a0[6] = (_Float16)f1.z; a0[7] = (_Float16)f1.w;
            a1[0] = (_Float16)g0.x; a1[1] = (_Float16)g0.y; a1[2] = (_Float16)g0.z; a1[3] = (_Float16)g0.w;
            a1[4] = (_Float16)g1.x; a1[5] = (_Float16)g1.y; a1[6] = (_Float16)g1.z; a1[7] = (_Float16)g1.w;
        } else {
            const _Float16* A = (const _Float16*)inv + (size_t)(v0 + lrow) * 64 + lgrp * 8;
            a0 = *(const half8*)A;
            a1 = *(const half8*)(A + 32);
        }
        f32x4 acc[4];
#pragma unroll
        for (int nt = 0; nt < 4; ++nt) { acc[nt] = (f32x4)0.f; }
#pragma unroll
        for (int nt = 0; nt < 4; ++nt) {
            acc[nt] = __builtin_amdgcn_mfma_f32_16x16x32_f16(a0, Bf[nt][0], acc[nt], 0, 0, 0);
            acc[nt] = __builtin_amdgcn_mfma_f32_16x16x32_f16(a1, Bf[nt][1], acc[nt], 0, 0, 0);
        }
#pragma unroll
        for (int r = 0; r < 4; ++r) {
            int node = v0 + lgrp * 4 + r;
            float w = odi[node];
#pragma unroll
            for (int nt = 0; nt < 4; ++nt)
                zs[(size_t)node * 64 + nt * 16 + lrow] = __float2half_rn(acc[nt][r] * w);
        }
    }
}

// ---------------- gather: half2 lanes, 2 edges per load instruction ----------------
// lane = (edge-parity half, feature-pair fp): lanes 0-31 even edges, 32-63 odd edges;
// each lane loads __half2 (features 2fp,2fp+1). Final combine: shfl_xor(32).
template <int RELU, int LAST>
__global__ __launch_bounds__(256) void k_gather(const __half* __restrict__ zs, const int* __restrict__ rowbeg,
                                                const int* __restrict__ rowend, const int* __restrict__ col,
                                                const float* __restrict__ idi, const float* __restrict__ b,
                                                __half* __restrict__ xout, float* __restrict__ outF,
                                                float* __restrict__ partials) {
    __shared__ float part[4];
    int tid = threadIdx.x;
    int lane = tid & 63;
    int wid = tid >> 6;
    int half = lane >> 5;   // 0: even edge slot, 1: odd edge slot
    int fp = lane & 31;     // feature-pair
    float2 bias2 = *(const float2*)&b[fp * 2];
    float nacc = 0.f;

    for (int g = blockIdx.x; g < N_GROUPS; g += GATHER_GRID) {
        int v = __builtin_amdgcn_readfirstlane(g * 4 + wid);
        int beg = rowbeg[v], end = rowend[v];
        float2 a0 = {0.f, 0.f}, a1 = {0.f, 0.f}, a2 = {0.f, 0.f}, a3 = {0.f, 0.f};
        int p = beg;
        // main: 8 pair-slots = 16 edges/iter, 8 loads in flight covering 16 edges
        for (; p + 16 <= end; p += 16) {
#pragma unroll
            for (int j = 0; j < 8; ++j) {
                int s = col[p + 2 * j + half];
                float2 f = __half22float2(*((const __half2*)(zs + (size_t)s * 64) + fp));
                if ((j & 3) == 0) { a0.x += f.x; a0.y += f.y; }
                else if ((j & 3) == 1) { a1.x += f.x; a1.y += f.y; }
                else if ((j & 3) == 2) { a2.x += f.x; a2.y += f.y; }
                else { a3.x += f.x; a3.y += f.y; }
            }
        }
        if (p + 8 <= end) {  // unmasked 4-slot granule (8 edges)
#pragma unroll
            for (int j = 0; j < 4; ++j) {
                int s = col[p + 2 * j + half];
                float2 f = __half22float2(*((const __half2*)(zs + (size_t)s * 64) + fp));
                if (j == 0) { a0.x += f.x; a0.y += f.y; }
                else if (j == 1) { a1.x += f.x; a1.y += f.y; }
                else if (j == 2) { a2.x += f.x; a2.y += f.y; }
                else { a3.x += f.x; a3.y += f.y; }
            }
            p += 8;
        }
        if (p < end) {  // masked 4-slot granule (clamped index, zeroed overrun)
#pragma unroll
            for (int j = 0; j < 4; ++j) {
                int e = p + 2 * j + half;
                int q = (e < end) ? e : (end - 1);
                int s = col[q];
                float2 f = __half22float2(*((const __half2*)(zs + (size_t)s * 64) + fp));
                float m = (e < end) ? 1.f : 0.f;
                if (j == 0) { a0.x = fmaf(f.x, m, a0.x); a0.y = fmaf(f.y, m, a0.y); }
                else if (j == 1) { a1.x = fmaf(f.x, m, a1.x); a1.y = fmaf(f.y, m, a1.y); }
                else if (j == 2) { a2.x = fmaf(f.x, m, a2.x); a2.y = fmaf(f.y, m, a2.y); }
                else { a3.x = fmaf(f.x, m, a3.x); a3.y = fmaf(f.y, m, a3.y); }
            }
        }
        float2 a;
        a.x = (a0.x + a1.x) + (a2.x + a3.x);
        a.y = (a0.y + a1.y) + (a2.y + a3.y);
        // combine even/odd halves: both halves end with identical totals
        a.x += __shfl_xor(a.x, 32, 64);
        a.y += __shfl_xor(a.y, 32, 64);
        float iv = idi[v];
        float2 o;
        o.x = fmaf(a.x, iv, bias2.x);
        o.y = fmaf(a.y, iv, bias2.y);
        if (RELU) { o.x = fmaxf(o.x, 0.f); o.y = fmaxf(o.y, 0.f); }

        if (LAST) {
            if (half == 0) *(float2*)&outF[(size_t)v * 64 + fp * 2] = o;
            float s = o.x * o.x + o.y * o.y;  // identical in both halves
#pragma unroll
            for (int off = 32; off > 0; off >>= 1) s += __shfl_xor(s, off, 64);
            if (lane == 0) nacc += sqrtf(0.5f * s);  // halves double-counted
        } else {
            if (half == 0)
                *((__half2*)(xout + (size_t)v * 64) + fp) = __floats2half2_rn(o.x, o.y);
        }
    }

    if (LAST) {
        if (lane == 0) part[wid] = nacc;
        __syncthreads();
        if (tid == 0) partials[blockIdx.x] = part[0] + part[1] + part[2] + part[3];
    }
}

__global__ __launch_bounds__(256) void k_reduce_factor(const float* __restrict__ partials,
                                                       float* __restrict__ factor) {
    __shared__ float sd[256];
    int tid = threadIdx.x;
    float s = 0.f;
    for (int i = tid; i < GATHER_GRID; i += 256) s += partials[i];
    sd[tid] = s;
    __syncthreads();
    for (int off = 128; off > 0; off >>= 1) {
        if (tid < off) sd[tid] += sd[tid + off];
        __syncthreads();
    }
    if (tid == 0) factor[0] = 8.0f * (float)N_NODES / sd[0];
}

// ---------------- sum pooling over sorted graph_ids ----------------
#define POOL_CHUNK 32
__global__ __launch_bounds__(256) void k_pool(const float* __restrict__ h, const int* __restrict__ gid,
                                              const float* __restrict__ factor, float* __restrict__ out) {
    int wave = (blockIdx.x * 256 + threadIdx.x) >> 6;
    int lane = threadIdx.x & 63;
    int v0 = wave * POOL_CHUNK;
    if (v0 >= N_NODES) return;
    float f = factor[0];
    int vend = min(v0 + POOL_CHUNK, N_NODES);
    int gprev = gid[v0];
    float acc = 0.f;
    for (int v = v0; v < vend; ++v) {
        int g = gid[v];
        if (g != gprev) {
            atomicAdd(&out[(size_t)gprev * 64 + lane], acc);
            acc = 0.f;
            gprev = g;
        }
        acc = fmaf(h[(size_t)v * 64 + lane], f, acc);
    }
    atomicAdd(&out[(size_t)gprev * 64 + lane], acc);
}

extern "C" void kernel_launch(void* const* d_in, const int* in_sizes, int n_in,
                              void* d_out, int out_size, void* d_ws, size_t ws_size,
                              hipStream_t stream) {
    const float* h    = (const float*)d_in[0];
    const int*   esrc = (const int*)d_in[1];
    const int*   edst = (const int*)d_in[2];
    const int*   gids = (const int*)d_in[3];
    const float* W0 = (const float*)d_in[4];
    const float* b0 = (const float*)d_in[5];
    const float* W1 = (const float*)d_in[6];
    const float* b1 = (const float*)d_in[7];
    const float* W2 = (const float*)d_in[8];
    const float* b2 = (const float*)d_in[9];
    float* out = (float*)d_out;

    char* wsp = (char*)d_ws;
    size_t off = 0;
    auto alloc = [&](size_t bytes) -> void* {
        void* p = wsp + off;
        off += (bytes + 255) & ~(size_t)255;
        return p;
    };
    // cursors: [0,16) sup-dst, [16,32) sup-src, [32,423) sub-dst, [423,814) sub-src
    int*   cursors    = (int*)alloc(814 * 4);
    float* odi        = (float*)alloc((size_t)N_NODES * 4);
    float* idi        = (float*)alloc((size_t)N_NODES * 4);
    int*   rowbeg     = (int*)alloc((size_t)N_NODES * 4);
    int*   rowend     = (int*)alloc((size_t)N_NODES * 4);
    float* partials   = (float*)alloc((size_t)GATHER_GRID * 4);
    float* factor     = (float*)alloc(4);
    int*   col        = (int*)alloc((size_t)NB * CAP * 4);        // 8.0 MB, fixed-stride
    __half* zsb       = (__half*)alloc((size_t)N_NODES * 64 * 2);
    __half* xh        = (__half*)alloc((size_t)N_NODES * 64 * 2);
    float* outF       = (float*)alloc((size_t)N_NODES * 64 * 4);  // 25.6 MB
    // aliases into outF (all dead before layer-0 GEMM; outF written by last gather)
    unsigned*       sup_dst  = (unsigned*)outF;                                   // 6.82 MB
    unsigned short* sup_src  = (unsigned short*)((char*)outF + (size_t)NSUP * CAP_S * 4);           // 3.41 MB
    unsigned*       part_dst = (unsigned*)((char*)outF + (size_t)NSUP * CAP_S * 6);                 // 8.00 MB
    unsigned char*  part_src = (unsigned char*)((char*)outF + (size_t)NSUP * CAP_S * 6 + (size_t)NB * CAP * 4);  // 2.0 MB

    int* scur_dst = cursors;
    int* scur_src = cursors + 16;
    int* gcur_dst = cursors + 32;
    int* gcur_src = cursors + 32 + NB;

    k_zero_i32<<<4, 256, 0, stream>>>(cursors, 814);
    k_zero_i32<<<(N_GRAPHS * 64 + 255) / 256, 256, 0, stream>>>((int*)out, N_GRAPHS * 64);

    // CSR build: two-level radix partition (16 supers -> 25 subs each), then per-bucket CSR/count
    k_passA<<<NCH_A, 256, 0, stream>>>(esrc, edst, scur_dst, scur_src, sup_dst, sup_src);
    k_passB<<<2 * NSUP * NCHB, 256, 0, stream>>>(sup_dst, sup_src, scur_dst, scur_src,
                                                 gcur_dst, gcur_src, part_dst, part_src);
    k_csr_count<<<2 * NB, 256, 0, stream>>>(part_dst, part_src, gcur_dst, gcur_src,
                                            rowbeg, rowend, idi, odi, col);

    // layer 0: z = h@W0 (MFMA, odi-scaled fp16) -> gather
    k_gemm_mfma<1><<<GEMM_GRID, 256, 0, stream>>>(h, W0, odi, zsb);
    k_gather<1, 0><<<GATHER_GRID, 256, 0, stream>>>(zsb, rowbeg, rowend, col, idi, b0, xh, nullptr, nullptr);
    // layer 1
    k_gemm_mfma<0><<<GEMM_GRID, 256, 0, stream>>>(xh, W1, odi, zsb);
    k_gather<1, 0><<<GATHER_GRID, 256, 0, stream>>>(zsb, rowbeg, rowend, col, idi, b1, xh, nullptr, nullptr);
    // layer 2 (last: f32 out + norm partials)
    k_gemm_mfma<0><<<GEMM_GRID, 256, 0, stream>>>(xh, W2, odi, zsb);
    k_gather<0, 1><<<GATHER_GRID, 256, 0, stream>>>(zsb, rowbeg, rowend, col, idi, b2, nullptr, outF, partials);

    // factor + pooling
    k_reduce_factor<<<1, 256, 0, stream>>>(partials, factor);
    int poolWaves  = (N_NODES + POOL_CHUNK - 1) / POOL_CHUNK;
    int poolBlocks = (poolWaves + 3) / 4;
    k_pool<<<poolBlocks, 256, 0, stream>>>(outF, gids, factor, out);
}

// Round 11
// 206.456 us; speedup vs baseline: 4.9543x; 1.0243x over previous
//
#include <hip/hip_runtime.h>
#include <hip/hip_fp16.h>

#define N_NODES 100000
#define N_EDGES 1600000
#define N_GRAPHS 2000
#define HID 64
#define NB 391          // final buckets of 256 nodes
#define CAP 5120        // per-bucket capacity (mean 4096; +16 sigma)
#define NSUP 16         // super-buckets of SUPW nodes
#define SUPW 6400       // 25 * 256
#define CAP_S 106496    // per-super capacity (mean 102400, +13 sigma), = 26*4096
#define CH_A 2048
#define NCH_A ((N_EDGES + CH_A - 1) / CH_A)   // 782
#define BCH 4096
#define NCHB 26         // CAP_S / BCH
#define GATHER_GRID 2048
#define GEMM_GRID 512
#define N_GROUPS (N_NODES / 4)   // 25000
#define N_TILE16 (N_NODES / 16)  // 6250 (exact)

typedef _Float16 half8 __attribute__((ext_vector_type(8)));
typedef float f32x4 __attribute__((ext_vector_type(4)));

// ---------------- utility: zero two ranges in one launch ----------------
__global__ __launch_bounds__(256) void k_zero2(int* __restrict__ p1, int n1,
                                               int* __restrict__ p2, int n2) {
    int i = blockIdx.x * 256 + threadIdx.x;
    if (i < n1) p1[i] = 0;
    if (i < n2) p2[i] = 0;
}

// ---------------- pass A: 16-way super-bucket split (dst u32 entries, src u16 entries) --------
__global__ __launch_bounds__(256) void k_passA(const int* __restrict__ src, const int* __restrict__ dst,
                                               int* __restrict__ scur_dst, int* __restrict__ scur_src,
                                               unsigned* __restrict__ sup_dst,
                                               unsigned short* __restrict__ sup_src) {
    __shared__ unsigned stD[CH_A];
    __shared__ unsigned short stS[CH_A];
    __shared__ unsigned char binD[CH_A];
    __shared__ unsigned char binS[CH_A];
    __shared__ int lcntD[NSUP], lexD[NSUP], lofD[NSUP], runD[NSUP];
    __shared__ int lcntS[NSUP], lexS[NSUP], lofS[NSUP], runS[NSUP];
    int tid = threadIdx.x;
    int e0 = blockIdx.x * CH_A;
    int n = min(CH_A, N_EDGES - e0);
    if (tid < NSUP) { lcntD[tid] = 0; lcntS[tid] = 0; }
    __syncthreads();
    int sv[8], dv[8];
#pragma unroll
    for (int k = 0; k < 8; ++k) {
        int i = k * 256 + tid;
        if (i < n) { sv[k] = src[e0 + i]; dv[k] = dst[e0 + i]; }
        else dv[k] = -1;
    }
#pragma unroll
    for (int k = 0; k < 8; ++k)
        if (dv[k] >= 0) {
            atomicAdd(&lcntD[dv[k] / SUPW], 1);
            atomicAdd(&lcntS[sv[k] / SUPW], 1);
        }
    __syncthreads();
    if (tid == 0)  { int a = 0; for (int i = 0; i < NSUP; ++i) { lexD[i] = a; lofD[i] = a; a += lcntD[i]; } }
    if (tid == 64) { int a = 0; for (int i = 0; i < NSUP; ++i) { lexS[i] = a; lofS[i] = a; a += lcntS[i]; } }
    __syncthreads();
#pragma unroll
    for (int k = 0; k < 8; ++k)
        if (dv[k] >= 0) {
            int d = dv[k], s = sv[k];
            int bD = d / SUPW;
            int pD = atomicAdd(&lofD[bD], 1);
            stD[pD] = ((unsigned)(d - bD * SUPW) << 17) | (unsigned)s;
            binD[pD] = (unsigned char)bD;
            int bS = s / SUPW;
            int pS = atomicAdd(&lofS[bS], 1);
            stS[pS] = (unsigned short)(s - bS * SUPW);
            binS[pS] = (unsigned char)bS;
        }
    __syncthreads();
    if (tid < NSUP) runD[tid] = lcntD[tid] ? atomicAdd(&scur_dst[tid], lcntD[tid]) : 0;
    if (tid >= 128 && tid < 128 + NSUP) {
        int b = tid - 128;
        runS[b] = lcntS[b] ? atomicAdd(&scur_src[b], lcntS[b]) : 0;
    }
    __syncthreads();
    for (int i = tid; i < n; i += 256) {
        int b = binD[i];
        int pos = runD[b] + (i - lexD[b]);
        if (pos < CAP_S) sup_dst[(size_t)b * CAP_S + pos] = stD[i];
    }
    for (int i = tid; i < n; i += 256) {
        int b = binS[i];
        int pos = runS[b] + (i - lexS[b]);
        if (pos < CAP_S) sup_src[(size_t)b * CAP_S + pos] = stS[i];
    }
}

// ---------------- pass B: refine each super-bucket into its 25 sub-buckets ----------------
__global__ __launch_bounds__(256) void k_passB(const unsigned* __restrict__ sup_dst,
                                               const unsigned short* __restrict__ sup_src,
                                               const int* __restrict__ scur_dst,
                                               const int* __restrict__ scur_src,
                                               int* __restrict__ gcur_dst, int* __restrict__ gcur_src,
                                               unsigned* __restrict__ part_dst,
                                               unsigned char* __restrict__ part_src) {
    __shared__ unsigned st[BCH];
    __shared__ unsigned char bin[BCH];
    __shared__ int lcnt[25], lex[25], lof[25], run[25];
    int tid = threadIdx.x;
    int isSrc = blockIdx.x >= NSUP * NCHB;
    int bx = isSrc ? blockIdx.x - NSUP * NCHB : blockIdx.x;
    int sb = bx / NCHB, ch = bx % NCHB;
    int total = isSrc ? scur_src[sb] : scur_dst[sb];
    total = min(total, CAP_S);
    int o0 = ch * BCH;
    int n = min(BCH, total - o0);
    if (n <= 0) return;
    int bg0 = sb * 25;
    if (tid < 25) lcnt[tid] = 0;
    __syncthreads();

    if (!isSrc) {
        unsigned ev[16];
        int bb[16];
#pragma unroll
        for (int k = 0; k < 16; ++k) {
            int i = k * 256 + tid;
            if (i < n) {
                unsigned e = sup_dst[(size_t)sb * CAP_S + o0 + i];
                ev[k] = e;
                bb[k] = (int)(e >> 25);
                atomicAdd(&lcnt[bb[k]], 1);
            } else bb[k] = -1;
        }
        __syncthreads();
        if (tid == 0) { int a = 0; for (int i = 0; i < 25; ++i) { lex[i] = a; lof[i] = a; a += lcnt[i]; } }
        __syncthreads();
#pragma unroll
        for (int k = 0; k < 16; ++k)
            if (bb[k] >= 0) {
                unsigned e = ev[k];
                unsigned s = e & 0x1FFFFu;
                unsigned low = (e >> 17) & 255u;
                int p = atomicAdd(&lof[bb[k]], 1);
                st[p] = (s << 8) | low;
                bin[p] = (unsigned char)bb[k];
            }
        __syncthreads();
        if (tid < 25) run[tid] = lcnt[tid] ? atomicAdd(&gcur_dst[bg0 + tid], lcnt[tid]) : 0;
        __syncthreads();
        for (int i = tid; i < n; i += 256) {
            int b = bin[i];
            int pos = run[b] + (i - lex[b]);
            if (pos < CAP) part_dst[(size_t)(bg0 + b) * CAP + pos] = st[i];
        }
    } else {
        unsigned char* st8 = (unsigned char*)st;
        int rv[16];
        int bb[16];
#pragma unroll
        for (int k = 0; k < 16; ++k) {
            int i = k * 256 + tid;
            if (i < n) {
                int r = (int)sup_src[(size_t)sb * CAP_S + o0 + i];
                rv[k] = r;
                bb[k] = r >> 8;
                atomicAdd(&lcnt[bb[k]], 1);
            } else bb[k] = -1;
        }
        __syncthreads();
        if (tid == 0) { int a = 0; for (int i = 0; i < 25; ++i) { lex[i] = a; lof[i] = a; a += lcnt[i]; } }
        __syncthreads();
#pragma unroll
        for (int k = 0; k < 16; ++k)
            if (bb[k] >= 0) {
                int p = atomicAdd(&lof[bb[k]], 1);
                st8[p] = (unsigned char)(rv[k] & 255);
                bin[p] = (unsigned char)bb[k];
            }
        __syncthreads();
        if (tid < 25) run[tid] = lcnt[tid] ? atomicAdd(&gcur_src[bg0 + tid], lcnt[tid]) : 0;
        __syncthreads();
        for (int i = tid; i < n; i += 256) {
            int b = bin[i];
            int pos = run[b] + (i - lex[b]);
            if (pos < CAP) part_src[(size_t)(bg0 + b) * CAP + pos] = st8[i];
        }
    }
}

// ---------------- merged: blocks [0,NB) build dst CSR; [NB,2NB) count out-deg -> odi ----------
__global__ __launch_bounds__(256) void k_csr_count(const unsigned* __restrict__ part_dst,
                                                   const unsigned char* __restrict__ part_src,
                                                   const int* __restrict__ gcur_dst,
                                                   const int* __restrict__ gcur_src,
                                                   int* __restrict__ rowbeg, int* __restrict__ rowend,
                                                   float* __restrict__ idi, float* __restrict__ odi,
                                                   int* __restrict__ col) {
    __shared__ int cnt[256];
    __shared__ int cur[256];
    __shared__ int wsum[4];
    int tid = threadIdx.x;
    if (blockIdx.x >= NB) {
        int b = blockIdx.x - NB;
        int nE = min(gcur_src[b], CAP);
        const unsigned char* pb = part_src + (size_t)b * CAP;
        cnt[tid] = 0;
        __syncthreads();
        for (int i = tid; i < nE; i += 256) atomicAdd(&cnt[pb[i]], 1);
        __syncthreads();
        int v = b * 256 + tid;
        if (v < N_NODES) odi[v] = rsqrtf((float)max(cnt[tid], 1));
        return;
    }
    int b = blockIdx.x;
    int base = b * CAP;
    int nE = min(gcur_dst[b], CAP);
    const unsigned* pb = part_dst + (size_t)b * CAP;
    cnt[tid] = 0;
    __syncthreads();
    for (int i = tid; i < nE; i += 256) atomicAdd(&cnt[pb[i] & 255], 1);
    __syncthreads();
    int c = cnt[tid];
    int incl = c;
#pragma unroll
    for (int off = 1; off < 64; off <<= 1) {
        int t = __shfl_up(incl, off, 64);
        if ((tid & 63) >= off) incl += t;
    }
    if ((tid & 63) == 63) wsum[tid >> 6] = incl;
    __syncthreads();
    int add = 0;
    for (int w = 0; w < (tid >> 6); ++w) add += wsum[w];
    incl += add;
    int excl = incl - c;
    int v = b * 256 + tid;
    if (v < N_NODES) {
        rowbeg[v] = base + excl;
        rowend[v] = base + incl;
        idi[v] = rsqrtf((float)max(c, 1));
    }
    cur[tid] = excl;
    __syncthreads();
    for (int i = tid; i < nE; i += 256) {
        unsigned e = pb[i];
        int p = atomicAdd(&cur[e & 255], 1);
        col[base + p] = (int)(e >> 8);
    }
}

// ---------------- dense GEMM via MFMA: zs[v] = (x[v] @ W) * odi[v]  (fp16 out) ----------------
template <int F32IN>
__global__ __launch_bounds__(256) void k_gemm_mfma(const void* __restrict__ inv,
                                                   const float* __restrict__ W,
                                                   const float* __restrict__ odi,
                                                   __half* __restrict__ zs) {
    __shared__ _Float16 Wt[64 * 64];  // Wt[j][k] = W[k][j]
    int tid = threadIdx.x;
    for (int i = tid; i < 4096; i += 256) {
        int k = i >> 6, j = i & 63;
        Wt[j * 64 + k] = (_Float16)W[i];
    }
    __syncthreads();

    int lane = tid & 63;
    int wid = tid >> 6;
    int lrow = lane & 15;
    int lgrp = lane >> 4;

    half8 Bf[4][2];
#pragma unroll
    for (int nt = 0; nt < 4; ++nt)
#pragma unroll
        for (int kh = 0; kh < 2; ++kh)
            Bf[nt][kh] = *(half8*)&Wt[(nt * 16 + lrow) * 64 + kh * 32 + lgrp * 8];

    for (int t = blockIdx.x * 4 + wid; t < N_TILE16; t += GEMM_GRID * 4) {
        int v0 = t * 16;
        half8 a0, a1;
        if (F32IN) {
            const float* A = (const float*)inv + (size_t)(v0 + lrow) * 64 + lgrp * 8;
            float4 f0 = *(const float4*)A;
            float4 f1 = *(const float4*)(A + 4);
            float4 g0 = *(const float4*)(A + 32);
            float4 g1 = *(const float4*)(A + 36);
            a0[0] = (_Float16)f0.x; a0[1] = (_Float16)f0.y; a0[2] = (_Float16)f0.z; a0[3] = (_Float16)f0.w;
            a0[4] = (_Float16)f1.x; a0[5] = (_Float16)f1.y; a0[6] = (_Float16)f1.z; a0[7] = (_Float16)f1.w;
            a1[0] = (_Float16)g0.x; a1[1] = (_Float16)g0.y; a1[2] = (_Float16)g0.z; a1[3] = (_Float16)g0.w;
            a1[4] = (_Float16)g1.x; a1[5] = (_Float16)g1.y; a1[6] = (_Float16)g1.z; a1[7] = (_Float16)g1.w;
        } else {
            const _Float16* A = (const _Float16*)inv + (size_t)(v0 + lrow) * 64 + lgrp * 8;
            a0 = *(const half8*)A;
            a1 = *(const half8*)(A + 32);
        }
        f32x4 acc[4];
#pragma unroll
        for (int nt = 0; nt < 4; ++nt) { acc[nt] = (f32x4)0.f; }
#pragma unroll
        for (int nt = 0; nt < 4; ++nt) {
            acc[nt] = __builtin_amdgcn_mfma_f32_16x16x32_f16(a0, Bf[nt][0], acc[nt], 0, 0, 0);
            acc[nt] = __builtin_amdgcn_mfma_f32_16x16x32_f16(a1, Bf[nt][1], acc[nt], 0, 0, 0);
        }
#pragma unroll
        for (int r = 0; r < 4; ++r) {
            int node = v0 + lgrp * 4 + r;
            float w = odi[node];
#pragma unroll
            for (int nt = 0; nt < 4; ++nt)
                zs[(size_t)node * 64 + nt * 16 + lrow] = __float2half_rn(acc[nt][r] * w);
        }
    }
}

// ---------------- gather v3: one coalesced col load per node + shfl-distributed srcs ----------
// lane = (edge-parity half, feature-pair fp). Lane l holds c = col[beg+min(l,deg-1)];
// pair-slot m's src for this lane = __shfl(c, 2m+half). Fallback to direct loads for deg>64.
template <int RELU, int LAST>
__global__ __launch_bounds__(256) void k_gather(const __half* __restrict__ zs, const int* __restrict__ rowbeg,
                                                const int* __restrict__ rowend, const int* __restrict__ col,
                                                const float* __restrict__ idi, const float* __restrict__ b,
                                                __half* __restrict__ xout, float* __restrict__ partials) {
    __shared__ float part[4];
    int tid = threadIdx.x;
    int lane = tid & 63;
    int wid = tid >> 6;
    int half = lane >> 5;   // 0: even edge slot, 1: odd edge slot
    int fp = lane & 31;     // feature-pair
    float2 bias2 = *(const float2*)&b[fp * 2];
    float nacc = 0.f;

    for (int g = blockIdx.x; g < N_GROUPS; g += GATHER_GRID) {
        int v = __builtin_amdgcn_readfirstlane(g * 4 + wid);
        int beg = rowbeg[v], end = rowend[v];
        int deg = end - beg;
        int degS = min(deg, 64);  // edges served by the shfl path
        int c = col[beg + min(lane, max(degS - 1, 0))];  // one coalesced load
        float2 a0 = {0.f, 0.f}, a1 = {0.f, 0.f}, a2 = {0.f, 0.f}, a3 = {0.f, 0.f};
        int m = 0;  // pair-slot index; slot m covers edges 2m (half 0), 2m+1 (half 1)
        // bulk: 8 slots = 16 edges per iter
        for (; (m + 8) * 2 <= degS; m += 8) {
#pragma unroll
            for (int j = 0; j < 8; ++j) {
                int s = __shfl(c, 2 * (m + j) + half, 64);
                float2 f = __half22float2(*((const __half2*)(zs + (size_t)s * 64) + fp));
                if ((j & 3) == 0) { a0.x += f.x; a0.y += f.y; }
                else if ((j & 3) == 1) { a1.x += f.x; a1.y += f.y; }
                else if ((j & 3) == 2) { a2.x += f.x; a2.y += f.y; }
                else { a3.x += f.x; a3.y += f.y; }
            }
        }
        if ((m + 4) * 2 <= degS) {  // unmasked 4-slot granule
#pragma unroll
            for (int j = 0; j < 4; ++j) {
                int s = __shfl(c, 2 * (m + j) + half, 64);
                float2 f = __half22float2(*((const __half2*)(zs + (size_t)s * 64) + fp));
                if (j == 0) { a0.x += f.x; a0.y += f.y; }
                else if (j == 1) { a1.x += f.x; a1.y += f.y; }
                else if (j == 2) { a2.x += f.x; a2.y += f.y; }
                else { a3.x += f.x; a3.y += f.y; }
            }
            m += 4;
        }
        if (m * 2 < degS) {  // masked 4-slot granule (≤ 7 edges left)
#pragma unroll
            for (int j = 0; j < 4; ++j) {
                int e = 2 * (m + j) + half;
                int ee = (e < degS) ? e : (degS - 1);
                int s = __shfl(c, ee, 64);
                float2 f = __half22float2(*((const __half2*)(zs + (size_t)s * 64) + fp));
                float msk = (e < degS) ? 1.f : 0.f;
                if (j == 0) { a0.x = fmaf(f.x, msk, a0.x); a0.y = fmaf(f.y, msk, a0.y); }
                else if (j == 1) { a1.x = fmaf(f.x, msk, a1.x); a1.y = fmaf(f.y, msk, a1.y); }
                else if (j == 2) { a2.x = fmaf(f.x, msk, a2.x); a2.y = fmaf(f.y, msk, a2.y); }
                else { a3.x = fmaf(f.x, msk, a3.x); a3.y = fmaf(f.y, msk, a3.y); }
            }
        }
        if (deg > 64) {  // rare fallback: direct per-edge col loads for the remainder
            for (int p = beg + 64; p < end; p += 8) {
#pragma unroll
                for (int j = 0; j < 4; ++j) {
                    int e = p + 2 * j + half;
                    int q = (e < end) ? e : (end - 1);
                    int s = col[q];
                    float2 f = __half22float2(*((const __half2*)(zs + (size_t)s * 64) + fp));
                    float msk = (e < end) ? 1.f : 0.f;
                    a0.x = fmaf(f.x, msk, a0.x); a0.y = fmaf(f.y, msk, a0.y);
                }
            }
        }
        float2 a;
        a.x = (a0.x + a1.x) + (a2.x + a3.x);
        a.y = (a0.y + a1.y) + (a2.y + a3.y);
        a.x += __shfl_xor(a.x, 32, 64);
        a.y += __shfl_xor(a.y, 32, 64);
        float iv = idi[v];
        float2 o;
        o.x = fmaf(a.x, iv, bias2.x);
        o.y = fmaf(a.y, iv, bias2.y);
        if (RELU) { o.x = fmaxf(o.x, 0.f); o.y = fmaxf(o.y, 0.f); }

        if (half == 0)
            *((__half2*)(xout + (size_t)v * 64) + fp) = __floats2half2_rn(o.x, o.y);

        if (LAST) {
            float s = o.x * o.x + o.y * o.y;  // both halves identical
#pragma unroll
            for (int off = 32; off > 0; off >>= 1) s += __shfl_xor(s, off, 64);
            if (lane == 0) nacc += sqrtf(0.5f * s);  // halves double-counted
        }
    }

    if (LAST) {
        if (lane == 0) part[wid] = nacc;
        __syncthreads();
        if (tid == 0) partials[blockIdx.x] = part[0] + part[1] + part[2] + part[3];
    }
}

__global__ __launch_bounds__(256) void k_reduce_factor(const float* __restrict__ partials,
                                                       float* __restrict__ factor) {
    __shared__ float sd[256];
    int tid = threadIdx.x;
    float s = 0.f;
    for (int i = tid; i < GATHER_GRID; i += 256) s += partials[i];
    sd[tid] = s;
    __syncthreads();
    for (int off = 128; off > 0; off >>= 1) {
        if (tid < off) sd[tid] += sd[tid + off];
        __syncthreads();
    }
    if (tid == 0) factor[0] = 8.0f * (float)N_NODES / sd[0];
}

// ---------------- sum pooling over sorted graph_ids (fp16 input) ----------------
#define POOL_CHUNK 32
__global__ __launch_bounds__(256) void k_pool(const __half* __restrict__ h, const int* __restrict__ gid,
                                              const float* __restrict__ factor, float* __restrict__ out) {
    int wave = (blockIdx.x * 256 + threadIdx.x) >> 6;
    int lane = threadIdx.x & 63;
    int v0 = wave * POOL_CHUNK;
    if (v0 >= N_NODES) return;
    float f = factor[0];
    int vend = min(v0 + POOL_CHUNK, N_NODES);
    int gprev = gid[v0];
    float acc = 0.f;
    for (int v = v0; v < vend; ++v) {
        int g = gid[v];
        if (g != gprev) {
            atomicAdd(&out[(size_t)gprev * 64 + lane], acc);
            acc = 0.f;
            gprev = g;
        }
        acc = fmaf(__half2float(h[(size_t)v * 64 + lane]), f, acc);
    }
    atomicAdd(&out[(size_t)gprev * 64 + lane], acc);
}

extern "C" void kernel_launch(void* const* d_in, const int* in_sizes, int n_in,
                              void* d_out, int out_size, void* d_ws, size_t ws_size,
                              hipStream_t stream) {
    const float* h    = (const float*)d_in[0];
    const int*   esrc = (const int*)d_in[1];
    const int*   edst = (const int*)d_in[2];
    const int*   gids = (const int*)d_in[3];
    const float* W0 = (const float*)d_in[4];
    const float* b0 = (const float*)d_in[5];
    const float* W1 = (const float*)d_in[6];
    const float* b1 = (const float*)d_in[7];
    const float* W2 = (const float*)d_in[8];
    const float* b2 = (const float*)d_in[9];
    float* out = (float*)d_out;

    char* wsp = (char*)d_ws;
    size_t off = 0;
    auto alloc = [&](size_t bytes) -> void* {
        void* p = wsp + off;
        off += (bytes + 255) & ~(size_t)255;
        return p;
    };
    // cursors: [0,16) sup-dst, [16,32) sup-src, [32,423) sub-dst, [423,814) sub-src
    int*   cursors    = (int*)alloc(814 * 4);
    float* odi        = (float*)alloc((size_t)N_NODES * 4);
    float* idi        = (float*)alloc((size_t)N_NODES * 4);
    int*   rowbeg     = (int*)alloc((size_t)N_NODES * 4);
    int*   rowend     = (int*)alloc((size_t)N_NODES * 4);
    float* partials   = (float*)alloc((size_t)GATHER_GRID * 4);
    float* factor     = (float*)alloc(4);
    int*   col        = (int*)alloc((size_t)NB * CAP * 4);          // 8.0 MB, fixed-stride
    __half* zsb       = (__half*)alloc((size_t)N_NODES * 64 * 2);   // 12.8 MB
    __half* xh        = (__half*)alloc((size_t)N_NODES * 64 * 2);   // 12.8 MB (final h lives here too)
    unsigned*       sup_dst  = (unsigned*)alloc((size_t)NSUP * CAP_S * 4);        // 6.82 MB
    unsigned short* sup_src  = (unsigned short*)alloc((size_t)NSUP * CAP_S * 2);  // 3.41 MB
    unsigned*       part_dst = (unsigned*)alloc((size_t)NB * CAP * 4);            // 8.00 MB
    unsigned char*  part_src = (unsigned char*)alloc((size_t)NB * CAP);           // 2.00 MB

    int* scur_dst = cursors;
    int* scur_src = cursors + 16;
    int* gcur_dst = cursors + 32;
    int* gcur_src = cursors + 32 + NB;

    k_zero2<<<(N_GRAPHS * 64 + 255) / 256, 256, 0, stream>>>(cursors, 814, (int*)out, N_GRAPHS * 64);

    // CSR build: two-level radix partition (16 supers -> 25 subs each), then per-bucket CSR/count
    k_passA<<<NCH_A, 256, 0, stream>>>(esrc, edst, scur_dst, scur_src, sup_dst, sup_src);
    k_passB<<<2 * NSUP * NCHB, 256, 0, stream>>>(sup_dst, sup_src, scur_dst, scur_src,
                                                 gcur_dst, gcur_src, part_dst, part_src);
    k_csr_count<<<2 * NB, 256, 0, stream>>>(part_dst, part_src, gcur_dst, gcur_src,
                                            rowbeg, rowend, idi, odi, col);

    // layer 0: z = h@W0 (MFMA, odi-scaled fp16) -> gather
    k_gemm_mfma<1><<<GEMM_GRID, 256, 0, stream>>>(h, W0, odi, zsb);
    k_gather<1, 0><<<GATHER_GRID, 256, 0, stream>>>(zsb, rowbeg, rowend, col, idi, b0, xh, nullptr);
    // layer 1
    k_gemm_mfma<0><<<GEMM_GRID, 256, 0, stream>>>(xh, W1, odi, zsb);
    k_gather<1, 0><<<GATHER_GRID, 256, 0, stream>>>(zsb, rowbeg, rowend, col, idi, b1, xh, nullptr);
    // layer 2 (last: fp16 out + norm partials)
    k_gemm_mfma<0><<<GEMM_GRID, 256, 0, stream>>>(xh, W2, odi, zsb);
    k_gather<0, 1><<<GATHER_GRID, 256, 0, stream>>>(zsb, rowbeg, rowend, col, idi, b2, xh, partials);

    // factor + pooling (fp16 final h)
    k_reduce_factor<<<1, 256, 0, stream>>>(partials, factor);
    int poolWaves  = (N_NODES + POOL_CHUNK - 1) / POOL_CHUNK;
    int poolBlocks = (poolWaves + 3) / 4;
    k_pool<<<poolBlocks, 256, 0, stream>>>(xh, gids, factor, out);
}

// Round 12
// 194.231 us; speedup vs baseline: 5.2662x; 1.0629x over previous
//
#include <hip/hip_runtime.h>
#include <hip/hip_fp16.h>

#define N_NODES 100000
#define N_EDGES 1600000
#define N_GRAPHS 2000
#define HID 64
#define NB 391          // final buckets of 256 nodes
#define CAP 5120        // per-bucket capacity (mean 4096; +16 sigma)
#define NSUP 16         // super-buckets of SUPW nodes
#define SUPW 6400       // 25 * 256
#define CAP_S 106496    // per-super capacity (mean 102400, +13 sigma), = 26*4096
#define CH_A 2048
#define NCH_A ((N_EDGES + CH_A - 1) / CH_A)   // 782
#define BCH 4096
#define NCHB 26         // CAP_S / BCH
#define GATHER_GRID 2048
#define NPW 13          // nodes per wave: 2048*4*13 = 106496 >= N_NODES
#define GEMM_GRID 512
#define N_TILE16 (N_NODES / 16)  // 6250 (exact)

typedef _Float16 half8 __attribute__((ext_vector_type(8)));
typedef float f32x4 __attribute__((ext_vector_type(4)));

// ---------------- utility: zero two ranges in one launch ----------------
__global__ __launch_bounds__(256) void k_zero2(int* __restrict__ p1, int n1,
                                               int* __restrict__ p2, int n2) {
    int i = blockIdx.x * 256 + threadIdx.x;
    if (i < n1) p1[i] = 0;
    if (i < n2) p2[i] = 0;
}

// ---------------- pass A: 16-way super-bucket split (dst u32 entries, src u16 entries) --------
__global__ __launch_bounds__(256) void k_passA(const int* __restrict__ src, const int* __restrict__ dst,
                                               int* __restrict__ scur_dst, int* __restrict__ scur_src,
                                               unsigned* __restrict__ sup_dst,
                                               unsigned short* __restrict__ sup_src) {
    __shared__ unsigned stD[CH_A];
    __shared__ unsigned short stS[CH_A];
    __shared__ unsigned char binD[CH_A];
    __shared__ unsigned char binS[CH_A];
    __shared__ int lcntD[NSUP], lexD[NSUP], lofD[NSUP], runD[NSUP];
    __shared__ int lcntS[NSUP], lexS[NSUP], lofS[NSUP], runS[NSUP];
    int tid = threadIdx.x;
    int e0 = blockIdx.x * CH_A;
    int n = min(CH_A, N_EDGES - e0);
    if (tid < NSUP) { lcntD[tid] = 0; lcntS[tid] = 0; }
    __syncthreads();
    int sv[8], dv[8];
#pragma unroll
    for (int k = 0; k < 8; ++k) {
        int i = k * 256 + tid;
        if (i < n) { sv[k] = src[e0 + i]; dv[k] = dst[e0 + i]; }
        else dv[k] = -1;
    }
#pragma unroll
    for (int k = 0; k < 8; ++k)
        if (dv[k] >= 0) {
            atomicAdd(&lcntD[dv[k] / SUPW], 1);
            atomicAdd(&lcntS[sv[k] / SUPW], 1);
        }
    __syncthreads();
    if (tid == 0)  { int a = 0; for (int i = 0; i < NSUP; ++i) { lexD[i] = a; lofD[i] = a; a += lcntD[i]; } }
    if (tid == 64) { int a = 0; for (int i = 0; i < NSUP; ++i) { lexS[i] = a; lofS[i] = a; a += lcntS[i]; } }
    __syncthreads();
#pragma unroll
    for (int k = 0; k < 8; ++k)
        if (dv[k] >= 0) {
            int d = dv[k], s = sv[k];
            int bD = d / SUPW;
            int pD = atomicAdd(&lofD[bD], 1);
            stD[pD] = ((unsigned)(d - bD * SUPW) << 17) | (unsigned)s;
            binD[pD] = (unsigned char)bD;
            int bS = s / SUPW;
            int pS = atomicAdd(&lofS[bS], 1);
            stS[pS] = (unsigned short)(s - bS * SUPW);
            binS[pS] = (unsigned char)bS;
        }
    __syncthreads();
    if (tid < NSUP) runD[tid] = lcntD[tid] ? atomicAdd(&scur_dst[tid], lcntD[tid]) : 0;
    if (tid >= 128 && tid < 128 + NSUP) {
        int b = tid - 128;
        runS[b] = lcntS[b] ? atomicAdd(&scur_src[b], lcntS[b]) : 0;
    }
    __syncthreads();
    for (int i = tid; i < n; i += 256) {
        int b = binD[i];
        int pos = runD[b] + (i - lexD[b]);
        if (pos < CAP_S) sup_dst[(size_t)b * CAP_S + pos] = stD[i];
    }
    for (int i = tid; i < n; i += 256) {
        int b = binS[i];
        int pos = runS[b] + (i - lexS[b]);
        if (pos < CAP_S) sup_src[(size_t)b * CAP_S + pos] = stS[i];
    }
}

// ---------------- pass B: refine each super-bucket into its 25 sub-buckets ----------------
__global__ __launch_bounds__(256) void k_passB(const unsigned* __restrict__ sup_dst,
                                               const unsigned short* __restrict__ sup_src,
                                               const int* __restrict__ scur_dst,
                                               const int* __restrict__ scur_src,
                                               int* __restrict__ gcur_dst, int* __restrict__ gcur_src,
                                               unsigned* __restrict__ part_dst,
                                               unsigned char* __restrict__ part_src) {
    __shared__ unsigned st[BCH];
    __shared__ unsigned char bin[BCH];
    __shared__ int lcnt[25], lex[25], lof[25], run[25];
    int tid = threadIdx.x;
    int isSrc = blockIdx.x >= NSUP * NCHB;
    int bx = isSrc ? blockIdx.x - NSUP * NCHB : blockIdx.x;
    int sb = bx / NCHB, ch = bx % NCHB;
    int total = isSrc ? scur_src[sb] : scur_dst[sb];
    total = min(total, CAP_S);
    int o0 = ch * BCH;
    int n = min(BCH, total - o0);
    if (n <= 0) return;
    int bg0 = sb * 25;
    if (tid < 25) lcnt[tid] = 0;
    __syncthreads();

    if (!isSrc) {
        unsigned ev[16];
        int bb[16];
#pragma unroll
        for (int k = 0; k < 16; ++k) {
            int i = k * 256 + tid;
            if (i < n) {
                unsigned e = sup_dst[(size_t)sb * CAP_S + o0 + i];
                ev[k] = e;
                bb[k] = (int)(e >> 25);
                atomicAdd(&lcnt[bb[k]], 1);
            } else bb[k] = -1;
        }
        __syncthreads();
        if (tid == 0) { int a = 0; for (int i = 0; i < 25; ++i) { lex[i] = a; lof[i] = a; a += lcnt[i]; } }
        __syncthreads();
#pragma unroll
        for (int k = 0; k < 16; ++k)
            if (bb[k] >= 0) {
                unsigned e = ev[k];
                unsigned s = e & 0x1FFFFu;
                unsigned low = (e >> 17) & 255u;
                int p = atomicAdd(&lof[bb[k]], 1);
                st[p] = (s << 8) | low;
                bin[p] = (unsigned char)bb[k];
            }
        __syncthreads();
        if (tid < 25) run[tid] = lcnt[tid] ? atomicAdd(&gcur_dst[bg0 + tid], lcnt[tid]) : 0;
        __syncthreads();
        for (int i = tid; i < n; i += 256) {
            int b = bin[i];
            int pos = run[b] + (i - lex[b]);
            if (pos < CAP) part_dst[(size_t)(bg0 + b) * CAP + pos] = st[i];
        }
    } else {
        unsigned char* st8 = (unsigned char*)st;
        int rv[16];
        int bb[16];
#pragma unroll
        for (int k = 0; k < 16; ++k) {
            int i = k * 256 + tid;
            if (i < n) {
                int r = (int)sup_src[(size_t)sb * CAP_S + o0 + i];
                rv[k] = r;
                bb[k] = r >> 8;
                atomicAdd(&lcnt[bb[k]], 1);
            } else bb[k] = -1;
        }
        __syncthreads();
        if (tid == 0) { int a = 0; for (int i = 0; i < 25; ++i) { lex[i] = a; lof[i] = a; a += lcnt[i]; } }
        __syncthreads();
#pragma unroll
        for (int k = 0; k < 16; ++k)
            if (bb[k] >= 0) {
                int p = atomicAdd(&lof[bb[k]], 1);
                st8[p] = (unsigned char)(rv[k] & 255);
                bin[p] = (unsigned char)bb[k];
            }
        __syncthreads();
        if (tid < 25) run[tid] = lcnt[tid] ? atomicAdd(&gcur_src[bg0 + tid], lcnt[tid]) : 0;
        __syncthreads();
        for (int i = tid; i < n; i += 256) {
            int b = bin[i];
            int pos = run[b] + (i - lex[b]);
            if (pos < CAP) part_src[(size_t)(bg0 + b) * CAP + pos] = st8[i];
        }
    }
}

// ---------------- merged: blocks [0,NB) build dst CSR; [NB,2NB) count out-deg -> odi ----------
__global__ __launch_bounds__(256) void k_csr_count(const unsigned* __restrict__ part_dst,
                                                   const unsigned char* __restrict__ part_src,
                                                   const int* __restrict__ gcur_dst,
                                                   const int* __restrict__ gcur_src,
                                                   int* __restrict__ rowbeg, int* __restrict__ rowend,
                                                   float* __restrict__ idi, float* __restrict__ odi,
                                                   int* __restrict__ col) {
    __shared__ int cnt[256];
    __shared__ int cur[256];
    __shared__ int wsum[4];
    int tid = threadIdx.x;
    if (blockIdx.x >= NB) {
        int b = blockIdx.x - NB;
        int nE = min(gcur_src[b], CAP);
        const unsigned char* pb = part_src + (size_t)b * CAP;
        cnt[tid] = 0;
        __syncthreads();
        for (int i = tid; i < nE; i += 256) atomicAdd(&cnt[pb[i]], 1);
        __syncthreads();
        int v = b * 256 + tid;
        if (v < N_NODES) odi[v] = rsqrtf((float)max(cnt[tid], 1));
        return;
    }
    int b = blockIdx.x;
    int base = b * CAP;
    int nE = min(gcur_dst[b], CAP);
    const unsigned* pb = part_dst + (size_t)b * CAP;
    cnt[tid] = 0;
    __syncthreads();
    for (int i = tid; i < nE; i += 256) atomicAdd(&cnt[pb[i] & 255], 1);
    __syncthreads();
    int c = cnt[tid];
    int incl = c;
#pragma unroll
    for (int off = 1; off < 64; off <<= 1) {
        int t = __shfl_up(incl, off, 64);
        if ((tid & 63) >= off) incl += t;
    }
    if ((tid & 63) == 63) wsum[tid >> 6] = incl;
    __syncthreads();
    int add = 0;
    for (int w = 0; w < (tid >> 6); ++w) add += wsum[w];
    incl += add;
    int excl = incl - c;
    int v = b * 256 + tid;
    if (v < N_NODES) {
        rowbeg[v] = base + excl;
        rowend[v] = base + incl;
        idi[v] = rsqrtf((float)max(c, 1));
    }
    cur[tid] = excl;
    __syncthreads();
    for (int i = tid; i < nE; i += 256) {
        unsigned e = pb[i];
        int p = atomicAdd(&cur[e & 255], 1);
        col[base + p] = (int)(e >> 8);
    }
}

// ---------------- dense GEMM via MFMA: zs[v] = (x[v] @ W) * odi[v]  (fp16 out) ----------------
template <int F32IN>
__global__ __launch_bounds__(256) void k_gemm_mfma(const void* __restrict__ inv,
                                                   const float* __restrict__ W,
                                                   const float* __restrict__ odi,
                                                   __half* __restrict__ zs) {
    __shared__ _Float16 Wt[64 * 64];  // Wt[j][k] = W[k][j]
    int tid = threadIdx.x;
    for (int i = tid; i < 4096; i += 256) {
        int k = i >> 6, j = i & 63;
        Wt[j * 64 + k] = (_Float16)W[i];
    }
    __syncthreads();

    int lane = tid & 63;
    int wid = tid >> 6;
    int lrow = lane & 15;
    int lgrp = lane >> 4;

    half8 Bf[4][2];
#pragma unroll
    for (int nt = 0; nt < 4; ++nt)
#pragma unroll
        for (int kh = 0; kh < 2; ++kh)
            Bf[nt][kh] = *(half8*)&Wt[(nt * 16 + lrow) * 64 + kh * 32 + lgrp * 8];

    for (int t = blockIdx.x * 4 + wid; t < N_TILE16; t += GEMM_GRID * 4) {
        int v0 = t * 16;
        half8 a0, a1;
        if (F32IN) {
            const float* A = (const float*)inv + (size_t)(v0 + lrow) * 64 + lgrp * 8;
            float4 f0 = *(const float4*)A;
            float4 f1 = *(const float4*)(A + 4);
            float4 g0 = *(const float4*)(A + 32);
            float4 g1 = *(const float4*)(A + 36);
            a0[0] = (_Float16)f0.x; a0[1] = (_Float16)f0.y; a0[2] = (_Float16)f0.z; a0[3] = (_Float16)f0.w;
            a0[4] = (_Float16)f1.x; a0[5] = (_Float16)f1.y; a0[6] = (_Float16)f1.z; a0[7] = (_Float16)f1.w;
            a1[0] = (_Float16)g0.x; a1[1] = (_Float16)g0.y; a1[2] = (_Float16)g0.z; a1[3] = (_Float16)g0.w;
            a1[4] = (_Float16)g1.x; a1[5] = (_Float16)g1.y; a1[6] = (_Float16)g1.z; a1[7] = (_Float16)g1.w;
        } else {
            const _Float16* A = (const _Float16*)inv + (size_t)(v0 + lrow) * 64 + lgrp * 8;
            a0 = *(const half8*)A;
            a1 = *(const half8*)(A + 32);
        }
        f32x4 acc[4];
#pragma unroll
        for (int nt = 0; nt < 4; ++nt) { acc[nt] = (f32x4)0.f; }
#pragma unroll
        for (int nt = 0; nt < 4; ++nt) {
            acc[nt] = __builtin_amdgcn_mfma_f32_16x16x32_f16(a0, Bf[nt][0], acc[nt], 0, 0, 0);
            acc[nt] = __builtin_amdgcn_mfma_f32_16x16x32_f16(a1, Bf[nt][1], acc[nt], 0, 0, 0);
        }
#pragma unroll
        for (int r = 0; r < 4; ++r) {
            int node = v0 + lgrp * 4 + r;
            float w = odi[node];
#pragma unroll
            for (int nt = 0; nt < 4; ++nt)
                zs[(size_t)node * 64 + nt * 16 + lrow] = __float2half_rn(acc[nt][r] * w);
        }
    }
}

// ---------------- gather v4: per-wave consecutive nodes; LAST fuses unscaled sum-pool -------
// lane = (edge-parity half, feature-pair fp). One coalesced col load per node + shfl srcs.
template <int RELU, int LAST>
__global__ __launch_bounds__(256) void k_gather(const __half* __restrict__ zs, const int* __restrict__ rowbeg,
                                                const int* __restrict__ rowend, const int* __restrict__ col,
                                                const float* __restrict__ idi, const float* __restrict__ b,
                                                __half* __restrict__ xout, const int* __restrict__ gid,
                                                float* __restrict__ out, float* __restrict__ partials) {
    __shared__ float part[4];
    int tid = threadIdx.x;
    int lane = tid & 63;
    int wid = tid >> 6;
    int half = lane >> 5;   // 0: even edge slot, 1: odd edge slot
    int fp = lane & 31;     // feature-pair
    float2 bias2 = *(const float2*)&b[fp * 2];
    float nacc = 0.f;
    float2 pacc = {0.f, 0.f};
    int curg = -1;

    int w = __builtin_amdgcn_readfirstlane(blockIdx.x * 4 + wid);
    int v0 = w * NPW;
    int vend = min(v0 + NPW, N_NODES);

    for (int v = v0; v < vend; ++v) {
        int beg = rowbeg[v], end = rowend[v];
        int deg = end - beg;
        int degS = min(deg, 64);  // edges served by the shfl path
        int c = col[beg + min(lane, max(degS - 1, 0))];  // one coalesced load
        float2 a0 = {0.f, 0.f}, a1 = {0.f, 0.f}, a2 = {0.f, 0.f}, a3 = {0.f, 0.f};
        int m = 0;  // pair-slot index; slot m covers edges 2m (half 0), 2m+1 (half 1)
        for (; (m + 8) * 2 <= degS; m += 8) {
#pragma unroll
            for (int j = 0; j < 8; ++j) {
                int s = __shfl(c, 2 * (m + j) + half, 64);
                float2 f = __half22float2(*((const __half2*)(zs + (size_t)s * 64) + fp));
                if ((j & 3) == 0) { a0.x += f.x; a0.y += f.y; }
                else if ((j & 3) == 1) { a1.x += f.x; a1.y += f.y; }
                else if ((j & 3) == 2) { a2.x += f.x; a2.y += f.y; }
                else { a3.x += f.x; a3.y += f.y; }
            }
        }
        if ((m + 4) * 2 <= degS) {
#pragma unroll
            for (int j = 0; j < 4; ++j) {
                int s = __shfl(c, 2 * (m + j) + half, 64);
                float2 f = __half22float2(*((const __half2*)(zs + (size_t)s * 64) + fp));
                if (j == 0) { a0.x += f.x; a0.y += f.y; }
                else if (j == 1) { a1.x += f.x; a1.y += f.y; }
                else if (j == 2) { a2.x += f.x; a2.y += f.y; }
                else { a3.x += f.x; a3.y += f.y; }
            }
            m += 4;
        }
        if (m * 2 < degS) {
#pragma unroll
            for (int j = 0; j < 4; ++j) {
                int e = 2 * (m + j) + half;
                int ee = (e < degS) ? e : (degS - 1);
                int s = __shfl(c, ee, 64);
                float2 f = __half22float2(*((const __half2*)(zs + (size_t)s * 64) + fp));
                float msk = (e < degS) ? 1.f : 0.f;
                if (j == 0) { a0.x = fmaf(f.x, msk, a0.x); a0.y = fmaf(f.y, msk, a0.y); }
                else if (j == 1) { a1.x = fmaf(f.x, msk, a1.x); a1.y = fmaf(f.y, msk, a1.y); }
                else if (j == 2) { a2.x = fmaf(f.x, msk, a2.x); a2.y = fmaf(f.y, msk, a2.y); }
                else { a3.x = fmaf(f.x, msk, a3.x); a3.y = fmaf(f.y, msk, a3.y); }
            }
        }
        if (deg > 64) {  // rare fallback: direct per-edge col loads for the remainder
            for (int p = beg + 64; p < end; p += 8) {
#pragma unroll
                for (int j = 0; j < 4; ++j) {
                    int e = p + 2 * j + half;
                    int q = (e < end) ? e : (end - 1);
                    int s = col[q];
                    float2 f = __half22float2(*((const __half2*)(zs + (size_t)s * 64) + fp));
                    float msk = (e < end) ? 1.f : 0.f;
                    a0.x = fmaf(f.x, msk, a0.x); a0.y = fmaf(f.y, msk, a0.y);
                }
            }
        }
        float2 a;
        a.x = (a0.x + a1.x) + (a2.x + a3.x);
        a.y = (a0.y + a1.y) + (a2.y + a3.y);
        a.x += __shfl_xor(a.x, 32, 64);
        a.y += __shfl_xor(a.y, 32, 64);
        float iv = idi[v];
        float2 o;
        o.x = fmaf(a.x, iv, bias2.x);
        o.y = fmaf(a.y, iv, bias2.y);
        if (RELU) { o.x = fmaxf(o.x, 0.f); o.y = fmaxf(o.y, 0.f); }

        if (LAST) {
            int gg = gid[v];  // wave-uniform scalar load
            if (gg != curg) {
                if (curg >= 0 && half == 0) {
                    atomicAdd(&out[(size_t)curg * 64 + fp * 2], pacc.x);
                    atomicAdd(&out[(size_t)curg * 64 + fp * 2 + 1], pacc.y);
                }
                curg = gg;
                pacc.x = 0.f; pacc.y = 0.f;
            }
            pacc.x += o.x; pacc.y += o.y;
            float s = o.x * o.x + o.y * o.y;  // both halves identical
#pragma unroll
            for (int off = 32; off > 0; off >>= 1) s += __shfl_xor(s, off, 64);
            if (lane == 0) nacc += sqrtf(0.5f * s);  // halves double-counted
        } else {
            if (half == 0)
                *((__half2*)(xout + (size_t)v * 64) + fp) = __floats2half2_rn(o.x, o.y);
        }
    }

    if (LAST) {
        if (curg >= 0 && half == 0) {
            atomicAdd(&out[(size_t)curg * 64 + fp * 2], pacc.x);
            atomicAdd(&out[(size_t)curg * 64 + fp * 2 + 1], pacc.y);
        }
        if (lane == 0) part[wid] = nacc;
        __syncthreads();
        if (tid == 0) partials[blockIdx.x] = part[0] + part[1] + part[2] + part[3];
    }
}

// ---------------- finish: factor from partials (redundant per block), scale out in place ------
__global__ __launch_bounds__(256) void k_finish(const float* __restrict__ partials,
                                                float* __restrict__ out) {
    __shared__ float sd[256];
    int tid = threadIdx.x;
    float s = 0.f;
    for (int i = tid; i < GATHER_GRID; i += 256) s += partials[i];
    sd[tid] = s;
    __syncthreads();
    for (int off = 128; off > 0; off >>= 1) {
        if (tid < off) sd[tid] += sd[tid + off];
        __syncthreads();
    }
    float factor = 8.0f * (float)N_NODES / sd[0];
    int i = blockIdx.x * 256 + tid;
    if (i < N_GRAPHS * 64) out[i] *= factor;
}

extern "C" void kernel_launch(void* const* d_in, const int* in_sizes, int n_in,
                              void* d_out, int out_size, void* d_ws, size_t ws_size,
                              hipStream_t stream) {
    const float* h    = (const float*)d_in[0];
    const int*   esrc = (const int*)d_in[1];
    const int*   edst = (const int*)d_in[2];
    const int*   gids = (const int*)d_in[3];
    const float* W0 = (const float*)d_in[4];
    const float* b0 = (const float*)d_in[5];
    const float* W1 = (const float*)d_in[6];
    const float* b1 = (const float*)d_in[7];
    const float* W2 = (const float*)d_in[8];
    const float* b2 = (const float*)d_in[9];
    float* out = (float*)d_out;

    char* wsp = (char*)d_ws;
    size_t off = 0;
    auto alloc = [&](size_t bytes) -> void* {
        void* p = wsp + off;
        off += (bytes + 255) & ~(size_t)255;
        return p;
    };
    // cursors: [0,16) sup-dst, [16,32) sup-src, [32,423) sub-dst, [423,814) sub-src
    int*   cursors    = (int*)alloc(814 * 4);
    float* odi        = (float*)alloc((size_t)N_NODES * 4);
    float* idi        = (float*)alloc((size_t)N_NODES * 4);
    int*   rowbeg     = (int*)alloc((size_t)N_NODES * 4);
    int*   rowend     = (int*)alloc((size_t)N_NODES * 4);
    float* partials   = (float*)alloc((size_t)GATHER_GRID * 4);
    int*   col        = (int*)alloc((size_t)NB * CAP * 4);          // 8.0 MB, fixed-stride
    __half* zsb       = (__half*)alloc((size_t)N_NODES * 64 * 2);   // 12.8 MB
    __half* xh        = (__half*)alloc((size_t)N_NODES * 64 * 2);   // 12.8 MB
    unsigned*       sup_dst  = (unsigned*)alloc((size_t)NSUP * CAP_S * 4);        // 6.82 MB
    unsigned short* sup_src  = (unsigned short*)alloc((size_t)NSUP * CAP_S * 2);  // 3.41 MB
    unsigned*       part_dst = (unsigned*)alloc((size_t)NB * CAP * 4);            // 8.00 MB
    unsigned char*  part_src = (unsigned char*)alloc((size_t)NB * CAP);           // 2.00 MB

    int* scur_dst = cursors;
    int* scur_src = cursors + 16;
    int* gcur_dst = cursors + 32;
    int* gcur_src = cursors + 32 + NB;

    k_zero2<<<(N_GRAPHS * 64 + 255) / 256, 256, 0, stream>>>(cursors, 814, (int*)out, N_GRAPHS * 64);

    // CSR build: two-level radix partition (16 supers -> 25 subs each), then per-bucket CSR/count
    k_passA<<<NCH_A, 256, 0, stream>>>(esrc, edst, scur_dst, scur_src, sup_dst, sup_src);
    k_passB<<<2 * NSUP * NCHB, 256, 0, stream>>>(sup_dst, sup_src, scur_dst, scur_src,
                                                 gcur_dst, gcur_src, part_dst, part_src);
    k_csr_count<<<2 * NB, 256, 0, stream>>>(part_dst, part_src, gcur_dst, gcur_src,
                                            rowbeg, rowend, idi, odi, col);

    // layer 0: z = h@W0 (MFMA, odi-scaled fp16) -> gather
    k_gemm_mfma<1><<<GEMM_GRID, 256, 0, stream>>>(h, W0, odi, zsb);
    k_gather<1, 0><<<GATHER_GRID, 256, 0, stream>>>(zsb, rowbeg, rowend, col, idi, b0, xh,
                                                    nullptr, nullptr, nullptr);
    // layer 1
    k_gemm_mfma<0><<<GEMM_GRID, 256, 0, stream>>>(xh, W1, odi, zsb);
    k_gather<1, 0><<<GATHER_GRID, 256, 0, stream>>>(zsb, rowbeg, rowend, col, idi, b1, xh,
                                                    nullptr, nullptr, nullptr);
    // layer 2 (last: fused unscaled sum-pool + norm partials; no xh write)
    k_gemm_mfma<0><<<GEMM_GRID, 256, 0, stream>>>(xh, W2, odi, zsb);
    k_gather<0, 1><<<GATHER_GRID, 256, 0, stream>>>(zsb, rowbeg, rowend, col, idi, b2, nullptr,
                                                    gids, out, partials);

    // factor + in-place scale of pooled output
    k_finish<<<(N_GRAPHS * 64 + 255) / 256, 256, 0, stream>>>(partials, out);
}